// Round 8
// baseline (431.901 us; speedup 1.0000x reference)
//
#include <hip/hip_runtime.h>
#include <hip/hip_bf16.h>

#define NN 50000
#define NE 800000
#define NG 512

typedef __bf16 bf16_t;
typedef __bf16 bf16x8 __attribute__((ext_vector_type(8)));
typedef __bf16 bf16x4 __attribute__((ext_vector_type(4)));
typedef float f32x4 __attribute__((ext_vector_type(4)));
typedef float f32x2 __attribute__((ext_vector_type(2)));

__device__ __forceinline__ float lrelu(float v) { return v >= 0.f ? v : 0.01f * v; }

// unpack 2 bf16 (packed in one u32) -> float2 (pair order: lo, hi)
__device__ __forceinline__ f32x2 unpk2(unsigned w) {
    union { unsigned u; float f; } lo, hi;
    lo.u = w << 16;
    hi.u = w & 0xffff0000u;
    f32x2 r; r[0] = lo.f; r[1] = hi.f; return r;
}

// opaque per-lane zero: forces VGPR addressing (vmcnt path) for loads that the
// compiler would otherwise scalarize onto the s_load/lgkmcnt path.
__device__ __forceinline__ int vzero() {
    int vz;
    asm("v_mov_b32 %0, 0" : "=v"(vz));
    return vz;
}

// ---------------- tiny precomputes ----------------
// TYB[b][t] = bf16( sum_k (emb[b][k]+c1l2b[k]) * W1[t][k] + c1lb[t] )
// WC1[t][c] = sum_k W1[t][k] * c1l2w[k][c]
// WC2[t][c] = sum_k W2[t][k] * c2l2w[k][c];  CB2[t] = sum_k W2[t][k]*c2l2b[k] + c2lb[t]
__global__ void gme_setup(const float* __restrict__ emb,
                          const float* __restrict__ c1lw, const float* __restrict__ c1l2w,
                          const float* __restrict__ c1l2b, const float* __restrict__ c1lb,
                          const float* __restrict__ c2lw, const float* __restrict__ c2l2w,
                          const float* __restrict__ c2l2b, const float* __restrict__ c2lb,
                          bf16_t* __restrict__ TYB, float* __restrict__ WC1,
                          float* __restrict__ WC2, float* __restrict__ CB2,
                          bf16_t* __restrict__ W2B) {
    int b = blockIdx.x, t = threadIdx.x;
    if (b < 51) {
        const float4* er = (const float4*)(emb + b * 128);
        const float4* zb = (const float4*)c1l2b;
        const float4* wr = (const float4*)(c1lw + t * 128);
        float s = 0.f;
        for (int k = 0; k < 32; ++k) {
            float4 e = er[k], z = zb[k], w = wr[k];
            s += (e.x + z.x) * w.x + (e.y + z.y) * w.y + (e.z + z.z) * w.z + (e.w + z.w) * w.w;
        }
        TYB[b * 256 + t] = (bf16_t)(s + c1lb[t]);
    } else if (b == 51) {
        const float4* wr = (const float4*)(c1lw + t * 128);
        const float4* cw = (const float4*)c1l2w;
        float4 a = make_float4(0.f, 0.f, 0.f, 0.f);
        for (int k = 0; k < 32; ++k) {
            float4 w = wr[k];
            float4 c0 = cw[k * 4 + 0], c1 = cw[k * 4 + 1], c2 = cw[k * 4 + 2], c3 = cw[k * 4 + 3];
            a.x += w.x * c0.x + w.y * c1.x + w.z * c2.x + w.w * c3.x;
            a.y += w.x * c0.y + w.y * c1.y + w.z * c2.y + w.w * c3.y;
            a.z += w.x * c0.z + w.y * c1.z + w.z * c2.z + w.w * c3.z;
            a.w += w.x * c0.w + w.y * c1.w + w.z * c2.w + w.w * c3.w;
        }
        ((float4*)WC1)[t] = a;
    } else if (b == 52) {
        const float4* wr = (const float4*)(c2lw + t * 256);
        const float4* cw = (const float4*)c2l2w;
        const float4* zb = (const float4*)c2l2b;
        float4 a = make_float4(0.f, 0.f, 0.f, 0.f);
        float ab = 0.f;
        for (int k = 0; k < 64; ++k) {
            float4 w = wr[k];
            float4 c0 = cw[k * 4 + 0], c1 = cw[k * 4 + 1], c2 = cw[k * 4 + 2], c3 = cw[k * 4 + 3];
            float4 z = zb[k];
            a.x += w.x * c0.x + w.y * c1.x + w.z * c2.x + w.w * c3.x;
            a.y += w.x * c0.y + w.y * c1.y + w.z * c2.y + w.w * c3.y;
            a.z += w.x * c0.z + w.y * c1.z + w.z * c2.z + w.w * c3.z;
            a.w += w.x * c0.w + w.y * c1.w + w.z * c2.w + w.w * c3.w;
            ab += w.x * z.x + w.y * z.y + w.z * z.z + w.w * z.w;
        }
        ((float4*)WC2)[t] = a;
        CB2[t] = ab + c2lb[t];
    } else {
        int i0 = (b - 53) * 1024;
        for (int r = 0; r < 4; ++r) {
            int i = i0 + r * 256 + t;
            W2B[i] = (bf16_t)c2lw[i];
        }
    }
}

// ---------------- CSR build ----------------
__global__ void gme_count(const int* __restrict__ ei, int* __restrict__ cnt) {
    int e = blockIdx.x * 256 + threadIdx.x;
    if (e >= NE) return;
    atomicAdd(&cnt[ei[NE + e]], 1);
}

__global__ void gme_scan1(const int* __restrict__ CNT, int* __restrict__ LP,
                          int* __restrict__ BS) {
    __shared__ int lds[256];
    int b = blockIdx.x, t = threadIdx.x;
    int i = b * 196 + t;
    int v = (t < 196 && i < NN) ? CNT[i] : 0;
    lds[t] = v;
    __syncthreads();
    for (int off = 1; off < 256; off <<= 1) {
        int u = (t >= off) ? lds[t - off] : 0;
        __syncthreads();
        lds[t] += u;
        __syncthreads();
    }
    if (t < 196 && i < NN) LP[i] = lds[t] - v;
    if (t == 255) BS[b] = lds[255];
}

__global__ void gme_scan2(const int* __restrict__ BS, int* __restrict__ BX,
                          int* __restrict__ RS) {
    __shared__ int lds[256];
    int t = threadIdx.x;
    int v = BS[t];
    lds[t] = v;
    __syncthreads();
    for (int off = 1; off < 256; off <<= 1) {
        int u = (t >= off) ? lds[t - off] : 0;
        __syncthreads();
        lds[t] += u;
        __syncthreads();
    }
    BX[t] = lds[t] - v;
    if (t == 255) RS[NN] = lds[255];
}

__global__ void gme_scan3(const int* __restrict__ LP, const int* __restrict__ BX,
                          int* __restrict__ RS, int* __restrict__ CUR) {
    int b = blockIdx.x, t = threadIdx.x;
    if (t >= 196) return;
    int i = b * 196 + t;
    if (i >= NN) return;
    int v = BX[b] + LP[i];
    RS[i] = v;
    CUR[i] = v;
}

// permute attr + meta into CSR order: 2 scattered stores per edge
__global__ void gme_scatter(const int* __restrict__ ei,
                            const float4* __restrict__ eattr,
                            const int* __restrict__ node_ids,
                            int* __restrict__ CUR, int* __restrict__ SM,
                            float4* __restrict__ SattrP) {
    int e = blockIdx.x * 256 + threadIdx.x;
    if (e >= NE) return;
    int s = ei[e];
    int d = ei[NE + e];
    int nid = node_ids[s];
    int pos = atomicAdd(&CUR[d], 1);
    SM[pos] = s | (nid << 16);
    SattrP[pos] = eattr[e];
}

// ---------------- conv1 layer: bf16 TY in LDS; 16-deep pipeline; fused BN1 ---
__global__ __launch_bounds__(256, 4) void gme_conv0(
        const int* __restrict__ RS, const int* __restrict__ SM,
        const float4* __restrict__ SattrP, const bf16_t* __restrict__ TYB,
        const float* __restrict__ Wc, float* __restrict__ agg,
        float* __restrict__ PART) {
    __shared__ __align__(16) uint2 sTY[51 * 64];  // 26112 B bf16 table
    {
        const uint4* s4 = (const uint4*)TYB;
        uint4* d4 = (uint4*)sTY;
        for (int i = threadIdx.x; i < 51 * 32; i += 256) d4[i] = s4[i];
    }
    __syncthreads();
    int lane = threadIdx.x & 63;
    int w = threadIdx.x >> 6;
    int vz = vzero();
    const float4* wc4 = (const float4*)Wc;
    int c4 = lane * 4;
    float4 w0 = wc4[c4 + 0], w1 = wc4[c4 + 1], w2 = wc4[c4 + 2], w3 = wc4[c4 + 3];
    f32x2 wA0 = {w0.x, w1.x}, wB0 = {w0.y, w1.y}, wC0 = {w0.z, w1.z}, wD0 = {w0.w, w1.w};
    f32x2 wA1 = {w2.x, w3.x}, wB1 = {w2.y, w3.y}, wC1 = {w2.z, w3.z}, wD1 = {w2.w, w3.w};
    const f32x2 zero = {0.f, 0.f};
    const uint2* lrow = sTY + lane;
    int base = blockIdx.x * 16 + w * 4;
    f32x2 ssum0 = zero, ssum1 = zero, qsum0 = zero, qsum1 = zero;
#pragma unroll 1
    for (int k = 0; k < 4; ++k) {
        int node = __builtin_amdgcn_readfirstlane(base + k);
        int rs = RS[node], re = RS[node + 1];
        f32x2 accP0 = zero, accP1 = zero, accA0 = zero, accA1 = zero;
        auto accum = [&](float4 a, uint2 r) {
            f32x2 y0 = unpk2(r.x), y1 = unpk2(r.y);
            f32x2 ax = {a.x, a.x}, ay = {a.y, a.y}, az = {a.z, a.z}, aw = {a.w, a.w};
            f32x2 m0 = __builtin_elementwise_fma(ax, wA0, y0);
            f32x2 m1 = __builtin_elementwise_fma(ax, wA1, y1);
            m0 = __builtin_elementwise_fma(ay, wB0, m0);
            m1 = __builtin_elementwise_fma(ay, wB1, m1);
            m0 = __builtin_elementwise_fma(az, wC0, m0);
            m1 = __builtin_elementwise_fma(az, wC1, m1);
            m0 = __builtin_elementwise_fma(aw, wD0, m0);
            m1 = __builtin_elementwise_fma(aw, wD1, m1);
            accA0 += m0; accA1 += m1;
            accP0 += __builtin_elementwise_max(m0, zero);
            accP1 += __builtin_elementwise_max(m1, zero);
        };
        int j = rs;
        // 16-deep SM->ds chain; attr loads in 2x8 halves to bound VGPR
        for (; j + 16 <= re; j += 16) {
            int m[16]; uint2 r[16];
#pragma unroll
            for (int u = 0; u < 16; ++u) m[u] = SM[j + u + vz];
#pragma unroll
            for (int u = 0; u < 16; ++u) r[u] = lrow[(m[u] >> 16) << 6];
            {
                float4 a[8];
#pragma unroll
                for (int u = 0; u < 8; ++u) a[u] = SattrP[j + u + vz];
#pragma unroll
                for (int u = 0; u < 8; ++u) accum(a[u], r[u]);
            }
            {
                float4 a[8];
#pragma unroll
                for (int u = 0; u < 8; ++u) a[u] = SattrP[j + 8 + u + vz];
#pragma unroll
                for (int u = 0; u < 8; ++u) accum(a[u], r[8 + u]);
            }
        }
        if (j + 8 <= re) {
            int m[8]; float4 a[8]; uint2 r[8];
#pragma unroll
            for (int u = 0; u < 8; ++u) m[u] = SM[j + u + vz];
#pragma unroll
            for (int u = 0; u < 8; ++u) r[u] = lrow[(m[u] >> 16) << 6];
#pragma unroll
            for (int u = 0; u < 8; ++u) a[u] = SattrP[j + u + vz];
#pragma unroll
            for (int u = 0; u < 8; ++u) accum(a[u], r[u]);
            j += 8;
        }
        if (j + 4 <= re) {
            int m[4]; float4 a[4]; uint2 r[4];
#pragma unroll
            for (int u = 0; u < 4; ++u) m[u] = SM[j + u + vz];
#pragma unroll
            for (int u = 0; u < 4; ++u) r[u] = lrow[(m[u] >> 16) << 6];
#pragma unroll
            for (int u = 0; u < 4; ++u) a[u] = SattrP[j + u + vz];
#pragma unroll
            for (int u = 0; u < 4; ++u) accum(a[u], r[u]);
            j += 4;
        }
        for (; j < re; ++j) {
            int m = SM[j + vz];
            accum(SattrP[j + vz], lrow[(m >> 16) << 6]);
        }
        const f32x2 c99 = {0.99f, 0.99f}, c01 = {0.01f, 0.01f};
        f32x2 o0 = __builtin_elementwise_fma(accP0, c99, accA0 * c01);
        f32x2 o1 = __builtin_elementwise_fma(accP1, c99, accA1 * c01);
        *((float4*)(agg + node * 256) + lane) = make_float4(o0[0], o0[1], o1[0], o1[1]);
        ssum0 += o0; ssum1 += o1;
        qsum0 += o0 * o0; qsum1 += o1 * o1;
    }
    // fused BN1 partial stats: cross-wave reduce in (now dead) sTY space
    __syncthreads();
    float* red = (float*)sTY;  // 4 waves x 512 floats = 8 KB scratch
    red[w * 512 + c4 + 0] = ssum0[0]; red[w * 512 + c4 + 1] = ssum0[1];
    red[w * 512 + c4 + 2] = ssum1[0]; red[w * 512 + c4 + 3] = ssum1[1];
    red[w * 512 + 256 + c4 + 0] = qsum0[0]; red[w * 512 + 256 + c4 + 1] = qsum0[1];
    red[w * 512 + 256 + c4 + 2] = qsum1[0]; red[w * 512 + 256 + c4 + 3] = qsum1[1];
    __syncthreads();
    int cc = threadIdx.x;
    float s = red[cc] + red[512 + cc] + red[1024 + cc] + red[1536 + cc];
    float q = red[256 + cc] + red[768 + cc] + red[1280 + cc] + red[1792 + cc];
    PART[blockIdx.x * 512 + cc] = s;
    PART[blockIdx.x * 512 + 256 + cc] = q;
}

// ---------------- conv2 layer: random gather from 25.6 MB bf16 table ---------
__global__ __launch_bounds__(256, 4) void gme_conv1(
        const int* __restrict__ RS, const int* __restrict__ SM,
        const float4* __restrict__ SattrP, const bf16_t* __restrict__ QB,
        const float* __restrict__ Wc, float* __restrict__ agg) {
    int lane = threadIdx.x & 63;
    int node = __builtin_amdgcn_readfirstlane(blockIdx.x * 4 + (threadIdx.x >> 6));
    if (node >= NN) return;
    const float4* wc4 = (const float4*)Wc;
    int c4 = lane * 4;
    float4 w0 = wc4[c4 + 0], w1 = wc4[c4 + 1], w2 = wc4[c4 + 2], w3 = wc4[c4 + 3];
    f32x2 wA0 = {w0.x, w1.x}, wB0 = {w0.y, w1.y}, wC0 = {w0.z, w1.z}, wD0 = {w0.w, w1.w};
    f32x2 wA1 = {w2.x, w3.x}, wB1 = {w2.y, w3.y}, wC1 = {w2.z, w3.z}, wD1 = {w2.w, w3.w};
    const f32x2 zero = {0.f, 0.f};
    f32x2 accP0 = zero, accP1 = zero, accA0 = zero, accA1 = zero;
    int rs = RS[node], re = RS[node + 1];
    const char* yb = (const char*)QB;
    unsigned loff = (unsigned)(lane << 3);
    auto rowld = [&](int row) -> uint2 {
        return *(const uint2*)(yb + ((unsigned)row << 9) + loff);
    };
    auto accum = [&](float4 a, uint2 r) {
        f32x2 y0 = unpk2(r.x), y1 = unpk2(r.y);
        f32x2 ax = {a.x, a.x}, ay = {a.y, a.y}, az = {a.z, a.z}, aw = {a.w, a.w};
        f32x2 m0 = __builtin_elementwise_fma(ax, wA0, y0);
        f32x2 m1 = __builtin_elementwise_fma(ax, wA1, y1);
        m0 = __builtin_elementwise_fma(ay, wB0, m0);
        m1 = __builtin_elementwise_fma(ay, wB1, m1);
        m0 = __builtin_elementwise_fma(az, wC0, m0);
        m1 = __builtin_elementwise_fma(az, wC1, m1);
        m0 = __builtin_elementwise_fma(aw, wD0, m0);
        m1 = __builtin_elementwise_fma(aw, wD1, m1);
        accA0 += m0; accA1 += m1;
        accP0 += __builtin_elementwise_max(m0, zero);
        accP1 += __builtin_elementwise_max(m1, zero);
    };
    int j = rs;
    for (; j + 12 <= re; j += 12) {
        int s[12]; float4 a[12]; uint2 r[12];
#pragma unroll
        for (int u = 0; u < 12; ++u) s[u] = SM[j + u];
#pragma unroll
        for (int u = 0; u < 12; ++u) r[u] = rowld(s[u] & 0xffff);
#pragma unroll
        for (int u = 0; u < 12; ++u) a[u] = SattrP[j + u];
#pragma unroll
        for (int u = 0; u < 12; ++u) accum(a[u], r[u]);
    }
    if (j + 8 <= re) {
        int s[8]; float4 a[8]; uint2 r[8];
#pragma unroll
        for (int u = 0; u < 8; ++u) s[u] = SM[j + u];
#pragma unroll
        for (int u = 0; u < 8; ++u) r[u] = rowld(s[u] & 0xffff);
#pragma unroll
        for (int u = 0; u < 8; ++u) a[u] = SattrP[j + u];
#pragma unroll
        for (int u = 0; u < 8; ++u) accum(a[u], r[u]);
        j += 8;
    }
    if (j + 4 <= re) {
        int s[4]; float4 a[4]; uint2 r[4];
#pragma unroll
        for (int u = 0; u < 4; ++u) s[u] = SM[j + u];
#pragma unroll
        for (int u = 0; u < 4; ++u) r[u] = rowld(s[u] & 0xffff);
#pragma unroll
        for (int u = 0; u < 4; ++u) a[u] = SattrP[j + u];
#pragma unroll
        for (int u = 0; u < 4; ++u) accum(a[u], r[u]);
        j += 4;
    }
    for (; j < re; ++j) accum(SattrP[j], rowld(SM[j] & 0xffff));
    const f32x2 c99 = {0.99f, 0.99f}, c01 = {0.01f, 0.01f};
    f32x2 o0 = __builtin_elementwise_fma(accP0, c99, accA0 * c01);
    f32x2 o1 = __builtin_elementwise_fma(accP1, c99, accA1 * c01);
    *((float4*)(agg + node * 256) + lane) = make_float4(o0[0], o0[1], o1[0], o1[1]);
}

// ---------------- BN stats (conv1 output): two-stage ----------------
__global__ __launch_bounds__(256) void gme_bns1(const float* __restrict__ P,
                                                float* __restrict__ PART) {
    __shared__ float ls[4][256], lq[4][256];
    int lane = threadIdx.x & 63;
    int w = threadIdx.x >> 6;
    int b = blockIdx.x;
    int r0 = b * 98;
    int r1 = r0 + 98; if (r1 > NN) r1 = NN;
    float4 s = make_float4(0, 0, 0, 0), q = make_float4(0, 0, 0, 0);
    for (int n = r0 + w; n < r1; n += 4) {
        float4 v = ((const float4*)P)[n * 64 + lane];
        s.x += v.x; s.y += v.y; s.z += v.z; s.w += v.w;
        q.x += v.x * v.x; q.y += v.y * v.y; q.z += v.z * v.z; q.w += v.w * v.w;
    }
    int c = lane * 4;
    ls[w][c] = s.x; ls[w][c + 1] = s.y; ls[w][c + 2] = s.z; ls[w][c + 3] = s.w;
    lq[w][c] = q.x; lq[w][c + 1] = q.y; lq[w][c + 2] = q.z; lq[w][c + 3] = q.w;
    __syncthreads();
    if (w == 0) {
#pragma unroll
        for (int k = 0; k < 4; ++k) {
            int cc = c + k;
            PART[b * 512 + cc] = ls[0][cc] + ls[1][cc] + ls[2][cc] + ls[3][cc];
            PART[b * 512 + 256 + cc] = lq[0][cc] + lq[1][cc] + lq[2][cc] + lq[3][cc];
        }
    }
}

// stage 2 over 512 partial rows (bns1 path) -> ST
__global__ __launch_bounds__(512) void gme_bns2(const float* __restrict__ PART,
                                                float* __restrict__ ST) {
    int t = threadIdx.x;
    int b = blockIdx.x;
    float acc = 0.f;
#pragma unroll
    for (int r = 0; r < 32; ++r) acc += PART[(b * 32 + r) * 512 + t];
    atomicAdd(&ST[t], acc);
}

// stage 2 over 3125 partial rows (conv0 fused-stats path) -> ST; 98 blocks
__global__ __launch_bounds__(512) void gme_bns2b(const float* __restrict__ PART,
                                                 float* __restrict__ ST) {
    int t = threadIdx.x;
    int b = blockIdx.x;
    int r0 = b * 32;
    int r1 = r0 + 32; if (r1 > 3125) r1 = 3125;
    float acc = 0.f;
    for (int r = r0; r < r1; ++r) acc += PART[r * 512 + t];
    atomicAdd(&ST[t], acc);
}

// ---------------- GEMM, BN1+LeakyReLU fused on A; CB2 folded into output -----
// W2B staged in LDS (128 KB, slot-XOR swizzle -> conflict-free ds_read_b128).
__global__ __launch_bounds__(256) void gme_gemm(const float* __restrict__ P,
                                                const float* __restrict__ ST,
                                                const float* __restrict__ bw,
                                                const float* __restrict__ bb,
                                                const bf16_t* __restrict__ W2B,
                                                const float* __restrict__ CB2,
                                                bf16_t* __restrict__ QB) {
    __shared__ float s_sc[256], s_sh[256];
    __shared__ __align__(16) uint4 sB[8192];  // 128 KB, 16B-slot swizzled
    {
        int c = threadIdx.x;
        float mean = ST[c] * (1.f / NN);
        float var = ST[256 + c] * (1.f / NN) - mean * mean;
        float sc = bw[c] * rsqrtf(var + 1e-5f);
        s_sc[c] = sc;
        s_sh[c] = bb[c] - mean * sc;
        const uint4* w4 = (const uint4*)W2B;
#pragma unroll
        for (int it = 0; it < 32; ++it) {
            int i = it * 256 + c;
            int row = i >> 5, slot = i & 31;
            sB[(row << 5) | (slot ^ (row & 7))] = w4[i];
        }
    }
    __syncthreads();
    int lane = threadIdx.x & 63;
    int wave = blockIdx.x * 4 + (threadIdx.x >> 6);
    if (wave >= NN / 16) return;
    int m0 = wave * 16;
    int r = lane & 15, q = lane >> 4;
    int rx = r & 7;
    const float* arow = P + (m0 + r) * 256 + q * 8;
    bf16x8 a[8];
#pragma unroll
    for (int kt = 0; kt < 8; ++kt) {
        int k0 = kt * 32 + q * 8;
        float4 u0 = *(const float4*)(arow + kt * 32);
        float4 u1 = *(const float4*)(arow + kt * 32 + 4);
        bf16x8 f;
        f[0] = (bf16_t)lrelu(fmaf(u0.x, s_sc[k0 + 0], s_sh[k0 + 0]));
        f[1] = (bf16_t)lrelu(fmaf(u0.y, s_sc[k0 + 1], s_sh[k0 + 1]));
        f[2] = (bf16_t)lrelu(fmaf(u0.z, s_sc[k0 + 2], s_sh[k0 + 2]));
        f[3] = (bf16_t)lrelu(fmaf(u0.w, s_sc[k0 + 3], s_sh[k0 + 3]));
        f[4] = (bf16_t)lrelu(fmaf(u1.x, s_sc[k0 + 4], s_sh[k0 + 4]));
        f[5] = (bf16_t)lrelu(fmaf(u1.y, s_sc[k0 + 5], s_sh[k0 + 5]));
        f[6] = (bf16_t)lrelu(fmaf(u1.z, s_sc[k0 + 6], s_sh[k0 + 6]));
        f[7] = (bf16_t)lrelu(fmaf(u1.w, s_sc[k0 + 7], s_sh[k0 + 7]));
        a[kt] = f;
    }
#pragma unroll 1
    for (int g = 0; g < 2; ++g) {
        f32x4 acc[8];
#pragma unroll
        for (int n8 = 0; n8 < 8; ++n8) acc[n8] = (f32x4){0.f, 0.f, 0.f, 0.f};
#pragma unroll
        for (int kt = 0; kt < 8; ++kt) {
            int slot = (kt * 4 + q) ^ rx;
            bf16x8 bf[8];
#pragma unroll
            for (int n8 = 0; n8 < 8; ++n8) {
                int row = g * 128 + n8 * 16 + r;
                bf[n8] = *(const bf16x8*)&sB[(row << 5) | slot];
            }
#pragma unroll
            for (int n8 = 0; n8 < 8; ++n8) {
                acc[n8] = __builtin_amdgcn_mfma_f32_16x16x32_bf16(bf[n8], a[kt], acc[n8], 0, 0, 0);
            }
        }
#pragma unroll
        for (int n8 = 0; n8 < 8; ++n8) {
            int nt = g * 8 + n8;
            float4 cbv = ((const float4*)CB2)[nt * 4 + q];
            bf16x4 o;
            o[0] = (bf16_t)(acc[n8][0] + cbv.x);
            o[1] = (bf16_t)(acc[n8][1] + cbv.y);
            o[2] = (bf16_t)(acc[n8][2] + cbv.z);
            o[3] = (bf16_t)(acc[n8][3] + cbv.w);
            *(bf16x4*)(QB + (m0 + r) * 256 + nt * 16 + q * 4) = o;
        }
    }
}

// ---------------- graph segment boundaries ----------------
__global__ void gme_gstart(const int* __restrict__ batch, int* __restrict__ GS) {
    int n = blockIdx.x * 256 + threadIdx.x;
    if (n >= NN) return;
    int b = batch[n];
    if (n == 0) {
        for (int g = 0; g <= b; ++g) GS[g] = 0;
    } else {
        int a = batch[n - 1];
        for (int g = a + 1; g <= b; ++g) GS[g] = n;
    }
    if (n == NN - 1) {
        for (int g = b + 1; g <= NG; ++g) GS[g] = NN;
    }
}

// ---------------- fused gate + attentional aggregation (BN2+lrelu inline) ----
__global__ __launch_bounds__(256) void gme_attn(const int* __restrict__ GS,
                                                const float* __restrict__ P,
                                                const float* __restrict__ ST,
                                                const float* __restrict__ bw,
                                                const float* __restrict__ bb,
                                                const float* __restrict__ gw,
                                                const float* __restrict__ gb,
                                                float* __restrict__ out) {
    __shared__ float gl[1024];
    __shared__ float rr[8];
    int g = blockIdx.x, t = threadIdx.x;
    int lo = GS[g], hi = GS[g + 1];
    if (lo >= hi) { out[g * 256 + t] = 0.f; return; }
    int lane = t & 63, w = t >> 6;
    // phase A: per-node gates, wave-parallel (wave w -> nodes lo+w, step 4)
    {
        float4 s4 = ((const float4*)ST)[lane];
        float4 q4 = ((const float4*)(ST + 256))[lane];
        float4 w4 = ((const float4*)bw)[lane];
        float4 b4 = ((const float4*)bb)[lane];
        float4 g4 = ((const float4*)gw)[lane];
        float m0 = s4.x * (1.f / NN), m1 = s4.y * (1.f / NN);
        float m2 = s4.z * (1.f / NN), m3 = s4.w * (1.f / NN);
        float sc0 = w4.x * rsqrtf(q4.x * (1.f / NN) - m0 * m0 + 1e-5f);
        float sc1 = w4.y * rsqrtf(q4.y * (1.f / NN) - m1 * m1 + 1e-5f);
        float sc2 = w4.z * rsqrtf(q4.z * (1.f / NN) - m2 * m2 + 1e-5f);
        float sc3 = w4.w * rsqrtf(q4.w * (1.f / NN) - m3 * m3 + 1e-5f);
        float sh0 = b4.x - m0 * sc0, sh1 = b4.y - m1 * sc1;
        float sh2 = b4.z - m2 * sc2, sh3 = b4.w - m3 * sc3;
        float gb0 = gb[0];
        for (int n = lo + w; n < hi; n += 4) {
            float4 p = *(const float4*)(P + n * 256 + lane * 4);
            float d = lrelu(fmaf(p.x, sc0, sh0)) * g4.x
                    + lrelu(fmaf(p.y, sc1, sh1)) * g4.y
                    + lrelu(fmaf(p.z, sc2, sh2)) * g4.z
                    + lrelu(fmaf(p.w, sc3, sh3)) * g4.w;
#pragma unroll
            for (int off = 32; off > 0; off >>= 1) d += __shfl_xor(d, off, 64);
            if (lane == 0) gl[n - lo] = d + gb0;
        }
    }
    __syncthreads();
    // phase B: softmax max + denom over gl[0..cnt)
    int cnt = hi - lo;
    float lm = -3.0e38f;
    for (int i = t; i < cnt; i += 256) lm = fmaxf(lm, gl[i]);
#pragma unroll
    for (int off = 32; off > 0; off >>= 1) lm = fmaxf(lm, __shfl_xor(lm, off, 64));
    if (lane == 0) rr[w] = lm;
    __syncthreads();
    float mx = fmaxf(fmaxf(rr[0], rr[1]), fmaxf(rr[2], rr[3]));
    float ls = 0.f;
    for (int i = t; i < cnt; i += 256) { float e = expf(gl[i] - mx); gl[i] = e; ls += e; }
#pragma unroll
    for (int off = 32; off > 0; off >>= 1) ls += __shfl_xor(ls, off, 64);
    if (lane == 0) rr[4 + w] = ls;
    __syncthreads();
    float sinv = 1.f / (rr[4] + rr[5] + rr[6] + rr[7]);
    // phase C: weighted accumulate, thread t = channel t (P slice is L2-hot)
    float mean = ST[t] * (1.f / NN);
    float var = ST[256 + t] * (1.f / NN) - mean * mean;
    float sc = bw[t] * rsqrtf(var + 1e-5f);
    float sh = bb[t] - mean * sc;
    float a0 = 0.f, a1 = 0.f, a2 = 0.f, a3 = 0.f;
    int n = lo;
    for (; n + 4 <= hi; n += 4) {
        float p0 = P[n * 256 + t], p1 = P[(n + 1) * 256 + t];
        float p2 = P[(n + 2) * 256 + t], p3 = P[(n + 3) * 256 + t];
        a0 = fmaf(gl[n - lo + 0], lrelu(fmaf(p0, sc, sh)), a0);
        a1 = fmaf(gl[n - lo + 1], lrelu(fmaf(p1, sc, sh)), a1);
        a2 = fmaf(gl[n - lo + 2], lrelu(fmaf(p2, sc, sh)), a2);
        a3 = fmaf(gl[n - lo + 3], lrelu(fmaf(p3, sc, sh)), a3);
    }
    for (; n < hi; ++n) a0 = fmaf(gl[n - lo], lrelu(fmaf(P[n * 256 + t], sc, sh)), a0);
    out[g * 256 + t] = (a0 + a1 + a2 + a3) * sinv;
}

extern "C" void kernel_launch(void* const* d_in, const int* in_sizes, int n_in,
                              void* d_out, int out_size, void* d_ws, size_t ws_size,
                              hipStream_t stream) {
    const int* node_ids = (const int*)d_in[0];
    const int* edge_index = (const int*)d_in[1];
    const float4* edge_attr = (const float4*)d_in[2];
    const int* batch = (const int*)d_in[3];
    const float* emb = (const float*)d_in[4];
    const float* c1l2w = (const float*)d_in[5];
    const float* c1l2b = (const float*)d_in[6];
    const float* c1lw = (const float*)d_in[7];
    const float* c1lb = (const float*)d_in[8];
    const float* bn1w = (const float*)d_in[9];
    const float* bn1b = (const float*)d_in[10];
    const float* c2l2w = (const float*)d_in[11];
    const float* c2l2b = (const float*)d_in[12];
    const float* c2lw = (const float*)d_in[13];
    const float* c2lb = (const float*)d_in[14];
    const float* bn2w = (const float*)d_in[15];
    const float* bn2b = (const float*)d_in[16];
    const float* gate_w = (const float*)d_in[17];
    const float* gate_b = (const float*)d_in[18];

    char* ws = (char*)d_ws;
    size_t oP = 0;                        // f32 [50000,256]
    size_t oQB = oP + 51200000;           // bf16 [50000,256]
    size_t oSattrP = oQB + 25600000;      // float4 [800000] permuted attr
    size_t oSM = oSattrP + 12800000;      // int [800000] {src | nid<<16}
    size_t oRS = oSM + 3200000;           // int [50001]
    size_t oCNT = oRS + 200064;           // int [50000]
    size_t oCUR = oCNT + 200000;          // int [50000]
    size_t oLP = oCUR + 200000;           // int [50000]
    size_t oBS = oLP + 200000;            // int [256]
    size_t oBX = oBS + 1024;              // int [256]
    size_t oTY = oBX + 1024;              // bf16 [51,256] (26 KB in 52 KB slot)
    size_t oWC1 = oTY + 52224;            // f32 [256,4]
    size_t oWC2 = oWC1 + 4096;            // f32 [256,4]
    size_t oCB2 = oWC2 + 4096;            // f32 [256]
    size_t oW2B = oCB2 + 1024;            // bf16 [256,256]
    size_t oST = oW2B + 131072;           // f32 [1024]: ST1+ST2
    size_t oGS = oST + 4096;              // int [513] -> pad 2064
    size_t oPART = oGS + 2064;            // f32 [3136*512] partials (6.4 MB)

    float* P = (float*)(ws + oP);
    bf16_t* QB = (bf16_t*)(ws + oQB);
    float4* SattrP = (float4*)(ws + oSattrP);
    int* SM = (int*)(ws + oSM);
    int* RS = (int*)(ws + oRS);
    int* CNT = (int*)(ws + oCNT);
    int* CUR = (int*)(ws + oCUR);
    int* LP = (int*)(ws + oLP);
    int* BS = (int*)(ws + oBS);
    int* BX = (int*)(ws + oBX);
    bf16_t* TYB = (bf16_t*)(ws + oTY);
    float* WC1 = (float*)(ws + oWC1);
    float* WC2 = (float*)(ws + oWC2);
    float* CB2 = (float*)(ws + oCB2);
    bf16_t* W2B = (bf16_t*)(ws + oW2B);
    float* ST1 = (float*)(ws + oST);
    float* ST2 = ST1 + 512;
    int* GS = (int*)(ws + oGS);
    float* PART = (float*)(ws + oPART);

    hipMemsetAsync(CNT, 0, NN * sizeof(int), stream);
    hipMemsetAsync(ST1, 0, 4096, stream);  // zeroes ST1 and ST2

    gme_setup<<<117, 256, 0, stream>>>(emb, c1lw, c1l2w, c1l2b, c1lb,
                                       c2lw, c2l2w, c2l2b, c2lb,
                                       TYB, WC1, WC2, CB2, W2B);
    gme_count<<<NE / 256, 256, 0, stream>>>(edge_index, CNT);
    gme_scan1<<<256, 256, 0, stream>>>(CNT, LP, BS);
    gme_scan2<<<1, 256, 0, stream>>>(BS, BX, RS);
    gme_scan3<<<256, 256, 0, stream>>>(LP, BX, RS, CUR);
    gme_scatter<<<NE / 256, 256, 0, stream>>>(edge_index, edge_attr, node_ids,
                                              CUR, SM, SattrP);
    gme_gstart<<<(NN + 255) / 256, 256, 0, stream>>>(batch, GS);
    // conv1: bf16 TY in LDS, 16-deep pipeline, BN1 stats fused -> PART
    gme_conv0<<<NN / 16, 256, 0, stream>>>(RS, SM, SattrP, TYB, WC1, P, PART);
    gme_bns2b<<<98, 512, 0, stream>>>(PART, ST1);
    gme_gemm<<<(NN / 16 + 3) / 4, 256, 0, stream>>>(P, ST1, bn1w, bn1b, W2B, CB2, QB);
    // conv2: rows from bf16 y2 table (CB2 folded), attr sequential
    gme_conv1<<<NN / 4, 256, 0, stream>>>(RS, SM, SattrP, QB, WC2, P);
    gme_bns1<<<512, 256, 0, stream>>>(P, PART);
    gme_bns2<<<16, 512, 0, stream>>>(PART, ST2);
    gme_attn<<<NG, 256, 0, stream>>>(GS, P, ST2, bn2w, bn2b, gate_w, gate_b,
                                     (float*)d_out);
}

// Round 9
// 404.953 us; speedup vs baseline: 1.0665x; 1.0665x over previous
//
#include <hip/hip_runtime.h>
#include <hip/hip_bf16.h>

#define NN 50000
#define NE 800000
#define NG 512

typedef __bf16 bf16_t;
typedef __bf16 bf16x8 __attribute__((ext_vector_type(8)));
typedef __bf16 bf16x4 __attribute__((ext_vector_type(4)));
typedef float f32x4 __attribute__((ext_vector_type(4)));
typedef float f32x2 __attribute__((ext_vector_type(2)));

__device__ __forceinline__ float lrelu(float v) { return v >= 0.f ? v : 0.01f * v; }

// unpack 2 bf16 (packed in one u32) -> float2 (pair order: lo, hi)
__device__ __forceinline__ f32x2 unpk2(unsigned w) {
    union { unsigned u; float f; } lo, hi;
    lo.u = w << 16;
    hi.u = w & 0xffff0000u;
    f32x2 r; r[0] = lo.f; r[1] = hi.f; return r;
}

// opaque per-lane zero: forces VGPR addressing (vmcnt path) for loads that the
// compiler would otherwise scalarize onto the s_load/lgkmcnt path.
__device__ __forceinline__ int vzero() {
    int vz;
    asm("v_mov_b32 %0, 0" : "=v"(vz));
    return vz;
}

// ---------------- tiny precomputes ----------------
// TYB[b][t] = bf16( sum_k (emb[b][k]+c1l2b[k]) * W1[t][k] + c1lb[t] )
// WC1[t][c] = sum_k W1[t][k] * c1l2w[k][c]
// WC2[t][c] = sum_k W2[t][k] * c2l2w[k][c];  CB2[t] = sum_k W2[t][k]*c2l2b[k] + c2lb[t]
__global__ void gme_setup(const float* __restrict__ emb,
                          const float* __restrict__ c1lw, const float* __restrict__ c1l2w,
                          const float* __restrict__ c1l2b, const float* __restrict__ c1lb,
                          const float* __restrict__ c2lw, const float* __restrict__ c2l2w,
                          const float* __restrict__ c2l2b, const float* __restrict__ c2lb,
                          bf16_t* __restrict__ TYB, float* __restrict__ WC1,
                          float* __restrict__ WC2, float* __restrict__ CB2,
                          bf16_t* __restrict__ W2B) {
    int b = blockIdx.x, t = threadIdx.x;
    if (b < 51) {
        const float4* er = (const float4*)(emb + b * 128);
        const float4* zb = (const float4*)c1l2b;
        const float4* wr = (const float4*)(c1lw + t * 128);
        float s = 0.f;
        for (int k = 0; k < 32; ++k) {
            float4 e = er[k], z = zb[k], w = wr[k];
            s += (e.x + z.x) * w.x + (e.y + z.y) * w.y + (e.z + z.z) * w.z + (e.w + z.w) * w.w;
        }
        TYB[b * 256 + t] = (bf16_t)(s + c1lb[t]);
    } else if (b == 51) {
        const float4* wr = (const float4*)(c1lw + t * 128);
        const float4* cw = (const float4*)c1l2w;
        float4 a = make_float4(0.f, 0.f, 0.f, 0.f);
        for (int k = 0; k < 32; ++k) {
            float4 w = wr[k];
            float4 c0 = cw[k * 4 + 0], c1 = cw[k * 4 + 1], c2 = cw[k * 4 + 2], c3 = cw[k * 4 + 3];
            a.x += w.x * c0.x + w.y * c1.x + w.z * c2.x + w.w * c3.x;
            a.y += w.x * c0.y + w.y * c1.y + w.z * c2.y + w.w * c3.y;
            a.z += w.x * c0.z + w.y * c1.z + w.z * c2.z + w.w * c3.z;
            a.w += w.x * c0.w + w.y * c1.w + w.z * c2.w + w.w * c3.w;
        }
        ((float4*)WC1)[t] = a;
    } else if (b == 52) {
        const float4* wr = (const float4*)(c2lw + t * 256);
        const float4* cw = (const float4*)c2l2w;
        const float4* zb = (const float4*)c2l2b;
        float4 a = make_float4(0.f, 0.f, 0.f, 0.f);
        float ab = 0.f;
        for (int k = 0; k < 64; ++k) {
            float4 w = wr[k];
            float4 c0 = cw[k * 4 + 0], c1 = cw[k * 4 + 1], c2 = cw[k * 4 + 2], c3 = cw[k * 4 + 3];
            float4 z = zb[k];
            a.x += w.x * c0.x + w.y * c1.x + w.z * c2.x + w.w * c3.x;
            a.y += w.x * c0.y + w.y * c1.y + w.z * c2.y + w.w * c3.y;
            a.z += w.x * c0.z + w.y * c1.z + w.z * c2.z + w.w * c3.z;
            a.w += w.x * c0.w + w.y * c1.w + w.z * c2.w + w.w * c3.w;
            ab += w.x * z.x + w.y * z.y + w.z * z.z + w.w * z.w;
        }
        ((float4*)WC2)[t] = a;
        CB2[t] = ab + c2lb[t];
    } else {
        int i0 = (b - 53) * 1024;
        for (int r = 0; r < 4; ++r) {
            int i = i0 + r * 256 + t;
            W2B[i] = (bf16_t)c2lw[i];
        }
    }
}

// ---------------- CSR build ----------------
__global__ void gme_count(const int* __restrict__ ei, int* __restrict__ cnt) {
    int e = blockIdx.x * 256 + threadIdx.x;
    if (e >= NE) return;
    atomicAdd(&cnt[ei[NE + e]], 1);
}

__global__ void gme_scan1(const int* __restrict__ CNT, int* __restrict__ LP,
                          int* __restrict__ BS) {
    __shared__ int lds[256];
    int b = blockIdx.x, t = threadIdx.x;
    int i = b * 196 + t;
    int v = (t < 196 && i < NN) ? CNT[i] : 0;
    lds[t] = v;
    __syncthreads();
    for (int off = 1; off < 256; off <<= 1) {
        int u = (t >= off) ? lds[t - off] : 0;
        __syncthreads();
        lds[t] += u;
        __syncthreads();
    }
    if (t < 196 && i < NN) LP[i] = lds[t] - v;
    if (t == 255) BS[b] = lds[255];
}

__global__ void gme_scan2(const int* __restrict__ BS, int* __restrict__ BX,
                          int* __restrict__ RS) {
    __shared__ int lds[256];
    int t = threadIdx.x;
    int v = BS[t];
    lds[t] = v;
    __syncthreads();
    for (int off = 1; off < 256; off <<= 1) {
        int u = (t >= off) ? lds[t - off] : 0;
        __syncthreads();
        lds[t] += u;
        __syncthreads();
    }
    BX[t] = lds[t] - v;
    if (t == 255) RS[NN] = lds[255];
}

__global__ void gme_scan3(const int* __restrict__ LP, const int* __restrict__ BX,
                          int* __restrict__ RS, int* __restrict__ CUR) {
    int b = blockIdx.x, t = threadIdx.x;
    if (t >= 196) return;
    int i = b * 196 + t;
    if (i >= NN) return;
    int v = BX[b] + LP[i];
    RS[i] = v;
    CUR[i] = v;
}

// single 16B record per edge: {src|nid<<16, attr.xy bf16x2, attr.zw bf16x2, 0}
__global__ void gme_scatter(const int* __restrict__ ei,
                            const float4* __restrict__ eattr,
                            const int* __restrict__ node_ids,
                            int* __restrict__ CUR, uint4* __restrict__ SE) {
    int e = blockIdx.x * 256 + threadIdx.x;
    if (e >= NE) return;
    int s = ei[e];
    int d = ei[NE + e];
    int nid = node_ids[s];
    float4 at = eattr[e];
    union { bf16_t h[2]; unsigned u; } p01, p23;
    p01.h[0] = (bf16_t)at.x; p01.h[1] = (bf16_t)at.y;
    p23.h[0] = (bf16_t)at.z; p23.h[1] = (bf16_t)at.w;
    int pos = atomicAdd(&CUR[d], 1);
    SE[pos] = make_uint4((unsigned)(s | (nid << 16)), p01.u, p23.u, 0u);
}

// ---------------- conv1 layer: bf16 TY table in LDS; single SE stream -------
__global__ __launch_bounds__(256) void gme_conv0(
        const int* __restrict__ RS, const uint4* __restrict__ SE,
        const bf16_t* __restrict__ TYB, const float* __restrict__ Wc,
        float* __restrict__ agg) {
    __shared__ __align__(16) uint2 sTY[51 * 64];  // 26112 B bf16 table
    {
        const uint4* s4 = (const uint4*)TYB;
        uint4* d4 = (uint4*)sTY;
        for (int i = threadIdx.x; i < 51 * 32; i += 256) d4[i] = s4[i];
    }
    __syncthreads();
    int lane = threadIdx.x & 63;
    int vz = vzero();
    const float4* wc4 = (const float4*)Wc;
    int c4 = lane * 4;
    float4 w0 = wc4[c4 + 0], w1 = wc4[c4 + 1], w2 = wc4[c4 + 2], w3 = wc4[c4 + 3];
    f32x2 wA0 = {w0.x, w1.x}, wB0 = {w0.y, w1.y}, wC0 = {w0.z, w1.z}, wD0 = {w0.w, w1.w};
    f32x2 wA1 = {w2.x, w3.x}, wB1 = {w2.y, w3.y}, wC1 = {w2.z, w3.z}, wD1 = {w2.w, w3.w};
    const f32x2 zero = {0.f, 0.f};
    const uint2* lrow = sTY + lane;
    int base = blockIdx.x * 16 + (threadIdx.x >> 6) * 4;
#pragma unroll 1
    for (int k = 0; k < 4; ++k) {
        int node = __builtin_amdgcn_readfirstlane(base + k);
        int rs = RS[node], re = RS[node + 1];
        f32x2 accP0 = zero, accP1 = zero, accA0 = zero, accA1 = zero;
        auto accum = [&](uint4 se, uint2 r) {
            f32x2 y0 = unpk2(r.x), y1 = unpk2(r.y);
            f32x2 axy = unpk2(se.y), azw = unpk2(se.z);
            f32x2 ax = {axy[0], axy[0]}, ay = {axy[1], axy[1]};
            f32x2 az = {azw[0], azw[0]}, aw = {azw[1], azw[1]};
            f32x2 m0 = __builtin_elementwise_fma(ax, wA0, y0);
            f32x2 m1 = __builtin_elementwise_fma(ax, wA1, y1);
            m0 = __builtin_elementwise_fma(ay, wB0, m0);
            m1 = __builtin_elementwise_fma(ay, wB1, m1);
            m0 = __builtin_elementwise_fma(az, wC0, m0);
            m1 = __builtin_elementwise_fma(az, wC1, m1);
            m0 = __builtin_elementwise_fma(aw, wD0, m0);
            m1 = __builtin_elementwise_fma(aw, wD1, m1);
            accA0 += m0; accA1 += m1;
            accP0 += __builtin_elementwise_max(m0, zero);
            accP1 += __builtin_elementwise_max(m1, zero);
        };
        int j = rs;
        for (; j + 8 <= re; j += 8) {
            uint4 se[8]; uint2 r[8];
#pragma unroll
            for (int u = 0; u < 8; ++u) se[u] = SE[j + u + vz];
#pragma unroll
            for (int u = 0; u < 8; ++u) r[u] = lrow[(se[u].x >> 16) << 6];
#pragma unroll
            for (int u = 0; u < 8; ++u) accum(se[u], r[u]);
        }
        if (j + 4 <= re) {
            uint4 se[4]; uint2 r[4];
#pragma unroll
            for (int u = 0; u < 4; ++u) se[u] = SE[j + u + vz];
#pragma unroll
            for (int u = 0; u < 4; ++u) r[u] = lrow[(se[u].x >> 16) << 6];
#pragma unroll
            for (int u = 0; u < 4; ++u) accum(se[u], r[u]);
            j += 4;
        }
        for (; j < re; ++j) {
            uint4 se = SE[j + vz];
            accum(se, lrow[(se.x >> 16) << 6]);
        }
        const f32x2 c99 = {0.99f, 0.99f}, c01 = {0.01f, 0.01f};
        f32x2 o0 = __builtin_elementwise_fma(accP0, c99, accA0 * c01);
        f32x2 o1 = __builtin_elementwise_fma(accP1, c99, accA1 * c01);
        *((float4*)(agg + node * 256) + lane) = make_float4(o0[0], o0[1], o1[0], o1[1]);
    }
}

// ---------------- conv2 layer: random gather from 25.6 MB bf16 table ---------
__global__ __launch_bounds__(256, 4) void gme_conv1(
        const int* __restrict__ RS, const uint4* __restrict__ SE,
        const bf16_t* __restrict__ QB, const float* __restrict__ Wc,
        float* __restrict__ agg) {
    int lane = threadIdx.x & 63;
    int node = __builtin_amdgcn_readfirstlane(blockIdx.x * 4 + (threadIdx.x >> 6));
    if (node >= NN) return;
    const float4* wc4 = (const float4*)Wc;
    int c4 = lane * 4;
    float4 w0 = wc4[c4 + 0], w1 = wc4[c4 + 1], w2 = wc4[c4 + 2], w3 = wc4[c4 + 3];
    f32x2 wA0 = {w0.x, w1.x}, wB0 = {w0.y, w1.y}, wC0 = {w0.z, w1.z}, wD0 = {w0.w, w1.w};
    f32x2 wA1 = {w2.x, w3.x}, wB1 = {w2.y, w3.y}, wC1 = {w2.z, w3.z}, wD1 = {w2.w, w3.w};
    const f32x2 zero = {0.f, 0.f};
    f32x2 accP0 = zero, accP1 = zero, accA0 = zero, accA1 = zero;
    int rs = RS[node], re = RS[node + 1];
    const char* yb = (const char*)QB;
    unsigned loff = (unsigned)(lane << 3);
    auto rowld = [&](unsigned row) -> uint2 {
        return *(const uint2*)(yb + (row << 9) + loff);
    };
    auto accum = [&](uint4 se, uint2 r) {
        f32x2 y0 = unpk2(r.x), y1 = unpk2(r.y);
        f32x2 axy = unpk2(se.y), azw = unpk2(se.z);
        f32x2 ax = {axy[0], axy[0]}, ay = {axy[1], axy[1]};
        f32x2 az = {azw[0], azw[0]}, aw = {azw[1], azw[1]};
        f32x2 m0 = __builtin_elementwise_fma(ax, wA0, y0);
        f32x2 m1 = __builtin_elementwise_fma(ax, wA1, y1);
        m0 = __builtin_elementwise_fma(ay, wB0, m0);
        m1 = __builtin_elementwise_fma(ay, wB1, m1);
        m0 = __builtin_elementwise_fma(az, wC0, m0);
        m1 = __builtin_elementwise_fma(az, wC1, m1);
        m0 = __builtin_elementwise_fma(aw, wD0, m0);
        m1 = __builtin_elementwise_fma(aw, wD1, m1);
        accA0 += m0; accA1 += m1;
        accP0 += __builtin_elementwise_max(m0, zero);
        accP1 += __builtin_elementwise_max(m1, zero);
    };
    int j = rs;
    for (; j + 12 <= re; j += 12) {
        uint4 se[12]; uint2 r[12];
#pragma unroll
        for (int u = 0; u < 12; ++u) se[u] = SE[j + u];
#pragma unroll
        for (int u = 0; u < 12; ++u) r[u] = rowld(se[u].x & 0xffffu);
#pragma unroll
        for (int u = 0; u < 12; ++u) accum(se[u], r[u]);
    }
    if (j + 8 <= re) {
        uint4 se[8]; uint2 r[8];
#pragma unroll
        for (int u = 0; u < 8; ++u) se[u] = SE[j + u];
#pragma unroll
        for (int u = 0; u < 8; ++u) r[u] = rowld(se[u].x & 0xffffu);
#pragma unroll
        for (int u = 0; u < 8; ++u) accum(se[u], r[u]);
        j += 8;
    }
    if (j + 4 <= re) {
        uint4 se[4]; uint2 r[4];
#pragma unroll
        for (int u = 0; u < 4; ++u) se[u] = SE[j + u];
#pragma unroll
        for (int u = 0; u < 4; ++u) r[u] = rowld(se[u].x & 0xffffu);
#pragma unroll
        for (int u = 0; u < 4; ++u) accum(se[u], r[u]);
        j += 4;
    }
    for (; j < re; ++j) {
        uint4 se = SE[j];
        accum(se, rowld(se.x & 0xffffu));
    }
    const f32x2 c99 = {0.99f, 0.99f}, c01 = {0.01f, 0.01f};
    f32x2 o0 = __builtin_elementwise_fma(accP0, c99, accA0 * c01);
    f32x2 o1 = __builtin_elementwise_fma(accP1, c99, accA1 * c01);
    *((float4*)(agg + node * 256) + lane) = make_float4(o0[0], o0[1], o1[0], o1[1]);
}

// ---------------- BN stats: two-stage, atomic stage2 ----------------
__global__ __launch_bounds__(256) void gme_bns1(const float* __restrict__ P,
                                                float* __restrict__ PART) {
    __shared__ float ls[4][256], lq[4][256];
    int lane = threadIdx.x & 63;
    int w = threadIdx.x >> 6;
    int b = blockIdx.x;
    int r0 = b * 98;
    int r1 = r0 + 98; if (r1 > NN) r1 = NN;
    float4 s = make_float4(0, 0, 0, 0), q = make_float4(0, 0, 0, 0);
    for (int n = r0 + w; n < r1; n += 4) {
        float4 v = ((const float4*)P)[n * 64 + lane];
        s.x += v.x; s.y += v.y; s.z += v.z; s.w += v.w;
        q.x += v.x * v.x; q.y += v.y * v.y; q.z += v.z * v.z; q.w += v.w * v.w;
    }
    int c = lane * 4;
    ls[w][c] = s.x; ls[w][c + 1] = s.y; ls[w][c + 2] = s.z; ls[w][c + 3] = s.w;
    lq[w][c] = q.x; lq[w][c + 1] = q.y; lq[w][c + 2] = q.z; lq[w][c + 3] = q.w;
    __syncthreads();
    if (w == 0) {
#pragma unroll
        for (int k = 0; k < 4; ++k) {
            int cc = c + k;
            PART[b * 512 + cc] = ls[0][cc] + ls[1][cc] + ls[2][cc] + ls[3][cc];
            PART[b * 512 + 256 + cc] = lq[0][cc] + lq[1][cc] + lq[2][cc] + lq[3][cc];
        }
    }
}

// stage 2: 16 blocks x 512 threads, 32 rows each, atomicAdd into zeroed ST.
__global__ __launch_bounds__(512) void gme_bns2(const float* __restrict__ PART,
                                                float* __restrict__ ST) {
    int t = threadIdx.x;
    int b = blockIdx.x;
    float acc = 0.f;
#pragma unroll
    for (int r = 0; r < 32; ++r) acc += PART[(b * 32 + r) * 512 + t];
    atomicAdd(&ST[t], acc);
}

// ---------------- GEMM, BN1+LeakyReLU fused on A; CB2 folded into output -----
// W2B staged in LDS (128 KB, slot-XOR swizzle -> conflict-free ds_read_b128).
__global__ __launch_bounds__(256) void gme_gemm(const float* __restrict__ P,
                                                const float* __restrict__ ST,
                                                const float* __restrict__ bw,
                                                const float* __restrict__ bb,
                                                const bf16_t* __restrict__ W2B,
                                                const float* __restrict__ CB2,
                                                bf16_t* __restrict__ QB) {
    __shared__ float s_sc[256], s_sh[256];
    __shared__ __align__(16) uint4 sB[8192];  // 128 KB, 16B-slot swizzled
    {
        int c = threadIdx.x;
        float mean = ST[c] * (1.f / NN);
        float var = ST[256 + c] * (1.f / NN) - mean * mean;
        float sc = bw[c] * rsqrtf(var + 1e-5f);
        s_sc[c] = sc;
        s_sh[c] = bb[c] - mean * sc;
        const uint4* w4 = (const uint4*)W2B;
#pragma unroll
        for (int it = 0; it < 32; ++it) {
            int i = it * 256 + c;
            int row = i >> 5, slot = i & 31;
            sB[(row << 5) | (slot ^ (row & 7))] = w4[i];
        }
    }
    __syncthreads();
    int lane = threadIdx.x & 63;
    int wave = blockIdx.x * 4 + (threadIdx.x >> 6);
    if (wave >= NN / 16) return;
    int m0 = wave * 16;
    int r = lane & 15, q = lane >> 4;
    int rx = r & 7;
    const float* arow = P + (m0 + r) * 256 + q * 8;
    bf16x8 a[8];
#pragma unroll
    for (int kt = 0; kt < 8; ++kt) {
        int k0 = kt * 32 + q * 8;
        float4 u0 = *(const float4*)(arow + kt * 32);
        float4 u1 = *(const float4*)(arow + kt * 32 + 4);
        bf16x8 f;
        f[0] = (bf16_t)lrelu(fmaf(u0.x, s_sc[k0 + 0], s_sh[k0 + 0]));
        f[1] = (bf16_t)lrelu(fmaf(u0.y, s_sc[k0 + 1], s_sh[k0 + 1]));
        f[2] = (bf16_t)lrelu(fmaf(u0.z, s_sc[k0 + 2], s_sh[k0 + 2]));
        f[3] = (bf16_t)lrelu(fmaf(u0.w, s_sc[k0 + 3], s_sh[k0 + 3]));
        f[4] = (bf16_t)lrelu(fmaf(u1.x, s_sc[k0 + 4], s_sh[k0 + 4]));
        f[5] = (bf16_t)lrelu(fmaf(u1.y, s_sc[k0 + 5], s_sh[k0 + 5]));
        f[6] = (bf16_t)lrelu(fmaf(u1.z, s_sc[k0 + 6], s_sh[k0 + 6]));
        f[7] = (bf16_t)lrelu(fmaf(u1.w, s_sc[k0 + 7], s_sh[k0 + 7]));
        a[kt] = f;
    }
#pragma unroll 1
    for (int g = 0; g < 2; ++g) {
        f32x4 acc[8];
#pragma unroll
        for (int n8 = 0; n8 < 8; ++n8) acc[n8] = (f32x4){0.f, 0.f, 0.f, 0.f};
#pragma unroll
        for (int kt = 0; kt < 8; ++kt) {
            int slot = (kt * 4 + q) ^ rx;
            bf16x8 bf[8];
#pragma unroll
            for (int n8 = 0; n8 < 8; ++n8) {
                int row = g * 128 + n8 * 16 + r;
                bf[n8] = *(const bf16x8*)&sB[(row << 5) | slot];
            }
#pragma unroll
            for (int n8 = 0; n8 < 8; ++n8) {
                acc[n8] = __builtin_amdgcn_mfma_f32_16x16x32_bf16(bf[n8], a[kt], acc[n8], 0, 0, 0);
            }
        }
#pragma unroll
        for (int n8 = 0; n8 < 8; ++n8) {
            int nt = g * 8 + n8;
            float4 cbv = ((const float4*)CB2)[nt * 4 + q];
            bf16x4 o;
            o[0] = (bf16_t)(acc[n8][0] + cbv.x);
            o[1] = (bf16_t)(acc[n8][1] + cbv.y);
            o[2] = (bf16_t)(acc[n8][2] + cbv.z);
            o[3] = (bf16_t)(acc[n8][3] + cbv.w);
            *(bf16x4*)(QB + (m0 + r) * 256 + nt * 16 + q * 4) = o;
        }
    }
}

// ---------------- graph segment boundaries ----------------
__global__ void gme_gstart(const int* __restrict__ batch, int* __restrict__ GS) {
    int n = blockIdx.x * 256 + threadIdx.x;
    if (n >= NN) return;
    int b = batch[n];
    if (n == 0) {
        for (int g = 0; g <= b; ++g) GS[g] = 0;
    } else {
        int a = batch[n - 1];
        for (int g = a + 1; g <= b; ++g) GS[g] = n;
    }
    if (n == NN - 1) {
        for (int g = b + 1; g <= NG; ++g) GS[g] = NN;
    }
}

// ---------------- fused gate + attentional aggregation (BN2+lrelu inline) ----
__global__ __launch_bounds__(256) void gme_attn(const int* __restrict__ GS,
                                                const float* __restrict__ P,
                                                const float* __restrict__ ST,
                                                const float* __restrict__ bw,
                                                const float* __restrict__ bb,
                                                const float* __restrict__ gw,
                                                const float* __restrict__ gb,
                                                float* __restrict__ out) {
    __shared__ float gl[1024];
    __shared__ float rr[8];
    int g = blockIdx.x, t = threadIdx.x;
    int lo = GS[g], hi = GS[g + 1];
    if (lo >= hi) { out[g * 256 + t] = 0.f; return; }
    int lane = t & 63, w = t >> 6;
    // phase A: per-node gates, wave-parallel (wave w -> nodes lo+w, step 4)
    {
        float4 s4 = ((const float4*)ST)[lane];
        float4 q4 = ((const float4*)(ST + 256))[lane];
        float4 w4 = ((const float4*)bw)[lane];
        float4 b4 = ((const float4*)bb)[lane];
        float4 g4 = ((const float4*)gw)[lane];
        float m0 = s4.x * (1.f / NN), m1 = s4.y * (1.f / NN);
        float m2 = s4.z * (1.f / NN), m3 = s4.w * (1.f / NN);
        float sc0 = w4.x * rsqrtf(q4.x * (1.f / NN) - m0 * m0 + 1e-5f);
        float sc1 = w4.y * rsqrtf(q4.y * (1.f / NN) - m1 * m1 + 1e-5f);
        float sc2 = w4.z * rsqrtf(q4.z * (1.f / NN) - m2 * m2 + 1e-5f);
        float sc3 = w4.w * rsqrtf(q4.w * (1.f / NN) - m3 * m3 + 1e-5f);
        float sh0 = b4.x - m0 * sc0, sh1 = b4.y - m1 * sc1;
        float sh2 = b4.z - m2 * sc2, sh3 = b4.w - m3 * sc3;
        float gb0 = gb[0];
        for (int n = lo + w; n < hi; n += 4) {
            float4 p = *(const float4*)(P + n * 256 + lane * 4);
            float d = lrelu(fmaf(p.x, sc0, sh0)) * g4.x
                    + lrelu(fmaf(p.y, sc1, sh1)) * g4.y
                    + lrelu(fmaf(p.z, sc2, sh2)) * g4.z
                    + lrelu(fmaf(p.w, sc3, sh3)) * g4.w;
#pragma unroll
            for (int off = 32; off > 0; off >>= 1) d += __shfl_xor(d, off, 64);
            if (lane == 0) gl[n - lo] = d + gb0;
        }
    }
    __syncthreads();
    // phase B: softmax max + denom over gl[0..cnt)
    int cnt = hi - lo;
    float lm = -3.0e38f;
    for (int i = t; i < cnt; i += 256) lm = fmaxf(lm, gl[i]);
#pragma unroll
    for (int off = 32; off > 0; off >>= 1) lm = fmaxf(lm, __shfl_xor(lm, off, 64));
    if (lane == 0) rr[w] = lm;
    __syncthreads();
    float mx = fmaxf(fmaxf(rr[0], rr[1]), fmaxf(rr[2], rr[3]));
    float ls = 0.f;
    for (int i = t; i < cnt; i += 256) { float e = expf(gl[i] - mx); gl[i] = e; ls += e; }
#pragma unroll
    for (int off = 32; off > 0; off >>= 1) ls += __shfl_xor(ls, off, 64);
    if (lane == 0) rr[4 + w] = ls;
    __syncthreads();
    float sinv = 1.f / (rr[4] + rr[5] + rr[6] + rr[7]);
    // phase C: weighted accumulate, thread t = channel t (P slice is L2-hot)
    float mean = ST[t] * (1.f / NN);
    float var = ST[256 + t] * (1.f / NN) - mean * mean;
    float sc = bw[t] * rsqrtf(var + 1e-5f);
    float sh = bb[t] - mean * sc;
    float a0 = 0.f, a1 = 0.f, a2 = 0.f, a3 = 0.f;
    int n = lo;
    for (; n + 4 <= hi; n += 4) {
        float p0 = P[n * 256 + t], p1 = P[(n + 1) * 256 + t];
        float p2 = P[(n + 2) * 256 + t], p3 = P[(n + 3) * 256 + t];
        a0 = fmaf(gl[n - lo + 0], lrelu(fmaf(p0, sc, sh)), a0);
        a1 = fmaf(gl[n - lo + 1], lrelu(fmaf(p1, sc, sh)), a1);
        a2 = fmaf(gl[n - lo + 2], lrelu(fmaf(p2, sc, sh)), a2);
        a3 = fmaf(gl[n - lo + 3], lrelu(fmaf(p3, sc, sh)), a3);
    }
    for (; n < hi; ++n) a0 = fmaf(gl[n - lo], lrelu(fmaf(P[n * 256 + t], sc, sh)), a0);
    out[g * 256 + t] = (a0 + a1 + a2 + a3) * sinv;
}

extern "C" void kernel_launch(void* const* d_in, const int* in_sizes, int n_in,
                              void* d_out, int out_size, void* d_ws, size_t ws_size,
                              hipStream_t stream) {
    const int* node_ids = (const int*)d_in[0];
    const int* edge_index = (const int*)d_in[1];
    const float4* edge_attr = (const float4*)d_in[2];
    const int* batch = (const int*)d_in[3];
    const float* emb = (const float*)d_in[4];
    const float* c1l2w = (const float*)d_in[5];
    const float* c1l2b = (const float*)d_in[6];
    const float* c1lw = (const float*)d_in[7];
    const float* c1lb = (const float*)d_in[8];
    const float* bn1w = (const float*)d_in[9];
    const float* bn1b = (const float*)d_in[10];
    const float* c2l2w = (const float*)d_in[11];
    const float* c2l2b = (const float*)d_in[12];
    const float* c2lw = (const float*)d_in[13];
    const float* c2lb = (const float*)d_in[14];
    const float* bn2w = (const float*)d_in[15];
    const float* bn2b = (const float*)d_in[16];
    const float* gate_w = (const float*)d_in[17];
    const float* gate_b = (const float*)d_in[18];

    char* ws = (char*)d_ws;
    size_t oP = 0;                        // f32 [50000,256]
    size_t oQB = oP + 51200000;           // bf16 [50000,256]
    size_t oSE = oQB + 25600000;          // uint4 [800000] packed edge records
    size_t oRS = oSE + 12800000;          // int [50001]
    size_t oCNT = oRS + 200064;           // int [50000]
    size_t oCUR = oCNT + 200000;          // int [50000]
    size_t oLP = oCUR + 200000;           // int [50000]
    size_t oBS = oLP + 200000;            // int [256]
    size_t oBX = oBS + 1024;              // int [256]
    size_t oTY = oBX + 1024;              // bf16 [51,256]
    size_t oWC1 = oTY + 52224;            // f32 [256,4]
    size_t oWC2 = oWC1 + 4096;            // f32 [256,4]
    size_t oCB2 = oWC2 + 4096;            // f32 [256]
    size_t oW2B = oCB2 + 1024;            // bf16 [256,256]
    size_t oST = oW2B + 131072;           // f32 [1024]: ST1+ST2
    size_t oGS = oST + 4096;              // int [513] -> pad 2064
    size_t oPART = oGS + 2064;            // f32 [512*512] partials (1 MB)

    float* P = (float*)(ws + oP);
    bf16_t* QB = (bf16_t*)(ws + oQB);
    uint4* SE = (uint4*)(ws + oSE);
    int* RS = (int*)(ws + oRS);
    int* CNT = (int*)(ws + oCNT);
    int* CUR = (int*)(ws + oCUR);
    int* LP = (int*)(ws + oLP);
    int* BS = (int*)(ws + oBS);
    int* BX = (int*)(ws + oBX);
    bf16_t* TYB = (bf16_t*)(ws + oTY);
    float* WC1 = (float*)(ws + oWC1);
    float* WC2 = (float*)(ws + oWC2);
    float* CB2 = (float*)(ws + oCB2);
    bf16_t* W2B = (bf16_t*)(ws + oW2B);
    float* ST1 = (float*)(ws + oST);
    float* ST2 = ST1 + 512;
    int* GS = (int*)(ws + oGS);
    float* PART = (float*)(ws + oPART);

    hipMemsetAsync(CNT, 0, NN * sizeof(int), stream);
    hipMemsetAsync(ST1, 0, 4096, stream);  // zeroes ST1 and ST2

    gme_setup<<<117, 256, 0, stream>>>(emb, c1lw, c1l2w, c1l2b, c1lb,
                                       c2lw, c2l2w, c2l2b, c2lb,
                                       TYB, WC1, WC2, CB2, W2B);
    gme_count<<<NE / 256, 256, 0, stream>>>(edge_index, CNT);
    gme_scan1<<<256, 256, 0, stream>>>(CNT, LP, BS);
    gme_scan2<<<1, 256, 0, stream>>>(BS, BX, RS);
    gme_scan3<<<256, 256, 0, stream>>>(LP, BX, RS, CUR);
    gme_scatter<<<NE / 256, 256, 0, stream>>>(edge_index, edge_attr, node_ids,
                                              CUR, SE);
    gme_gstart<<<(NN + 255) / 256, 256, 0, stream>>>(batch, GS);
    // conv1: bf16 TY table staged in LDS, single packed SE stream
    gme_conv0<<<NN / 16, 256, 0, stream>>>(RS, SE, TYB, WC1, P);
    gme_bns1<<<512, 256, 0, stream>>>(P, PART);
    gme_bns2<<<16, 512, 0, stream>>>(PART, ST1);
    gme_gemm<<<(NN / 16 + 3) / 4, 256, 0, stream>>>(P, ST1, bn1w, bn1b, W2B, CB2, QB);
    // conv2: rows from bf16 y2 table (CB2 folded), single packed SE stream
    gme_conv1<<<NN / 4, 256, 0, stream>>>(RS, SE, QB, WC2, P);
    gme_bns1<<<512, 256, 0, stream>>>(P, PART);
    gme_bns2<<<16, 512, 0, stream>>>(PART, ST2);
    gme_attn<<<NG, 256, 0, stream>>>(GS, P, ST2, bn2w, bn2b, gate_w, gate_b,
                                     (float*)d_out);
}

// Round 10
// 389.494 us; speedup vs baseline: 1.1089x; 1.0397x over previous
//
#include <hip/hip_runtime.h>
#include <hip/hip_bf16.h>

#define NN 50000
#define NE 800000
#define NG 512

typedef __bf16 bf16_t;
typedef __bf16 bf16x8 __attribute__((ext_vector_type(8)));
typedef __bf16 bf16x4 __attribute__((ext_vector_type(4)));
typedef float f32x4 __attribute__((ext_vector_type(4)));
typedef float f32x2 __attribute__((ext_vector_type(2)));

__device__ __forceinline__ float lrelu(float v) { return v >= 0.f ? v : 0.01f * v; }

// unpack 2 bf16 (packed in one u32) -> float2 (pair order: lo, hi)
__device__ __forceinline__ f32x2 unpk2(unsigned w) {
    union { unsigned u; float f; } lo, hi;
    lo.u = w << 16;
    hi.u = w & 0xffff0000u;
    f32x2 r; r[0] = lo.f; r[1] = hi.f; return r;
}

// opaque per-lane zero: forces VGPR addressing (vmcnt path) for loads that the
// compiler would otherwise scalarize onto the s_load/lgkmcnt path.
__device__ __forceinline__ int vzero() {
    int vz;
    asm("v_mov_b32 %0, 0" : "=v"(vz));
    return vz;
}

// ---------------- tiny precomputes + CNT zeroing ----------------
// TYB[b][t] = bf16( sum_k (emb[b][k]+c1l2b[k]) * W1[t][k] + c1lb[t] )
// WC1[t][c] = sum_k W1[t][k] * c1l2w[k][c]
// WC2[t][c] = sum_k W2[t][k] * c2l2w[k][c];  CB2[t] = sum_k W2[t][k]*c2l2b[k] + c2lb[t]
__global__ void gme_setup(const float* __restrict__ emb,
                          const float* __restrict__ c1lw, const float* __restrict__ c1l2w,
                          const float* __restrict__ c1l2b, const float* __restrict__ c1lb,
                          const float* __restrict__ c2lw, const float* __restrict__ c2l2w,
                          const float* __restrict__ c2l2b, const float* __restrict__ c2lb,
                          bf16_t* __restrict__ TYB, float* __restrict__ WC1,
                          float* __restrict__ WC2, float* __restrict__ CB2,
                          bf16_t* __restrict__ W2B, int* __restrict__ CNT) {
    int b = blockIdx.x, t = threadIdx.x;
    if (b < 51) {
        const float4* er = (const float4*)(emb + b * 128);
        const float4* zb = (const float4*)c1l2b;
        const float4* wr = (const float4*)(c1lw + t * 128);
        float s = 0.f;
        for (int k = 0; k < 32; ++k) {
            float4 e = er[k], z = zb[k], w = wr[k];
            s += (e.x + z.x) * w.x + (e.y + z.y) * w.y + (e.z + z.z) * w.z + (e.w + z.w) * w.w;
        }
        TYB[b * 256 + t] = (bf16_t)(s + c1lb[t]);
    } else if (b == 51) {
        const float4* wr = (const float4*)(c1lw + t * 128);
        const float4* cw = (const float4*)c1l2w;
        float4 a = make_float4(0.f, 0.f, 0.f, 0.f);
        for (int k = 0; k < 32; ++k) {
            float4 w = wr[k];
            float4 c0 = cw[k * 4 + 0], c1 = cw[k * 4 + 1], c2 = cw[k * 4 + 2], c3 = cw[k * 4 + 3];
            a.x += w.x * c0.x + w.y * c1.x + w.z * c2.x + w.w * c3.x;
            a.y += w.x * c0.y + w.y * c1.y + w.z * c2.y + w.w * c3.y;
            a.z += w.x * c0.z + w.y * c1.z + w.z * c2.z + w.w * c3.z;
            a.w += w.x * c0.w + w.y * c1.w + w.z * c2.w + w.w * c3.w;
        }
        ((float4*)WC1)[t] = a;
    } else if (b == 52) {
        const float4* wr = (const float4*)(c2lw + t * 256);
        const float4* cw = (const float4*)c2l2w;
        const float4* zb = (const float4*)c2l2b;
        float4 a = make_float4(0.f, 0.f, 0.f, 0.f);
        float ab = 0.f;
        for (int k = 0; k < 64; ++k) {
            float4 w = wr[k];
            float4 c0 = cw[k * 4 + 0], c1 = cw[k * 4 + 1], c2 = cw[k * 4 + 2], c3 = cw[k * 4 + 3];
            float4 z = zb[k];
            a.x += w.x * c0.x + w.y * c1.x + w.z * c2.x + w.w * c3.x;
            a.y += w.x * c0.y + w.y * c1.y + w.z * c2.y + w.w * c3.y;
            a.z += w.x * c0.z + w.y * c1.z + w.z * c2.z + w.w * c3.z;
            a.w += w.x * c0.w + w.y * c1.w + w.z * c2.w + w.w * c3.w;
            ab += w.x * z.x + w.y * z.y + w.z * z.z + w.w * z.w;
        }
        ((float4*)WC2)[t] = a;
        CB2[t] = ab + c2lb[t];
    } else if (b < 117) {
        int i0 = (b - 53) * 1024;
        for (int r = 0; r < 4; ++r) {
            int i = i0 + r * 256 + t;
            W2B[i] = (bf16_t)c2lw[i];
        }
    } else {
        int i = (b - 117) * 256 + t;
        if (i < NN) CNT[i] = 0;
    }
}

// ---------------- CSR build ----------------
__global__ void gme_count(const int* __restrict__ ei, int* __restrict__ cnt) {
    int e = blockIdx.x * 256 + threadIdx.x;
    if (e >= NE) return;
    atomicAdd(&cnt[ei[NE + e]], 1);
}

__global__ void gme_scan1(const int* __restrict__ CNT, int* __restrict__ LP,
                          int* __restrict__ BS) {
    __shared__ int lds[256];
    int b = blockIdx.x, t = threadIdx.x;
    int i = b * 196 + t;
    int v = (t < 196 && i < NN) ? CNT[i] : 0;
    lds[t] = v;
    __syncthreads();
    for (int off = 1; off < 256; off <<= 1) {
        int u = (t >= off) ? lds[t - off] : 0;
        __syncthreads();
        lds[t] += u;
        __syncthreads();
    }
    if (t < 196 && i < NN) LP[i] = lds[t] - v;
    if (t == 255) BS[b] = lds[255];
}

__global__ void gme_scan2(const int* __restrict__ BS, int* __restrict__ BX,
                          int* __restrict__ RS) {
    __shared__ int lds[256];
    int t = threadIdx.x;
    int v = BS[t];
    lds[t] = v;
    __syncthreads();
    for (int off = 1; off < 256; off <<= 1) {
        int u = (t >= off) ? lds[t - off] : 0;
        __syncthreads();
        lds[t] += u;
        __syncthreads();
    }
    BX[t] = lds[t] - v;
    if (t == 255) RS[NN] = lds[255];
}

// scan3 + graph-segment boundaries fused (same iteration space over nodes)
__global__ void gme_scan3(const int* __restrict__ LP, const int* __restrict__ BX,
                          int* __restrict__ RS, int* __restrict__ CUR,
                          const int* __restrict__ batch, int* __restrict__ GS) {
    int b = blockIdx.x, t = threadIdx.x;
    if (t >= 196) return;
    int i = b * 196 + t;
    if (i >= NN) return;
    int v = BX[b] + LP[i];
    RS[i] = v;
    CUR[i] = v;
    int bb = batch[i];
    if (i == 0) {
        for (int g = 0; g <= bb; ++g) GS[g] = 0;
    } else {
        int a = batch[i - 1];
        for (int g = a + 1; g <= bb; ++g) GS[g] = i;
    }
    if (i == NN - 1) {
        for (int g = bb + 1; g <= NG; ++g) GS[g] = NN;
    }
}

// single 16B record per edge: {src|nid<<16, attr.xy bf16x2, attr.zw bf16x2, 0}
__global__ void gme_scatter(const int* __restrict__ ei,
                            const float4* __restrict__ eattr,
                            const int* __restrict__ node_ids,
                            int* __restrict__ CUR, uint4* __restrict__ SE) {
    int e = blockIdx.x * 256 + threadIdx.x;
    if (e >= NE) return;
    int s = ei[e];
    int d = ei[NE + e];
    int nid = node_ids[s];
    float4 at = eattr[e];
    union { bf16_t h[2]; unsigned u; } p01, p23;
    p01.h[0] = (bf16_t)at.x; p01.h[1] = (bf16_t)at.y;
    p23.h[0] = (bf16_t)at.z; p23.h[1] = (bf16_t)at.w;
    int pos = atomicAdd(&CUR[d], 1);
    SE[pos] = make_uint4((unsigned)(s | (nid << 16)), p01.u, p23.u, 0u);
}

// ---------------- conv1 layer: bf16 TY in LDS; fused BN1 partial stats ------
__global__ __launch_bounds__(256) void gme_conv0(
        const int* __restrict__ RS, const uint4* __restrict__ SE,
        const bf16_t* __restrict__ TYB, const float* __restrict__ Wc,
        float* __restrict__ agg, float* __restrict__ PARTS) {
    __shared__ __align__(16) uint2 sTY[51 * 64];  // 26112 B bf16 table
    {
        const uint4* s4 = (const uint4*)TYB;
        uint4* d4 = (uint4*)sTY;
        for (int i = threadIdx.x; i < 51 * 32; i += 256) d4[i] = s4[i];
    }
    __syncthreads();
    int lane = threadIdx.x & 63;
    int w = threadIdx.x >> 6;
    int vz = vzero();
    const float4* wc4 = (const float4*)Wc;
    int c4 = lane * 4;
    float4 w0 = wc4[c4 + 0], w1 = wc4[c4 + 1], w2 = wc4[c4 + 2], w3 = wc4[c4 + 3];
    f32x2 wA0 = {w0.x, w1.x}, wB0 = {w0.y, w1.y}, wC0 = {w0.z, w1.z}, wD0 = {w0.w, w1.w};
    f32x2 wA1 = {w2.x, w3.x}, wB1 = {w2.y, w3.y}, wC1 = {w2.z, w3.z}, wD1 = {w2.w, w3.w};
    const f32x2 zero = {0.f, 0.f};
    const uint2* lrow = sTY + lane;
    int base = blockIdx.x * 16 + w * 4;
    f32x2 ssum0 = zero, ssum1 = zero, qsum0 = zero, qsum1 = zero;
#pragma unroll 1
    for (int k = 0; k < 4; ++k) {
        int node = __builtin_amdgcn_readfirstlane(base + k);
        int rs = RS[node], re = RS[node + 1];
        f32x2 accP0 = zero, accP1 = zero, accA0 = zero, accA1 = zero;
        auto accum = [&](uint4 se, uint2 r) {
            f32x2 y0 = unpk2(r.x), y1 = unpk2(r.y);
            f32x2 axy = unpk2(se.y), azw = unpk2(se.z);
            f32x2 ax = {axy[0], axy[0]}, ay = {axy[1], axy[1]};
            f32x2 az = {azw[0], azw[0]}, aw = {azw[1], azw[1]};
            f32x2 m0 = __builtin_elementwise_fma(ax, wA0, y0);
            f32x2 m1 = __builtin_elementwise_fma(ax, wA1, y1);
            m0 = __builtin_elementwise_fma(ay, wB0, m0);
            m1 = __builtin_elementwise_fma(ay, wB1, m1);
            m0 = __builtin_elementwise_fma(az, wC0, m0);
            m1 = __builtin_elementwise_fma(az, wC1, m1);
            m0 = __builtin_elementwise_fma(aw, wD0, m0);
            m1 = __builtin_elementwise_fma(aw, wD1, m1);
            accA0 += m0; accA1 += m1;
            accP0 += __builtin_elementwise_max(m0, zero);
            accP1 += __builtin_elementwise_max(m1, zero);
        };
        int j = rs;
        for (; j + 8 <= re; j += 8) {
            uint4 se[8]; uint2 r[8];
#pragma unroll
            for (int u = 0; u < 8; ++u) se[u] = SE[j + u + vz];
#pragma unroll
            for (int u = 0; u < 8; ++u) r[u] = lrow[(se[u].x >> 16) << 6];
#pragma unroll
            for (int u = 0; u < 8; ++u) accum(se[u], r[u]);
        }
        if (j + 4 <= re) {
            uint4 se[4]; uint2 r[4];
#pragma unroll
            for (int u = 0; u < 4; ++u) se[u] = SE[j + u + vz];
#pragma unroll
            for (int u = 0; u < 4; ++u) r[u] = lrow[(se[u].x >> 16) << 6];
#pragma unroll
            for (int u = 0; u < 4; ++u) accum(se[u], r[u]);
            j += 4;
        }
        for (; j < re; ++j) {
            uint4 se = SE[j + vz];
            accum(se, lrow[(se.x >> 16) << 6]);
        }
        const f32x2 c99 = {0.99f, 0.99f}, c01 = {0.01f, 0.01f};
        f32x2 o0 = __builtin_elementwise_fma(accP0, c99, accA0 * c01);
        f32x2 o1 = __builtin_elementwise_fma(accP1, c99, accA1 * c01);
        *((float4*)(agg + node * 256) + lane) = make_float4(o0[0], o0[1], o1[0], o1[1]);
        ssum0 += o0; ssum1 += o1;
        qsum0 += o0 * o0; qsum1 += o1 * o1;
    }
    // fused BN1 partial stats: cross-wave reduce in (now dead) sTY space,
    // then 2 atomicAdds per thread into the 256-row PARTS accumulator.
    __syncthreads();
    float* red = (float*)sTY;  // 4 waves x 512 floats = 8 KB scratch
    red[w * 512 + c4 + 0] = ssum0[0]; red[w * 512 + c4 + 1] = ssum0[1];
    red[w * 512 + c4 + 2] = ssum1[0]; red[w * 512 + c4 + 3] = ssum1[1];
    red[w * 512 + 256 + c4 + 0] = qsum0[0]; red[w * 512 + 256 + c4 + 1] = qsum0[1];
    red[w * 512 + 256 + c4 + 2] = qsum1[0]; red[w * 512 + 256 + c4 + 3] = qsum1[1];
    __syncthreads();
    int cc = threadIdx.x;
    float s = red[cc] + red[512 + cc] + red[1024 + cc] + red[1536 + cc];
    float q = red[256 + cc] + red[768 + cc] + red[1280 + cc] + red[1792 + cc];
    int prow = (blockIdx.x & 255) * 512;
    atomicAdd(&PARTS[prow + cc], s);
    atomicAdd(&PARTS[prow + 256 + cc], q);
}

// ---------------- conv2 layer: random gather; fused BN2 partial stats -------
__global__ __launch_bounds__(256, 4) void gme_conv1(
        const int* __restrict__ RS, const uint4* __restrict__ SE,
        const bf16_t* __restrict__ QB, const float* __restrict__ Wc,
        float* __restrict__ agg, float* __restrict__ PARTS) {
    __shared__ float red[2048];
    int lane = threadIdx.x & 63;
    int w = threadIdx.x >> 6;
    int node = __builtin_amdgcn_readfirstlane(blockIdx.x * 4 + w);
    const float4* wc4 = (const float4*)Wc;
    int c4 = lane * 4;
    float4 w0 = wc4[c4 + 0], w1 = wc4[c4 + 1], w2 = wc4[c4 + 2], w3 = wc4[c4 + 3];
    f32x2 wA0 = {w0.x, w1.x}, wB0 = {w0.y, w1.y}, wC0 = {w0.z, w1.z}, wD0 = {w0.w, w1.w};
    f32x2 wA1 = {w2.x, w3.x}, wB1 = {w2.y, w3.y}, wC1 = {w2.z, w3.z}, wD1 = {w2.w, w3.w};
    const f32x2 zero = {0.f, 0.f};
    f32x2 accP0 = zero, accP1 = zero, accA0 = zero, accA1 = zero;
    int rs = RS[node], re = RS[node + 1];
    const char* yb = (const char*)QB;
    unsigned loff = (unsigned)(lane << 3);
    auto rowld = [&](unsigned row) -> uint2 {
        return *(const uint2*)(yb + (row << 9) + loff);
    };
    auto accum = [&](uint4 se, uint2 r) {
        f32x2 y0 = unpk2(r.x), y1 = unpk2(r.y);
        f32x2 axy = unpk2(se.y), azw = unpk2(se.z);
        f32x2 ax = {axy[0], axy[0]}, ay = {axy[1], axy[1]};
        f32x2 az = {azw[0], azw[0]}, aw = {azw[1], azw[1]};
        f32x2 m0 = __builtin_elementwise_fma(ax, wA0, y0);
        f32x2 m1 = __builtin_elementwise_fma(ax, wA1, y1);
        m0 = __builtin_elementwise_fma(ay, wB0, m0);
        m1 = __builtin_elementwise_fma(ay, wB1, m1);
        m0 = __builtin_elementwise_fma(az, wC0, m0);
        m1 = __builtin_elementwise_fma(az, wC1, m1);
        m0 = __builtin_elementwise_fma(aw, wD0, m0);
        m1 = __builtin_elementwise_fma(aw, wD1, m1);
        accA0 += m0; accA1 += m1;
        accP0 += __builtin_elementwise_max(m0, zero);
        accP1 += __builtin_elementwise_max(m1, zero);
    };
    int j = rs;
    for (; j + 12 <= re; j += 12) {
        uint4 se[12]; uint2 r[12];
#pragma unroll
        for (int u = 0; u < 12; ++u) se[u] = SE[j + u];
#pragma unroll
        for (int u = 0; u < 12; ++u) r[u] = rowld(se[u].x & 0xffffu);
#pragma unroll
        for (int u = 0; u < 12; ++u) accum(se[u], r[u]);
    }
    if (j + 8 <= re) {
        uint4 se[8]; uint2 r[8];
#pragma unroll
        for (int u = 0; u < 8; ++u) se[u] = SE[j + u];
#pragma unroll
        for (int u = 0; u < 8; ++u) r[u] = rowld(se[u].x & 0xffffu);
#pragma unroll
        for (int u = 0; u < 8; ++u) accum(se[u], r[u]);
        j += 8;
    }
    if (j + 4 <= re) {
        uint4 se[4]; uint2 r[4];
#pragma unroll
        for (int u = 0; u < 4; ++u) se[u] = SE[j + u];
#pragma unroll
        for (int u = 0; u < 4; ++u) r[u] = rowld(se[u].x & 0xffffu);
#pragma unroll
        for (int u = 0; u < 4; ++u) accum(se[u], r[u]);
        j += 4;
    }
    for (; j < re; ++j) {
        uint4 se = SE[j];
        accum(se, rowld(se.x & 0xffffu));
    }
    const f32x2 c99 = {0.99f, 0.99f}, c01 = {0.01f, 0.01f};
    f32x2 o0 = __builtin_elementwise_fma(accP0, c99, accA0 * c01);
    f32x2 o1 = __builtin_elementwise_fma(accP1, c99, accA1 * c01);
    *((float4*)(agg + node * 256) + lane) = make_float4(o0[0], o0[1], o1[0], o1[1]);
    // fused BN2 partial stats (each wave owns one node)
    red[w * 512 + c4 + 0] = o0[0]; red[w * 512 + c4 + 1] = o0[1];
    red[w * 512 + c4 + 2] = o1[0]; red[w * 512 + c4 + 3] = o1[1];
    red[w * 512 + 256 + c4 + 0] = o0[0] * o0[0];
    red[w * 512 + 256 + c4 + 1] = o0[1] * o0[1];
    red[w * 512 + 256 + c4 + 2] = o1[0] * o1[0];
    red[w * 512 + 256 + c4 + 3] = o1[1] * o1[1];
    __syncthreads();
    int cc = threadIdx.x;
    float s = red[cc] + red[512 + cc] + red[1024 + cc] + red[1536 + cc];
    float q = red[256 + cc] + red[768 + cc] + red[1280 + cc] + red[1792 + cc];
    int prow = (blockIdx.x & 255) * 512;
    atomicAdd(&PARTS[prow + cc], s);
    atomicAdd(&PARTS[prow + 256 + cc], q);
}

// ---------------- PARTS (256x512) -> ST reducer; optionally re-zero ----------
__global__ __launch_bounds__(512) void gme_bred(float* __restrict__ PARTS,
                                                float* __restrict__ ST, int zero) {
    int t = threadIdx.x;
    int b = blockIdx.x;
    float acc = 0.f;
#pragma unroll
    for (int r = 0; r < 16; ++r) acc += PARTS[(b * 16 + r) * 512 + t];
    atomicAdd(&ST[t], acc);
    if (zero) {
#pragma unroll
        for (int r = 0; r < 16; ++r) PARTS[(b * 16 + r) * 512 + t] = 0.f;
    }
}

// ---------------- GEMM, BN1+LeakyReLU fused on A; CB2 folded into output -----
// W2B staged in LDS (128 KB, slot-XOR swizzle -> conflict-free ds_read_b128).
__global__ __launch_bounds__(256) void gme_gemm(const float* __restrict__ P,
                                                const float* __restrict__ ST,
                                                const float* __restrict__ bw,
                                                const float* __restrict__ bb,
                                                const bf16_t* __restrict__ W2B,
                                                const float* __restrict__ CB2,
                                                bf16_t* __restrict__ QB) {
    __shared__ float s_sc[256], s_sh[256];
    __shared__ __align__(16) uint4 sB[8192];  // 128 KB, 16B-slot swizzled
    {
        int c = threadIdx.x;
        float mean = ST[c] * (1.f / NN);
        float var = ST[256 + c] * (1.f / NN) - mean * mean;
        float sc = bw[c] * rsqrtf(var + 1e-5f);
        s_sc[c] = sc;
        s_sh[c] = bb[c] - mean * sc;
        const uint4* w4 = (const uint4*)W2B;
#pragma unroll
        for (int it = 0; it < 32; ++it) {
            int i = it * 256 + c;
            int row = i >> 5, slot = i & 31;
            sB[(row << 5) | (slot ^ (row & 7))] = w4[i];
        }
    }
    __syncthreads();
    int lane = threadIdx.x & 63;
    int wave = blockIdx.x * 4 + (threadIdx.x >> 6);
    if (wave >= NN / 16) return;
    int m0 = wave * 16;
    int r = lane & 15, q = lane >> 4;
    int rx = r & 7;
    const float* arow = P + (m0 + r) * 256 + q * 8;
    bf16x8 a[8];
#pragma unroll
    for (int kt = 0; kt < 8; ++kt) {
        int k0 = kt * 32 + q * 8;
        float4 u0 = *(const float4*)(arow + kt * 32);
        float4 u1 = *(const float4*)(arow + kt * 32 + 4);
        bf16x8 f;
        f[0] = (bf16_t)lrelu(fmaf(u0.x, s_sc[k0 + 0], s_sh[k0 + 0]));
        f[1] = (bf16_t)lrelu(fmaf(u0.y, s_sc[k0 + 1], s_sh[k0 + 1]));
        f[2] = (bf16_t)lrelu(fmaf(u0.z, s_sc[k0 + 2], s_sh[k0 + 2]));
        f[3] = (bf16_t)lrelu(fmaf(u0.w, s_sc[k0 + 3], s_sh[k0 + 3]));
        f[4] = (bf16_t)lrelu(fmaf(u1.x, s_sc[k0 + 4], s_sh[k0 + 4]));
        f[5] = (bf16_t)lrelu(fmaf(u1.y, s_sc[k0 + 5], s_sh[k0 + 5]));
        f[6] = (bf16_t)lrelu(fmaf(u1.z, s_sc[k0 + 6], s_sh[k0 + 6]));
        f[7] = (bf16_t)lrelu(fmaf(u1.w, s_sc[k0 + 7], s_sh[k0 + 7]));
        a[kt] = f;
    }
#pragma unroll 1
    for (int g = 0; g < 2; ++g) {
        f32x4 acc[8];
#pragma unroll
        for (int n8 = 0; n8 < 8; ++n8) acc[n8] = (f32x4){0.f, 0.f, 0.f, 0.f};
#pragma unroll
        for (int kt = 0; kt < 8; ++kt) {
            int slot = (kt * 4 + q) ^ rx;
            bf16x8 bf[8];
#pragma unroll
            for (int n8 = 0; n8 < 8; ++n8) {
                int row = g * 128 + n8 * 16 + r;
                bf[n8] = *(const bf16x8*)&sB[(row << 5) | slot];
            }
#pragma unroll
            for (int n8 = 0; n8 < 8; ++n8) {
                acc[n8] = __builtin_amdgcn_mfma_f32_16x16x32_bf16(bf[n8], a[kt], acc[n8], 0, 0, 0);
            }
        }
#pragma unroll
        for (int n8 = 0; n8 < 8; ++n8) {
            int nt = g * 8 + n8;
            float4 cbv = ((const float4*)CB2)[nt * 4 + q];
            bf16x4 o;
            o[0] = (bf16_t)(acc[n8][0] + cbv.x);
            o[1] = (bf16_t)(acc[n8][1] + cbv.y);
            o[2] = (bf16_t)(acc[n8][2] + cbv.z);
            o[3] = (bf16_t)(acc[n8][3] + cbv.w);
            *(bf16x4*)(QB + (m0 + r) * 256 + nt * 16 + q * 4) = o;
        }
    }
}

// ---------------- fused gate + attentional aggregation (BN2+lrelu inline) ----
__global__ __launch_bounds__(256) void gme_attn(const int* __restrict__ GS,
                                                const float* __restrict__ P,
                                                const float* __restrict__ ST,
                                                const float* __restrict__ bw,
                                                const float* __restrict__ bb,
                                                const float* __restrict__ gw,
                                                const float* __restrict__ gb,
                                                float* __restrict__ out) {
    __shared__ float gl[1024];
    __shared__ float rr[8];
    int g = blockIdx.x, t = threadIdx.x;
    int lo = GS[g], hi = GS[g + 1];
    if (lo >= hi) { out[g * 256 + t] = 0.f; return; }
    int lane = t & 63, w = t >> 6;
    // phase A: per-node gates, wave-parallel (wave w -> nodes lo+w, step 4)
    {
        float4 s4 = ((const float4*)ST)[lane];
        float4 q4 = ((const float4*)(ST + 256))[lane];
        float4 w4 = ((const float4*)bw)[lane];
        float4 b4 = ((const float4*)bb)[lane];
        float4 g4 = ((const float4*)gw)[lane];
        float m0 = s4.x * (1.f / NN), m1 = s4.y * (1.f / NN);
        float m2 = s4.z * (1.f / NN), m3 = s4.w * (1.f / NN);
        float sc0 = w4.x * rsqrtf(q4.x * (1.f / NN) - m0 * m0 + 1e-5f);
        float sc1 = w4.y * rsqrtf(q4.y * (1.f / NN) - m1 * m1 + 1e-5f);
        float sc2 = w4.z * rsqrtf(q4.z * (1.f / NN) - m2 * m2 + 1e-5f);
        float sc3 = w4.w * rsqrtf(q4.w * (1.f / NN) - m3 * m3 + 1e-5f);
        float sh0 = b4.x - m0 * sc0, sh1 = b4.y - m1 * sc1;
        float sh2 = b4.z - m2 * sc2, sh3 = b4.w - m3 * sc3;
        float gb0 = gb[0];
        for (int n = lo + w; n < hi; n += 4) {
            float4 p = *(const float4*)(P + n * 256 + lane * 4);
            float d = lrelu(fmaf(p.x, sc0, sh0)) * g4.x
                    + lrelu(fmaf(p.y, sc1, sh1)) * g4.y
                    + lrelu(fmaf(p.z, sc2, sh2)) * g4.z
                    + lrelu(fmaf(p.w, sc3, sh3)) * g4.w;
#pragma unroll
            for (int off = 32; off > 0; off >>= 1) d += __shfl_xor(d, off, 64);
            if (lane == 0) gl[n - lo] = d + gb0;
        }
    }
    __syncthreads();
    // phase B: softmax max + denom over gl[0..cnt)
    int cnt = hi - lo;
    float lm = -3.0e38f;
    for (int i = t; i < cnt; i += 256) lm = fmaxf(lm, gl[i]);
#pragma unroll
    for (int off = 32; off > 0; off >>= 1) lm = fmaxf(lm, __shfl_xor(lm, off, 64));
    if (lane == 0) rr[w] = lm;
    __syncthreads();
    float mx = fmaxf(fmaxf(rr[0], rr[1]), fmaxf(rr[2], rr[3]));
    float ls = 0.f;
    for (int i = t; i < cnt; i += 256) { float e = expf(gl[i] - mx); gl[i] = e; ls += e; }
#pragma unroll
    for (int off = 32; off > 0; off >>= 1) ls += __shfl_xor(ls, off, 64);
    if (lane == 0) rr[4 + w] = ls;
    __syncthreads();
    float sinv = 1.f / (rr[4] + rr[5] + rr[6] + rr[7]);
    // phase C: weighted accumulate, thread t = channel t (P slice is L2-hot)
    float mean = ST[t] * (1.f / NN);
    float var = ST[256 + t] * (1.f / NN) - mean * mean;
    float sc = bw[t] * rsqrtf(var + 1e-5f);
    float sh = bb[t] - mean * sc;
    float a0 = 0.f, a1 = 0.f, a2 = 0.f, a3 = 0.f;
    int n = lo;
    for (; n + 4 <= hi; n += 4) {
        float p0 = P[n * 256 + t], p1 = P[(n + 1) * 256 + t];
        float p2 = P[(n + 2) * 256 + t], p3 = P[(n + 3) * 256 + t];
        a0 = fmaf(gl[n - lo + 0], lrelu(fmaf(p0, sc, sh)), a0);
        a1 = fmaf(gl[n - lo + 1], lrelu(fmaf(p1, sc, sh)), a1);
        a2 = fmaf(gl[n - lo + 2], lrelu(fmaf(p2, sc, sh)), a2);
        a3 = fmaf(gl[n - lo + 3], lrelu(fmaf(p3, sc, sh)), a3);
    }
    for (; n < hi; ++n) a0 = fmaf(gl[n - lo], lrelu(fmaf(P[n * 256 + t], sc, sh)), a0);
    out[g * 256 + t] = (a0 + a1 + a2 + a3) * sinv;
}

extern "C" void kernel_launch(void* const* d_in, const int* in_sizes, int n_in,
                              void* d_out, int out_size, void* d_ws, size_t ws_size,
                              hipStream_t stream) {
    const int* node_ids = (const int*)d_in[0];
    const int* edge_index = (const int*)d_in[1];
    const float4* edge_attr = (const float4*)d_in[2];
    const int* batch = (const int*)d_in[3];
    const float* emb = (const float*)d_in[4];
    const float* c1l2w = (const float*)d_in[5];
    const float* c1l2b = (const float*)d_in[6];
    const float* c1lw = (const float*)d_in[7];
    const float* c1lb = (const float*)d_in[8];
    const float* bn1w = (const float*)d_in[9];
    const float* bn1b = (const float*)d_in[10];
    const float* c2l2w = (const float*)d_in[11];
    const float* c2l2b = (const float*)d_in[12];
    const float* c2lw = (const float*)d_in[13];
    const float* c2lb = (const float*)d_in[14];
    const float* bn2w = (const float*)d_in[15];
    const float* bn2b = (const float*)d_in[16];
    const float* gate_w = (const float*)d_in[17];
    const float* gate_b = (const float*)d_in[18];

    char* ws = (char*)d_ws;
    size_t oP = 0;                        // f32 [50000,256]
    size_t oQB = oP + 51200000;           // bf16 [50000,256]
    size_t oSE = oQB + 25600000;          // uint4 [800000] packed edge records
    size_t oRS = oSE + 12800000;          // int [50001]
    size_t oCNT = oRS + 200064;           // int [50000]
    size_t oCUR = oCNT + 200000;          // int [50000]
    size_t oLP = oCUR + 200000;           // int [50000]
    size_t oBS = oLP + 200000;            // int [256]
    size_t oBX = oBS + 1024;              // int [256]
    size_t oTY = oBX + 1024;              // bf16 [51,256]
    size_t oWC1 = oTY + 52224;            // f32 [256,4]
    size_t oWC2 = oWC1 + 4096;            // f32 [256,4]
    size_t oCB2 = oWC2 + 4096;            // f32 [256]
    size_t oW2B = oCB2 + 1024;            // bf16 [256,256]
    size_t oST = oW2B + 131072;           // f32 [1024]: ST1+ST2
    size_t oPARTS = oST + 4096;           // f32 [256,512] stats accumulator
    size_t oGS = oPARTS + 524288;         // int [513]

    float* P = (float*)(ws + oP);
    bf16_t* QB = (bf16_t*)(ws + oQB);
    uint4* SE = (uint4*)(ws + oSE);
    int* RS = (int*)(ws + oRS);
    int* CNT = (int*)(ws + oCNT);
    int* CUR = (int*)(ws + oCUR);
    int* LP = (int*)(ws + oLP);
    int* BS = (int*)(ws + oBS);
    int* BX = (int*)(ws + oBX);
    bf16_t* TYB = (bf16_t*)(ws + oTY);
    float* WC1 = (float*)(ws + oWC1);
    float* WC2 = (float*)(ws + oWC2);
    float* CB2 = (float*)(ws + oCB2);
    bf16_t* W2B = (bf16_t*)(ws + oW2B);
    float* ST1 = (float*)(ws + oST);
    float* ST2 = ST1 + 512;
    float* PARTS = (float*)(ws + oPARTS);
    int* GS = (int*)(ws + oGS);

    // one memset covers ST1+ST2 (4 KB) and PARTS (512 KB), contiguous
    hipMemsetAsync(ST1, 0, 4096 + 524288, stream);

    gme_setup<<<313, 256, 0, stream>>>(emb, c1lw, c1l2w, c1l2b, c1lb,
                                       c2lw, c2l2w, c2l2b, c2lb,
                                       TYB, WC1, WC2, CB2, W2B, CNT);
    gme_count<<<NE / 256, 256, 0, stream>>>(edge_index, CNT);
    gme_scan1<<<256, 256, 0, stream>>>(CNT, LP, BS);
    gme_scan2<<<1, 256, 0, stream>>>(BS, BX, RS);
    gme_scan3<<<256, 256, 0, stream>>>(LP, BX, RS, CUR, batch, GS);
    gme_scatter<<<NE / 256, 256, 0, stream>>>(edge_index, edge_attr, node_ids,
                                              CUR, SE);
    // conv1: bf16 TY table in LDS, packed SE stream, BN1 stats fused -> PARTS
    gme_conv0<<<NN / 16, 256, 0, stream>>>(RS, SE, TYB, WC1, P, PARTS);
    gme_bred<<<16, 512, 0, stream>>>(PARTS, ST1, 1);   // -> ST1, re-zero PARTS
    gme_gemm<<<(NN / 16 + 3) / 4, 256, 0, stream>>>(P, ST1, bn1w, bn1b, W2B, CB2, QB);
    // conv2: rows from bf16 y2 table (CB2 folded), BN2 stats fused -> PARTS
    gme_conv1<<<NN / 4, 256, 0, stream>>>(RS, SE, QB, WC2, P, PARTS);
    gme_bred<<<16, 512, 0, stream>>>(PARTS, ST2, 0);   // -> ST2
    gme_attn<<<NG, 256, 0, stream>>>(GS, P, ST2, bn2w, bn2b, gate_w, gate_b,
                                     (float*)d_out);
}

// Round 11
// 363.614 us; speedup vs baseline: 1.1878x; 1.0712x over previous
//
#include <hip/hip_runtime.h>
#include <hip/hip_bf16.h>

#define NN 50000
#define NE 800000
#define NG 512

typedef __bf16 bf16_t;
typedef __bf16 bf16x8 __attribute__((ext_vector_type(8)));
typedef __bf16 bf16x4 __attribute__((ext_vector_type(4)));
typedef float f32x4 __attribute__((ext_vector_type(4)));
typedef float f32x2 __attribute__((ext_vector_type(2)));

__device__ __forceinline__ float lrelu(float v) { return v >= 0.f ? v : 0.01f * v; }

// unpack 2 bf16 (packed in one u32) -> float2 (pair order: lo, hi)
__device__ __forceinline__ f32x2 unpk2(unsigned w) {
    union { unsigned u; float f; } lo, hi;
    lo.u = w << 16;
    hi.u = w & 0xffff0000u;
    f32x2 r; r[0] = lo.f; r[1] = hi.f; return r;
}

// opaque per-lane zero: forces VGPR addressing (vmcnt path) for loads that the
// compiler would otherwise scalarize onto the s_load/lgkmcnt path.
__device__ __forceinline__ int vzero() {
    int vz;
    asm("v_mov_b32 %0, 0" : "=v"(vz));
    return vz;
}

// ---------------- tiny precomputes + CNT zeroing ----------------
// TYB[b][t] = bf16( sum_k (emb[b][k]+c1l2b[k]) * W1[t][k] + c1lb[t] )
// WC1[t][c] = sum_k W1[t][k] * c1l2w[k][c]
// WC2[t][c] = sum_k W2[t][k] * c2l2w[k][c];  CB2[t] = sum_k W2[t][k]*c2l2b[k] + c2lb[t]
__global__ void gme_setup(const float* __restrict__ emb,
                          const float* __restrict__ c1lw, const float* __restrict__ c1l2w,
                          const float* __restrict__ c1l2b, const float* __restrict__ c1lb,
                          const float* __restrict__ c2lw, const float* __restrict__ c2l2w,
                          const float* __restrict__ c2l2b, const float* __restrict__ c2lb,
                          bf16_t* __restrict__ TYB, float* __restrict__ WC1,
                          float* __restrict__ WC2, float* __restrict__ CB2,
                          bf16_t* __restrict__ W2B, int* __restrict__ CNT) {
    int b = blockIdx.x, t = threadIdx.x;
    if (b < 51) {
        const float4* er = (const float4*)(emb + b * 128);
        const float4* zb = (const float4*)c1l2b;
        const float4* wr = (const float4*)(c1lw + t * 128);
        float s = 0.f;
        for (int k = 0; k < 32; ++k) {
            float4 e = er[k], z = zb[k], w = wr[k];
            s += (e.x + z.x) * w.x + (e.y + z.y) * w.y + (e.z + z.z) * w.z + (e.w + z.w) * w.w;
        }
        TYB[b * 256 + t] = (bf16_t)(s + c1lb[t]);
    } else if (b == 51) {
        const float4* wr = (const float4*)(c1lw + t * 128);
        const float4* cw = (const float4*)c1l2w;
        float4 a = make_float4(0.f, 0.f, 0.f, 0.f);
        for (int k = 0; k < 32; ++k) {
            float4 w = wr[k];
            float4 c0 = cw[k * 4 + 0], c1 = cw[k * 4 + 1], c2 = cw[k * 4 + 2], c3 = cw[k * 4 + 3];
            a.x += w.x * c0.x + w.y * c1.x + w.z * c2.x + w.w * c3.x;
            a.y += w.x * c0.y + w.y * c1.y + w.z * c2.y + w.w * c3.y;
            a.z += w.x * c0.z + w.y * c1.z + w.z * c2.z + w.w * c3.z;
            a.w += w.x * c0.w + w.y * c1.w + w.z * c2.w + w.w * c3.w;
        }
        ((float4*)WC1)[t] = a;
    } else if (b == 52) {
        const float4* wr = (const float4*)(c2lw + t * 256);
        const float4* cw = (const float4*)c2l2w;
        const float4* zb = (const float4*)c2l2b;
        float4 a = make_float4(0.f, 0.f, 0.f, 0.f);
        float ab = 0.f;
        for (int k = 0; k < 64; ++k) {
            float4 w = wr[k];
            float4 c0 = cw[k * 4 + 0], c1 = cw[k * 4 + 1], c2 = cw[k * 4 + 2], c3 = cw[k * 4 + 3];
            float4 z = zb[k];
            a.x += w.x * c0.x + w.y * c1.x + w.z * c2.x + w.w * c3.x;
            a.y += w.x * c0.y + w.y * c1.y + w.z * c2.y + w.w * c3.y;
            a.z += w.x * c0.z + w.y * c1.z + w.z * c2.z + w.w * c3.z;
            a.w += w.x * c0.w + w.y * c1.w + w.z * c2.w + w.w * c3.w;
            ab += w.x * z.x + w.y * z.y + w.z * z.z + w.w * z.w;
        }
        ((float4*)WC2)[t] = a;
        CB2[t] = ab + c2lb[t];
    } else if (b < 117) {
        int i0 = (b - 53) * 1024;
        for (int r = 0; r < 4; ++r) {
            int i = i0 + r * 256 + t;
            W2B[i] = (bf16_t)c2lw[i];
        }
    } else {
        int i = (b - 117) * 256 + t;
        if (i < NN) CNT[i] = 0;
    }
}

// ---------------- CSR build ----------------
// count + per-edge rank (rank persisted so scatter needs no atomic)
__global__ void gme_count(const int* __restrict__ ei, int* __restrict__ cnt,
                          int* __restrict__ RK) {
    int e = blockIdx.x * 256 + threadIdx.x;
    if (e >= NE) return;
    RK[e] = atomicAdd(&cnt[ei[NE + e]], 1);
}

__global__ void gme_scan1(const int* __restrict__ CNT, int* __restrict__ LP,
                          int* __restrict__ BS) {
    __shared__ int lds[256];
    int b = blockIdx.x, t = threadIdx.x;
    int i = b * 196 + t;
    int v = (t < 196 && i < NN) ? CNT[i] : 0;
    lds[t] = v;
    __syncthreads();
    for (int off = 1; off < 256; off <<= 1) {
        int u = (t >= off) ? lds[t - off] : 0;
        __syncthreads();
        lds[t] += u;
        __syncthreads();
    }
    if (t < 196 && i < NN) LP[i] = lds[t] - v;
    if (t == 255) BS[b] = lds[255];
}

__global__ void gme_scan2(const int* __restrict__ BS, int* __restrict__ BX,
                          int* __restrict__ RS) {
    __shared__ int lds[256];
    int t = threadIdx.x;
    int v = BS[t];
    lds[t] = v;
    __syncthreads();
    for (int off = 1; off < 256; off <<= 1) {
        int u = (t >= off) ? lds[t - off] : 0;
        __syncthreads();
        lds[t] += u;
        __syncthreads();
    }
    BX[t] = lds[t] - v;
    if (t == 255) RS[NN] = lds[255];
}

// scan3 + graph-segment boundaries fused (same iteration space over nodes)
__global__ void gme_scan3(const int* __restrict__ LP, const int* __restrict__ BX,
                          int* __restrict__ RS,
                          const int* __restrict__ batch, int* __restrict__ GS) {
    int b = blockIdx.x, t = threadIdx.x;
    if (t >= 196) return;
    int i = b * 196 + t;
    if (i >= NN) return;
    RS[i] = BX[b] + LP[i];
    int bb = batch[i];
    if (i == 0) {
        for (int g = 0; g <= bb; ++g) GS[g] = 0;
    } else {
        int a = batch[i - 1];
        for (int g = a + 1; g <= bb; ++g) GS[g] = i;
    }
    if (i == NN - 1) {
        for (int g = bb + 1; g <= NG; ++g) GS[g] = NN;
    }
}

// single 16B record per edge: {src|nid<<16, attr.xy bf16x2, attr.zw bf16x2, 0}
// pos computed from persisted rank -> no atomic in the scatter chain.
__global__ void gme_scatter(const int* __restrict__ ei,
                            const float4* __restrict__ eattr,
                            const int* __restrict__ node_ids,
                            const int* __restrict__ RS, const int* __restrict__ RK,
                            uint4* __restrict__ SE) {
    int e = blockIdx.x * 256 + threadIdx.x;
    if (e >= NE) return;
    int s = ei[e];
    int d = ei[NE + e];
    int nid = node_ids[s];
    float4 at = eattr[e];
    union { bf16_t h[2]; unsigned u; } p01, p23;
    p01.h[0] = (bf16_t)at.x; p01.h[1] = (bf16_t)at.y;
    p23.h[0] = (bf16_t)at.z; p23.h[1] = (bf16_t)at.w;
    int pos = RS[d] + RK[e];
    SE[pos] = make_uint4((unsigned)(s | (nid << 16)), p01.u, p23.u, 0u);
}

// ---------------- conv1 layer: bf16 TY in LDS; fused BN1 partial stats ------
__global__ __launch_bounds__(256) void gme_conv0(
        const int* __restrict__ RS, const uint4* __restrict__ SE,
        const bf16_t* __restrict__ TYB, const float* __restrict__ Wc,
        float* __restrict__ agg, float* __restrict__ PARTS) {
    __shared__ __align__(16) uint2 sTY[51 * 64];  // 26112 B bf16 table
    {
        const uint4* s4 = (const uint4*)TYB;
        uint4* d4 = (uint4*)sTY;
        for (int i = threadIdx.x; i < 51 * 32; i += 256) d4[i] = s4[i];
    }
    __syncthreads();
    int lane = threadIdx.x & 63;
    int w = threadIdx.x >> 6;
    int vz = vzero();
    const float4* wc4 = (const float4*)Wc;
    int c4 = lane * 4;
    float4 w0 = wc4[c4 + 0], w1 = wc4[c4 + 1], w2 = wc4[c4 + 2], w3 = wc4[c4 + 3];
    f32x2 wA0 = {w0.x, w1.x}, wB0 = {w0.y, w1.y}, wC0 = {w0.z, w1.z}, wD0 = {w0.w, w1.w};
    f32x2 wA1 = {w2.x, w3.x}, wB1 = {w2.y, w3.y}, wC1 = {w2.z, w3.z}, wD1 = {w2.w, w3.w};
    const f32x2 zero = {0.f, 0.f};
    const uint2* lrow = sTY + lane;
    int base = blockIdx.x * 16 + w * 4;
    f32x2 ssum0 = zero, ssum1 = zero, qsum0 = zero, qsum1 = zero;
#pragma unroll 1
    for (int k = 0; k < 4; ++k) {
        int node = __builtin_amdgcn_readfirstlane(base + k);
        int rs = RS[node], re = RS[node + 1];
        f32x2 accP0 = zero, accP1 = zero, accA0 = zero, accA1 = zero;
        auto accum = [&](uint4 se, uint2 r) {
            f32x2 y0 = unpk2(r.x), y1 = unpk2(r.y);
            f32x2 axy = unpk2(se.y), azw = unpk2(se.z);
            f32x2 ax = {axy[0], axy[0]}, ay = {axy[1], axy[1]};
            f32x2 az = {azw[0], azw[0]}, aw = {azw[1], azw[1]};
            f32x2 m0 = __builtin_elementwise_fma(ax, wA0, y0);
            f32x2 m1 = __builtin_elementwise_fma(ax, wA1, y1);
            m0 = __builtin_elementwise_fma(ay, wB0, m0);
            m1 = __builtin_elementwise_fma(ay, wB1, m1);
            m0 = __builtin_elementwise_fma(az, wC0, m0);
            m1 = __builtin_elementwise_fma(az, wC1, m1);
            m0 = __builtin_elementwise_fma(aw, wD0, m0);
            m1 = __builtin_elementwise_fma(aw, wD1, m1);
            accA0 += m0; accA1 += m1;
            accP0 += __builtin_elementwise_max(m0, zero);
            accP1 += __builtin_elementwise_max(m1, zero);
        };
        int j = rs;
        for (; j + 8 <= re; j += 8) {
            uint4 se[8]; uint2 r[8];
#pragma unroll
            for (int u = 0; u < 8; ++u) se[u] = SE[j + u + vz];
#pragma unroll
            for (int u = 0; u < 8; ++u) r[u] = lrow[(se[u].x >> 16) << 6];
#pragma unroll
            for (int u = 0; u < 8; ++u) accum(se[u], r[u]);
        }
        if (j + 4 <= re) {
            uint4 se[4]; uint2 r[4];
#pragma unroll
            for (int u = 0; u < 4; ++u) se[u] = SE[j + u + vz];
#pragma unroll
            for (int u = 0; u < 4; ++u) r[u] = lrow[(se[u].x >> 16) << 6];
#pragma unroll
            for (int u = 0; u < 4; ++u) accum(se[u], r[u]);
            j += 4;
        }
        for (; j < re; ++j) {
            uint4 se = SE[j + vz];
            accum(se, lrow[(se.x >> 16) << 6]);
        }
        const f32x2 c99 = {0.99f, 0.99f}, c01 = {0.01f, 0.01f};
        f32x2 o0 = __builtin_elementwise_fma(accP0, c99, accA0 * c01);
        f32x2 o1 = __builtin_elementwise_fma(accP1, c99, accA1 * c01);
        *((float4*)(agg + node * 256) + lane) = make_float4(o0[0], o0[1], o1[0], o1[1]);
        ssum0 += o0; ssum1 += o1;
        qsum0 += o0 * o0; qsum1 += o1 * o1;
    }
    // fused BN1 partial stats: cross-wave reduce in (now dead) sTY space,
    // then 2 atomicAdds per thread into the 256-row PARTS accumulator.
    __syncthreads();
    float* red = (float*)sTY;  // 4 waves x 512 floats = 8 KB scratch
    red[w * 512 + c4 + 0] = ssum0[0]; red[w * 512 + c4 + 1] = ssum0[1];
    red[w * 512 + c4 + 2] = ssum1[0]; red[w * 512 + c4 + 3] = ssum1[1];
    red[w * 512 + 256 + c4 + 0] = qsum0[0]; red[w * 512 + 256 + c4 + 1] = qsum0[1];
    red[w * 512 + 256 + c4 + 2] = qsum1[0]; red[w * 512 + 256 + c4 + 3] = qsum1[1];
    __syncthreads();
    int cc = threadIdx.x;
    float s = red[cc] + red[512 + cc] + red[1024 + cc] + red[1536 + cc];
    float q = red[256 + cc] + red[768 + cc] + red[1280 + cc] + red[1792 + cc];
    int prow = (blockIdx.x & 255) * 512;
    atomicAdd(&PARTS[prow + cc], s);
    atomicAdd(&PARTS[prow + 256 + cc], q);
}

// ---------------- conv2 layer: random gather; SE batch prefetch; fused BN2 ---
__global__ __launch_bounds__(256, 4) void gme_conv1(
        const int* __restrict__ RS, const uint4* __restrict__ SE,
        const bf16_t* __restrict__ QB, const float* __restrict__ Wc,
        float* __restrict__ agg, float* __restrict__ PARTS) {
    __shared__ float red[2048];
    int lane = threadIdx.x & 63;
    int w = threadIdx.x >> 6;
    int node = __builtin_amdgcn_readfirstlane(blockIdx.x * 4 + w);
    const float4* wc4 = (const float4*)Wc;
    int c4 = lane * 4;
    float4 w0 = wc4[c4 + 0], w1 = wc4[c4 + 1], w2 = wc4[c4 + 2], w3 = wc4[c4 + 3];
    f32x2 wA0 = {w0.x, w1.x}, wB0 = {w0.y, w1.y}, wC0 = {w0.z, w1.z}, wD0 = {w0.w, w1.w};
    f32x2 wA1 = {w2.x, w3.x}, wB1 = {w2.y, w3.y}, wC1 = {w2.z, w3.z}, wD1 = {w2.w, w3.w};
    const f32x2 zero = {0.f, 0.f};
    f32x2 accP0 = zero, accP1 = zero, accA0 = zero, accA1 = zero;
    int rs = RS[node], re = RS[node + 1];
    const char* yb = (const char*)QB;
    unsigned loff = (unsigned)(lane << 3);
    auto rowld = [&](unsigned row) -> uint2 {
        return *(const uint2*)(yb + (row << 9) + loff);
    };
    auto accum = [&](uint4 se, uint2 r) {
        f32x2 y0 = unpk2(r.x), y1 = unpk2(r.y);
        f32x2 axy = unpk2(se.y), azw = unpk2(se.z);
        f32x2 ax = {axy[0], axy[0]}, ay = {axy[1], axy[1]};
        f32x2 az = {azw[0], azw[0]}, aw = {azw[1], azw[1]};
        f32x2 m0 = __builtin_elementwise_fma(ax, wA0, y0);
        f32x2 m1 = __builtin_elementwise_fma(ax, wA1, y1);
        m0 = __builtin_elementwise_fma(ay, wB0, m0);
        m1 = __builtin_elementwise_fma(ay, wB1, m1);
        m0 = __builtin_elementwise_fma(az, wC0, m0);
        m1 = __builtin_elementwise_fma(az, wC1, m1);
        m0 = __builtin_elementwise_fma(aw, wD0, m0);
        m1 = __builtin_elementwise_fma(aw, wD1, m1);
        accA0 += m0; accA1 += m1;
        accP0 += __builtin_elementwise_max(m0, zero);
        accP1 += __builtin_elementwise_max(m1, zero);
    };
    int j = rs;
    // software-pipelined 8-deep: SE batch k+1 (s_loads, lgkmcnt) issues while
    // batch k's row gathers (vmcnt) are in flight / being consumed.
    if (j + 8 <= re) {
        uint4 se[8];
#pragma unroll
        for (int u = 0; u < 8; ++u) se[u] = SE[j + u];
        while (true) {
            uint2 r[8];
#pragma unroll
            for (int u = 0; u < 8; ++u) r[u] = rowld(se[u].x & 0xffffu);
            bool more = (j + 16 <= re);
            uint4 seN[8];
            if (more) {
#pragma unroll
                for (int u = 0; u < 8; ++u) seN[u] = SE[j + 8 + u];
            }
#pragma unroll
            for (int u = 0; u < 8; ++u) accum(se[u], r[u]);
            j += 8;
            if (!more) break;
#pragma unroll
            for (int u = 0; u < 8; ++u) se[u] = seN[u];
        }
    }
    if (j + 4 <= re) {
        uint4 se[4]; uint2 r[4];
#pragma unroll
        for (int u = 0; u < 4; ++u) se[u] = SE[j + u];
#pragma unroll
        for (int u = 0; u < 4; ++u) r[u] = rowld(se[u].x & 0xffffu);
#pragma unroll
        for (int u = 0; u < 4; ++u) accum(se[u], r[u]);
        j += 4;
    }
    for (; j < re; ++j) {
        uint4 se = SE[j];
        accum(se, rowld(se.x & 0xffffu));
    }
    const f32x2 c99 = {0.99f, 0.99f}, c01 = {0.01f, 0.01f};
    f32x2 o0 = __builtin_elementwise_fma(accP0, c99, accA0 * c01);
    f32x2 o1 = __builtin_elementwise_fma(accP1, c99, accA1 * c01);
    *((float4*)(agg + node * 256) + lane) = make_float4(o0[0], o0[1], o1[0], o1[1]);
    // fused BN2 partial stats (each wave owns one node)
    red[w * 512 + c4 + 0] = o0[0]; red[w * 512 + c4 + 1] = o0[1];
    red[w * 512 + c4 + 2] = o1[0]; red[w * 512 + c4 + 3] = o1[1];
    red[w * 512 + 256 + c4 + 0] = o0[0] * o0[0];
    red[w * 512 + 256 + c4 + 1] = o0[1] * o0[1];
    red[w * 512 + 256 + c4 + 2] = o1[0] * o1[0];
    red[w * 512 + 256 + c4 + 3] = o1[1] * o1[1];
    __syncthreads();
    int cc = threadIdx.x;
    float s = red[cc] + red[512 + cc] + red[1024 + cc] + red[1536 + cc];
    float q = red[256 + cc] + red[768 + cc] + red[1280 + cc] + red[1792 + cc];
    int prow = (blockIdx.x & 255) * 512;
    atomicAdd(&PARTS[prow + cc], s);
    atomicAdd(&PARTS[prow + 256 + cc], q);
}

// ---------------- PARTS (256x512) -> ST reducer; optionally re-zero ----------
__global__ __launch_bounds__(512) void gme_bred(float* __restrict__ PARTS,
                                                float* __restrict__ ST, int zero) {
    int t = threadIdx.x;
    int b = blockIdx.x;
    float acc = 0.f;
#pragma unroll
    for (int r = 0; r < 16; ++r) acc += PARTS[(b * 16 + r) * 512 + t];
    atomicAdd(&ST[t], acc);
    if (zero) {
#pragma unroll
        for (int r = 0; r < 16; ++r) PARTS[(b * 16 + r) * 512 + t] = 0.f;
    }
}

// ---------------- GEMM, BN1+LeakyReLU fused on A; CB2 folded into output -----
// W2B staged in LDS (128 KB, slot-XOR swizzle -> conflict-free ds_read_b128).
__global__ __launch_bounds__(256) void gme_gemm(const float* __restrict__ P,
                                                const float* __restrict__ ST,
                                                const float* __restrict__ bw,
                                                const float* __restrict__ bb,
                                                const bf16_t* __restrict__ W2B,
                                                const float* __restrict__ CB2,
                                                bf16_t* __restrict__ QB) {
    __shared__ float s_sc[256], s_sh[256];
    __shared__ __align__(16) uint4 sB[8192];  // 128 KB, 16B-slot swizzled
    {
        int c = threadIdx.x;
        float mean = ST[c] * (1.f / NN);
        float var = ST[256 + c] * (1.f / NN) - mean * mean;
        float sc = bw[c] * rsqrtf(var + 1e-5f);
        s_sc[c] = sc;
        s_sh[c] = bb[c] - mean * sc;
        const uint4* w4 = (const uint4*)W2B;
#pragma unroll
        for (int it = 0; it < 32; ++it) {
            int i = it * 256 + c;
            int row = i >> 5, slot = i & 31;
            sB[(row << 5) | (slot ^ (row & 7))] = w4[i];
        }
    }
    __syncthreads();
    int lane = threadIdx.x & 63;
    int wave = blockIdx.x * 4 + (threadIdx.x >> 6);
    if (wave >= NN / 16) return;
    int m0 = wave * 16;
    int r = lane & 15, q = lane >> 4;
    int rx = r & 7;
    const float* arow = P + (m0 + r) * 256 + q * 8;
    bf16x8 a[8];
#pragma unroll
    for (int kt = 0; kt < 8; ++kt) {
        int k0 = kt * 32 + q * 8;
        float4 u0 = *(const float4*)(arow + kt * 32);
        float4 u1 = *(const float4*)(arow + kt * 32 + 4);
        bf16x8 f;
        f[0] = (bf16_t)lrelu(fmaf(u0.x, s_sc[k0 + 0], s_sh[k0 + 0]));
        f[1] = (bf16_t)lrelu(fmaf(u0.y, s_sc[k0 + 1], s_sh[k0 + 1]));
        f[2] = (bf16_t)lrelu(fmaf(u0.z, s_sc[k0 + 2], s_sh[k0 + 2]));
        f[3] = (bf16_t)lrelu(fmaf(u0.w, s_sc[k0 + 3], s_sh[k0 + 3]));
        f[4] = (bf16_t)lrelu(fmaf(u1.x, s_sc[k0 + 4], s_sh[k0 + 4]));
        f[5] = (bf16_t)lrelu(fmaf(u1.y, s_sc[k0 + 5], s_sh[k0 + 5]));
        f[6] = (bf16_t)lrelu(fmaf(u1.z, s_sc[k0 + 6], s_sh[k0 + 6]));
        f[7] = (bf16_t)lrelu(fmaf(u1.w, s_sc[k0 + 7], s_sh[k0 + 7]));
        a[kt] = f;
    }
#pragma unroll 1
    for (int g = 0; g < 2; ++g) {
        f32x4 acc[8];
#pragma unroll
        for (int n8 = 0; n8 < 8; ++n8) acc[n8] = (f32x4){0.f, 0.f, 0.f, 0.f};
#pragma unroll
        for (int kt = 0; kt < 8; ++kt) {
            int slot = (kt * 4 + q) ^ rx;
            bf16x8 bf[8];
#pragma unroll
            for (int n8 = 0; n8 < 8; ++n8) {
                int row = g * 128 + n8 * 16 + r;
                bf[n8] = *(const bf16x8*)&sB[(row << 5) | slot];
            }
#pragma unroll
            for (int n8 = 0; n8 < 8; ++n8) {
                acc[n8] = __builtin_amdgcn_mfma_f32_16x16x32_bf16(bf[n8], a[kt], acc[n8], 0, 0, 0);
            }
        }
#pragma unroll
        for (int n8 = 0; n8 < 8; ++n8) {
            int nt = g * 8 + n8;
            float4 cbv = ((const float4*)CB2)[nt * 4 + q];
            bf16x4 o;
            o[0] = (bf16_t)(acc[n8][0] + cbv.x);
            o[1] = (bf16_t)(acc[n8][1] + cbv.y);
            o[2] = (bf16_t)(acc[n8][2] + cbv.z);
            o[3] = (bf16_t)(acc[n8][3] + cbv.w);
            *(bf16x4*)(QB + (m0 + r) * 256 + nt * 16 + q * 4) = o;
        }
    }
}

// ---------------- fused gate + attentional aggregation (BN2+lrelu inline) ----
__global__ __launch_bounds__(256) void gme_attn(const int* __restrict__ GS,
                                                const float* __restrict__ P,
                                                const float* __restrict__ ST,
                                                const float* __restrict__ bw,
                                                const float* __restrict__ bb,
                                                const float* __restrict__ gw,
                                                const float* __restrict__ gb,
                                                float* __restrict__ out) {
    __shared__ float gl[1024];
    __shared__ float rr[8];
    int g = blockIdx.x, t = threadIdx.x;
    int lo = GS[g], hi = GS[g + 1];
    if (lo >= hi) { out[g * 256 + t] = 0.f; return; }
    int lane = t & 63, w = t >> 6;
    // phase A: per-node gates, wave-parallel (wave w -> nodes lo+w, step 4)
    {
        float4 s4 = ((const float4*)ST)[lane];
        float4 q4 = ((const float4*)(ST + 256))[lane];
        float4 w4 = ((const float4*)bw)[lane];
        float4 b4 = ((const float4*)bb)[lane];
        float4 g4 = ((const float4*)gw)[lane];
        float m0 = s4.x * (1.f / NN), m1 = s4.y * (1.f / NN);
        float m2 = s4.z * (1.f / NN), m3 = s4.w * (1.f / NN);
        float sc0 = w4.x * rsqrtf(q4.x * (1.f / NN) - m0 * m0 + 1e-5f);
        float sc1 = w4.y * rsqrtf(q4.y * (1.f / NN) - m1 * m1 + 1e-5f);
        float sc2 = w4.z * rsqrtf(q4.z * (1.f / NN) - m2 * m2 + 1e-5f);
        float sc3 = w4.w * rsqrtf(q4.w * (1.f / NN) - m3 * m3 + 1e-5f);
        float sh0 = b4.x - m0 * sc0, sh1 = b4.y - m1 * sc1;
        float sh2 = b4.z - m2 * sc2, sh3 = b4.w - m3 * sc3;
        float gb0 = gb[0];
        for (int n = lo + w; n < hi; n += 4) {
            float4 p = *(const float4*)(P + n * 256 + lane * 4);
            float d = lrelu(fmaf(p.x, sc0, sh0)) * g4.x
                    + lrelu(fmaf(p.y, sc1, sh1)) * g4.y
                    + lrelu(fmaf(p.z, sc2, sh2)) * g4.z
                    + lrelu(fmaf(p.w, sc3, sh3)) * g4.w;
#pragma unroll
            for (int off = 32; off > 0; off >>= 1) d += __shfl_xor(d, off, 64);
            if (lane == 0) gl[n - lo] = d + gb0;
        }
    }
    __syncthreads();
    // phase B: softmax max + denom over gl[0..cnt)
    int cnt = hi - lo;
    float lm = -3.0e38f;
    for (int i = t; i < cnt; i += 256) lm = fmaxf(lm, gl[i]);
#pragma unroll
    for (int off = 32; off > 0; off >>= 1) lm = fmaxf(lm, __shfl_xor(lm, off, 64));
    if (lane == 0) rr[w] = lm;
    __syncthreads();
    float mx = fmaxf(fmaxf(rr[0], rr[1]), fmaxf(rr[2], rr[3]));
    float ls = 0.f;
    for (int i = t; i < cnt; i += 256) { float e = expf(gl[i] - mx); gl[i] = e; ls += e; }
#pragma unroll
    for (int off = 32; off > 0; off >>= 1) ls += __shfl_xor(ls, off, 64);
    if (lane == 0) rr[4 + w] = ls;
    __syncthreads();
    float sinv = 1.f / (rr[4] + rr[5] + rr[6] + rr[7]);
    // phase C: weighted accumulate, thread t = channel t (P slice is L2-hot)
    float mean = ST[t] * (1.f / NN);
    float var = ST[256 + t] * (1.f / NN) - mean * mean;
    float sc = bw[t] * rsqrtf(var + 1e-5f);
    float sh = bb[t] - mean * sc;
    float a0 = 0.f, a1 = 0.f, a2 = 0.f, a3 = 0.f;
    int n = lo;
    for (; n + 4 <= hi; n += 4) {
        float p0 = P[n * 256 + t], p1 = P[(n + 1) * 256 + t];
        float p2 = P[(n + 2) * 256 + t], p3 = P[(n + 3) * 256 + t];
        a0 = fmaf(gl[n - lo + 0], lrelu(fmaf(p0, sc, sh)), a0);
        a1 = fmaf(gl[n - lo + 1], lrelu(fmaf(p1, sc, sh)), a1);
        a2 = fmaf(gl[n - lo + 2], lrelu(fmaf(p2, sc, sh)), a2);
        a3 = fmaf(gl[n - lo + 3], lrelu(fmaf(p3, sc, sh)), a3);
    }
    for (; n < hi; ++n) a0 = fmaf(gl[n - lo], lrelu(fmaf(P[n * 256 + t], sc, sh)), a0);
    out[g * 256 + t] = (a0 + a1 + a2 + a3) * sinv;
}

extern "C" void kernel_launch(void* const* d_in, const int* in_sizes, int n_in,
                              void* d_out, int out_size, void* d_ws, size_t ws_size,
                              hipStream_t stream) {
    const int* node_ids = (const int*)d_in[0];
    const int* edge_index = (const int*)d_in[1];
    const float4* edge_attr = (const float4*)d_in[2];
    const int* batch = (const int*)d_in[3];
    const float* emb = (const float*)d_in[4];
    const float* c1l2w = (const float*)d_in[5];
    const float* c1l2b = (const float*)d_in[6];
    const float* c1lw = (const float*)d_in[7];
    const float* c1lb = (const float*)d_in[8];
    const float* bn1w = (const float*)d_in[9];
    const float* bn1b = (const float*)d_in[10];
    const float* c2l2w = (const float*)d_in[11];
    const float* c2l2b = (const float*)d_in[12];
    const float* c2lw = (const float*)d_in[13];
    const float* c2lb = (const float*)d_in[14];
    const float* bn2w = (const float*)d_in[15];
    const float* bn2b = (const float*)d_in[16];
    const float* gate_w = (const float*)d_in[17];
    const float* gate_b = (const float*)d_in[18];

    char* ws = (char*)d_ws;
    size_t oP = 0;                        // f32 [50000,256]
    size_t oQB = oP + 51200000;           // bf16 [50000,256]
    size_t oSE = oQB + 25600000;          // uint4 [800000] packed edge records
    size_t oRK = oSE + 12800000;          // int [800000] per-edge rank
    size_t oRS = oRK + 3200000;           // int [50001]
    size_t oCNT = oRS + 200064;           // int [50000]
    size_t oLP = oCNT + 200000;           // int [50000]
    size_t oBS = oLP + 200000;            // int [256]
    size_t oBX = oBS + 1024;              // int [256]
    size_t oTY = oBX + 1024;              // bf16 [51,256]
    size_t oWC1 = oTY + 52224;            // f32 [256,4]
    size_t oWC2 = oWC1 + 4096;            // f32 [256,4]
    size_t oCB2 = oWC2 + 4096;            // f32 [256]
    size_t oW2B = oCB2 + 1024;            // bf16 [256,256]
    size_t oST = oW2B + 131072;           // f32 [1024]: ST1+ST2
    size_t oPARTS = oST + 4096;           // f32 [256,512] stats accumulator
    size_t oGS = oPARTS + 524288;         // int [513]

    float* P = (float*)(ws + oP);
    bf16_t* QB = (bf16_t*)(ws + oQB);
    uint4* SE = (uint4*)(ws + oSE);
    int* RK = (int*)(ws + oRK);
    int* RS = (int*)(ws + oRS);
    int* CNT = (int*)(ws + oCNT);
    int* LP = (int*)(ws + oLP);
    int* BS = (int*)(ws + oBS);
    int* BX = (int*)(ws + oBX);
    bf16_t* TYB = (bf16_t*)(ws + oTY);
    float* WC1 = (float*)(ws + oWC1);
    float* WC2 = (float*)(ws + oWC2);
    float* CB2 = (float*)(ws + oCB2);
    bf16_t* W2B = (bf16_t*)(ws + oW2B);
    float* ST1 = (float*)(ws + oST);
    float* ST2 = ST1 + 512;
    float* PARTS = (float*)(ws + oPARTS);
    int* GS = (int*)(ws + oGS);

    // one memset covers ST1+ST2 (4 KB) and PARTS (512 KB), contiguous
    hipMemsetAsync(ST1, 0, 4096 + 524288, stream);

    gme_setup<<<313, 256, 0, stream>>>(emb, c1lw, c1l2w, c1l2b, c1lb,
                                       c2lw, c2l2w, c2l2b, c2lb,
                                       TYB, WC1, WC2, CB2, W2B, CNT);
    gme_count<<<NE / 256, 256, 0, stream>>>(edge_index, CNT, RK);
    gme_scan1<<<256, 256, 0, stream>>>(CNT, LP, BS);
    gme_scan2<<<1, 256, 0, stream>>>(BS, BX, RS);
    gme_scan3<<<256, 256, 0, stream>>>(LP, BX, RS, batch, GS);
    gme_scatter<<<NE / 256, 256, 0, stream>>>(edge_index, edge_attr, node_ids,
                                              RS, RK, SE);
    // conv1: bf16 TY table in LDS, packed SE stream, BN1 stats fused -> PARTS
    gme_conv0<<<NN / 16, 256, 0, stream>>>(RS, SE, TYB, WC1, P, PARTS);
    gme_bred<<<16, 512, 0, stream>>>(PARTS, ST1, 1);   // -> ST1, re-zero PARTS
    gme_gemm<<<(NN / 16 + 3) / 4, 256, 0, stream>>>(P, ST1, bn1w, bn1b, W2B, CB2, QB);
    // conv2: SE-batch software pipeline, BN2 stats fused -> PARTS
    gme_conv1<<<NN / 4, 256, 0, stream>>>(RS, SE, QB, WC2, P, PARTS);
    gme_bred<<<16, 512, 0, stream>>>(PARTS, ST2, 0);   // -> ST2
    gme_attn<<<NG, 256, 0, stream>>>(GS, P, ST2, bn2w, bn2b, gate_w, gate_b,
                                     (float*)d_out);
}

// Round 12
// 355.404 us; speedup vs baseline: 1.2152x; 1.0231x over previous
//
#include <hip/hip_runtime.h>
#include <hip/hip_bf16.h>

#define NN 50000
#define NE 800000
#define NG 512

typedef __bf16 bf16_t;
typedef __bf16 bf16x8 __attribute__((ext_vector_type(8)));
typedef __bf16 bf16x4 __attribute__((ext_vector_type(4)));
typedef float f32x4 __attribute__((ext_vector_type(4)));
typedef float f32x2 __attribute__((ext_vector_type(2)));

__device__ __forceinline__ float lrelu(float v) { return v >= 0.f ? v : 0.01f * v; }

// unpack 2 bf16 (packed in one u32) -> float2 (pair order: lo, hi)
__device__ __forceinline__ f32x2 unpk2(unsigned w) {
    union { unsigned u; float f; } lo, hi;
    lo.u = w << 16;
    hi.u = w & 0xffff0000u;
    f32x2 r; r[0] = lo.f; r[1] = hi.f; return r;
}

// pack 2 f32 -> u32 of 2 bf16 (RTN via cast)
__device__ __forceinline__ unsigned pk2(float a, float b) {
    union { bf16_t h[2]; unsigned u; } p;
    p.h[0] = (bf16_t)a; p.h[1] = (bf16_t)b;
    return p.u;
}

// opaque per-lane zero: forces VGPR addressing (vmcnt path) for loads that the
// compiler would otherwise scalarize onto the s_load/lgkmcnt path.
__device__ __forceinline__ int vzero() {
    int vz;
    asm("v_mov_b32 %0, 0" : "=v"(vz));
    return vz;
}

// ---------------- tiny precomputes + CNT zeroing ----------------
__global__ void gme_setup(const float* __restrict__ emb,
                          const float* __restrict__ c1lw, const float* __restrict__ c1l2w,
                          const float* __restrict__ c1l2b, const float* __restrict__ c1lb,
                          const float* __restrict__ c2lw, const float* __restrict__ c2l2w,
                          const float* __restrict__ c2l2b, const float* __restrict__ c2lb,
                          bf16_t* __restrict__ TYB, float* __restrict__ WC1,
                          float* __restrict__ WC2, float* __restrict__ CB2,
                          bf16_t* __restrict__ W2B, int* __restrict__ CNT) {
    int b = blockIdx.x, t = threadIdx.x;
    if (b < 51) {
        const float4* er = (const float4*)(emb + b * 128);
        const float4* zb = (const float4*)c1l2b;
        const float4* wr = (const float4*)(c1lw + t * 128);
        float s = 0.f;
        for (int k = 0; k < 32; ++k) {
            float4 e = er[k], z = zb[k], w = wr[k];
            s += (e.x + z.x) * w.x + (e.y + z.y) * w.y + (e.z + z.z) * w.z + (e.w + z.w) * w.w;
        }
        TYB[b * 256 + t] = (bf16_t)(s + c1lb[t]);
    } else if (b == 51) {
        const float4* wr = (const float4*)(c1lw + t * 128);
        const float4* cw = (const float4*)c1l2w;
        float4 a = make_float4(0.f, 0.f, 0.f, 0.f);
        for (int k = 0; k < 32; ++k) {
            float4 w = wr[k];
            float4 c0 = cw[k * 4 + 0], c1 = cw[k * 4 + 1], c2 = cw[k * 4 + 2], c3 = cw[k * 4 + 3];
            a.x += w.x * c0.x + w.y * c1.x + w.z * c2.x + w.w * c3.x;
            a.y += w.x * c0.y + w.y * c1.y + w.z * c2.y + w.w * c3.y;
            a.z += w.x * c0.z + w.y * c1.z + w.z * c2.z + w.w * c3.z;
            a.w += w.x * c0.w + w.y * c1.w + w.z * c2.w + w.w * c3.w;
        }
        ((float4*)WC1)[t] = a;
    } else if (b == 52) {
        const float4* wr = (const float4*)(c2lw + t * 256);
        const float4* cw = (const float4*)c2l2w;
        const float4* zb = (const float4*)c2l2b;
        float4 a = make_float4(0.f, 0.f, 0.f, 0.f);
        float ab = 0.f;
        for (int k = 0; k < 64; ++k) {
            float4 w = wr[k];
            float4 c0 = cw[k * 4 + 0], c1 = cw[k * 4 + 1], c2 = cw[k * 4 + 2], c3 = cw[k * 4 + 3];
            float4 z = zb[k];
            a.x += w.x * c0.x + w.y * c1.x + w.z * c2.x + w.w * c3.x;
            a.y += w.x * c0.y + w.y * c1.y + w.z * c2.y + w.w * c3.y;
            a.z += w.x * c0.z + w.y * c1.z + w.z * c2.z + w.w * c3.z;
            a.w += w.x * c0.w + w.y * c1.w + w.z * c2.w + w.w * c3.w;
            ab += w.x * z.x + w.y * z.y + w.z * z.z + w.w * z.w;
        }
        ((float4*)WC2)[t] = a;
        CB2[t] = ab + c2lb[t];
    } else if (b < 117) {
        int i0 = (b - 53) * 1024;
        for (int r = 0; r < 4; ++r) {
            int i = i0 + r * 256 + t;
            W2B[i] = (bf16_t)c2lw[i];
        }
    } else {
        int i = (b - 117) * 256 + t;
        if (i < NN) CNT[i] = 0;
    }
}

// ---------------- CSR build ----------------
__global__ void gme_count(const int* __restrict__ ei, int* __restrict__ cnt,
                          int* __restrict__ RK) {
    int e = blockIdx.x * 256 + threadIdx.x;
    if (e >= NE) return;
    RK[e] = atomicAdd(&cnt[ei[NE + e]], 1);
}

__global__ void gme_scan1(const int* __restrict__ CNT, int* __restrict__ LP,
                          int* __restrict__ BS) {
    __shared__ int lds[256];
    int b = blockIdx.x, t = threadIdx.x;
    int i = b * 196 + t;
    int v = (t < 196 && i < NN) ? CNT[i] : 0;
    lds[t] = v;
    __syncthreads();
    for (int off = 1; off < 256; off <<= 1) {
        int u = (t >= off) ? lds[t - off] : 0;
        __syncthreads();
        lds[t] += u;
        __syncthreads();
    }
    if (t < 196 && i < NN) LP[i] = lds[t] - v;
    if (t == 255) BS[b] = lds[255];
}

__global__ void gme_scan2(const int* __restrict__ BS, int* __restrict__ BX,
                          int* __restrict__ RS) {
    __shared__ int lds[256];
    int t = threadIdx.x;
    int v = BS[t];
    lds[t] = v;
    __syncthreads();
    for (int off = 1; off < 256; off <<= 1) {
        int u = (t >= off) ? lds[t - off] : 0;
        __syncthreads();
        lds[t] += u;
        __syncthreads();
    }
    BX[t] = lds[t] - v;
    if (t == 255) RS[NN] = lds[255];
}

// scan3 + graph-segment boundaries fused
__global__ void gme_scan3(const int* __restrict__ LP, const int* __restrict__ BX,
                          int* __restrict__ RS,
                          const int* __restrict__ batch, int* __restrict__ GS) {
    int b = blockIdx.x, t = threadIdx.x;
    if (t >= 196) return;
    int i = b * 196 + t;
    if (i >= NN) return;
    RS[i] = BX[b] + LP[i];
    int bb = batch[i];
    if (i == 0) {
        for (int g = 0; g <= bb; ++g) GS[g] = 0;
    } else {
        int a = batch[i - 1];
        for (int g = a + 1; g <= bb; ++g) GS[g] = i;
    }
    if (i == NN - 1) {
        for (int g = bb + 1; g <= NG; ++g) GS[g] = NN;
    }
}

// single 16B record per edge; pos from persisted rank -> no atomic
__global__ void gme_scatter(const int* __restrict__ ei,
                            const float4* __restrict__ eattr,
                            const int* __restrict__ node_ids,
                            const int* __restrict__ RS, const int* __restrict__ RK,
                            uint4* __restrict__ SE) {
    int e = blockIdx.x * 256 + threadIdx.x;
    if (e >= NE) return;
    int s = ei[e];
    int d = ei[NE + e];
    int nid = node_ids[s];
    float4 at = eattr[e];
    int pos = RS[d] + RK[e];
    SE[pos] = make_uint4((unsigned)(s | (nid << 16)), pk2(at.x, at.y), pk2(at.z, at.w), 0u);
}

// ---------------- conv1 layer: bf16 TY in LDS; SE pipeline; bf16 P out ------
__global__ __launch_bounds__(256) void gme_conv0(
        const int* __restrict__ RS, const uint4* __restrict__ SE,
        const bf16_t* __restrict__ TYB, const float* __restrict__ Wc,
        bf16_t* __restrict__ agg, float* __restrict__ PARTS) {
    __shared__ __align__(16) uint2 sTY[51 * 64];  // 26112 B bf16 table
    {
        const uint4* s4 = (const uint4*)TYB;
        uint4* d4 = (uint4*)sTY;
        for (int i = threadIdx.x; i < 51 * 32; i += 256) d4[i] = s4[i];
    }
    __syncthreads();
    int lane = threadIdx.x & 63;
    int w = threadIdx.x >> 6;
    int vz = vzero();
    const float4* wc4 = (const float4*)Wc;
    int c4 = lane * 4;
    float4 w0 = wc4[c4 + 0], w1 = wc4[c4 + 1], w2 = wc4[c4 + 2], w3 = wc4[c4 + 3];
    f32x2 wA0 = {w0.x, w1.x}, wB0 = {w0.y, w1.y}, wC0 = {w0.z, w1.z}, wD0 = {w0.w, w1.w};
    f32x2 wA1 = {w2.x, w3.x}, wB1 = {w2.y, w3.y}, wC1 = {w2.z, w3.z}, wD1 = {w2.w, w3.w};
    const f32x2 zero = {0.f, 0.f};
    const uint2* lrow = sTY + lane;
    int base = blockIdx.x * 16 + w * 4;
    f32x2 ssum0 = zero, ssum1 = zero, qsum0 = zero, qsum1 = zero;
#pragma unroll 1
    for (int k = 0; k < 4; ++k) {
        int node = __builtin_amdgcn_readfirstlane(base + k);
        int rs = RS[node], re = RS[node + 1];
        f32x2 accP0 = zero, accP1 = zero, accA0 = zero, accA1 = zero;
        auto accum = [&](uint4 se, uint2 r) {
            f32x2 y0 = unpk2(r.x), y1 = unpk2(r.y);
            f32x2 axy = unpk2(se.y), azw = unpk2(se.z);
            f32x2 ax = {axy[0], axy[0]}, ay = {axy[1], axy[1]};
            f32x2 az = {azw[0], azw[0]}, aw = {azw[1], azw[1]};
            f32x2 m0 = __builtin_elementwise_fma(ax, wA0, y0);
            f32x2 m1 = __builtin_elementwise_fma(ax, wA1, y1);
            m0 = __builtin_elementwise_fma(ay, wB0, m0);
            m1 = __builtin_elementwise_fma(ay, wB1, m1);
            m0 = __builtin_elementwise_fma(az, wC0, m0);
            m1 = __builtin_elementwise_fma(az, wC1, m1);
            m0 = __builtin_elementwise_fma(aw, wD0, m0);
            m1 = __builtin_elementwise_fma(aw, wD1, m1);
            accA0 += m0; accA1 += m1;
            accP0 += __builtin_elementwise_max(m0, zero);
            accP1 += __builtin_elementwise_max(m1, zero);
        };
        int j = rs;
        // software pipeline: SE batch k+1 loads while batch k computes
        if (j + 8 <= re) {
            uint4 se[8];
#pragma unroll
            for (int u = 0; u < 8; ++u) se[u] = SE[j + u + vz];
            while (true) {
                uint2 r[8];
#pragma unroll
                for (int u = 0; u < 8; ++u) r[u] = lrow[(se[u].x >> 16) << 6];
                bool more = (j + 16 <= re);
                uint4 seN[8];
                if (more) {
#pragma unroll
                    for (int u = 0; u < 8; ++u) seN[u] = SE[j + 8 + u + vz];
                }
#pragma unroll
                for (int u = 0; u < 8; ++u) accum(se[u], r[u]);
                j += 8;
                if (!more) break;
#pragma unroll
                for (int u = 0; u < 8; ++u) se[u] = seN[u];
            }
        }
        if (j + 4 <= re) {
            uint4 se[4]; uint2 r[4];
#pragma unroll
            for (int u = 0; u < 4; ++u) se[u] = SE[j + u + vz];
#pragma unroll
            for (int u = 0; u < 4; ++u) r[u] = lrow[(se[u].x >> 16) << 6];
#pragma unroll
            for (int u = 0; u < 4; ++u) accum(se[u], r[u]);
            j += 4;
        }
        for (; j < re; ++j) {
            uint4 se = SE[j + vz];
            accum(se, lrow[(se.x >> 16) << 6]);
        }
        const f32x2 c99 = {0.99f, 0.99f}, c01 = {0.01f, 0.01f};
        f32x2 o0 = __builtin_elementwise_fma(accP0, c99, accA0 * c01);
        f32x2 o1 = __builtin_elementwise_fma(accP1, c99, accA1 * c01);
        uint2 ov;
        ov.x = pk2(o0[0], o0[1]);
        ov.y = pk2(o1[0], o1[1]);
        *((uint2*)(agg + node * 256) + lane) = ov;
        ssum0 += o0; ssum1 += o1;
        qsum0 += o0 * o0; qsum1 += o1 * o1;
    }
    // fused BN1 partial stats
    __syncthreads();
    float* red = (float*)sTY;
    red[w * 512 + c4 + 0] = ssum0[0]; red[w * 512 + c4 + 1] = ssum0[1];
    red[w * 512 + c4 + 2] = ssum1[0]; red[w * 512 + c4 + 3] = ssum1[1];
    red[w * 512 + 256 + c4 + 0] = qsum0[0]; red[w * 512 + 256 + c4 + 1] = qsum0[1];
    red[w * 512 + 256 + c4 + 2] = qsum1[0]; red[w * 512 + 256 + c4 + 3] = qsum1[1];
    __syncthreads();
    int cc = threadIdx.x;
    float s = red[cc] + red[512 + cc] + red[1024 + cc] + red[1536 + cc];
    float q = red[256 + cc] + red[768 + cc] + red[1280 + cc] + red[1792 + cc];
    int prow = (blockIdx.x & 255) * 512;
    atomicAdd(&PARTS[prow + cc], s);
    atomicAdd(&PARTS[prow + 256 + cc], q);
}

// ---------------- conv2 layer: random gather; SE pipeline; bf16 P out -------
__global__ __launch_bounds__(256, 4) void gme_conv1(
        const int* __restrict__ RS, const uint4* __restrict__ SE,
        const bf16_t* __restrict__ QB, const float* __restrict__ Wc,
        bf16_t* __restrict__ agg, float* __restrict__ PARTS) {
    __shared__ float red[2048];
    int lane = threadIdx.x & 63;
    int w = threadIdx.x >> 6;
    int node = __builtin_amdgcn_readfirstlane(blockIdx.x * 4 + w);
    const float4* wc4 = (const float4*)Wc;
    int c4 = lane * 4;
    float4 w0 = wc4[c4 + 0], w1 = wc4[c4 + 1], w2 = wc4[c4 + 2], w3 = wc4[c4 + 3];
    f32x2 wA0 = {w0.x, w1.x}, wB0 = {w0.y, w1.y}, wC0 = {w0.z, w1.z}, wD0 = {w0.w, w1.w};
    f32x2 wA1 = {w2.x, w3.x}, wB1 = {w2.y, w3.y}, wC1 = {w2.z, w3.z}, wD1 = {w2.w, w3.w};
    const f32x2 zero = {0.f, 0.f};
    f32x2 accP0 = zero, accP1 = zero, accA0 = zero, accA1 = zero;
    int rs = RS[node], re = RS[node + 1];
    const char* yb = (const char*)QB;
    unsigned loff = (unsigned)(lane << 3);
    auto rowld = [&](unsigned row) -> uint2 {
        return *(const uint2*)(yb + (row << 9) + loff);
    };
    auto accum = [&](uint4 se, uint2 r) {
        f32x2 y0 = unpk2(r.x), y1 = unpk2(r.y);
        f32x2 axy = unpk2(se.y), azw = unpk2(se.z);
        f32x2 ax = {axy[0], axy[0]}, ay = {axy[1], axy[1]};
        f32x2 az = {azw[0], azw[0]}, aw = {azw[1], azw[1]};
        f32x2 m0 = __builtin_elementwise_fma(ax, wA0, y0);
        f32x2 m1 = __builtin_elementwise_fma(ax, wA1, y1);
        m0 = __builtin_elementwise_fma(ay, wB0, m0);
        m1 = __builtin_elementwise_fma(ay, wB1, m1);
        m0 = __builtin_elementwise_fma(az, wC0, m0);
        m1 = __builtin_elementwise_fma(az, wC1, m1);
        m0 = __builtin_elementwise_fma(aw, wD0, m0);
        m1 = __builtin_elementwise_fma(aw, wD1, m1);
        accA0 += m0; accA1 += m1;
        accP0 += __builtin_elementwise_max(m0, zero);
        accP1 += __builtin_elementwise_max(m1, zero);
    };
    int j = rs;
    if (j + 8 <= re) {
        uint4 se[8];
#pragma unroll
        for (int u = 0; u < 8; ++u) se[u] = SE[j + u];
        while (true) {
            uint2 r[8];
#pragma unroll
            for (int u = 0; u < 8; ++u) r[u] = rowld(se[u].x & 0xffffu);
            bool more = (j + 16 <= re);
            uint4 seN[8];
            if (more) {
#pragma unroll
                for (int u = 0; u < 8; ++u) seN[u] = SE[j + 8 + u];
            }
#pragma unroll
            for (int u = 0; u < 8; ++u) accum(se[u], r[u]);
            j += 8;
            if (!more) break;
#pragma unroll
            for (int u = 0; u < 8; ++u) se[u] = seN[u];
        }
    }
    if (j + 4 <= re) {
        uint4 se[4]; uint2 r[4];
#pragma unroll
        for (int u = 0; u < 4; ++u) se[u] = SE[j + u];
#pragma unroll
        for (int u = 0; u < 4; ++u) r[u] = rowld(se[u].x & 0xffffu);
#pragma unroll
        for (int u = 0; u < 4; ++u) accum(se[u], r[u]);
        j += 4;
    }
    for (; j < re; ++j) {
        uint4 se = SE[j];
        accum(se, rowld(se.x & 0xffffu));
    }
    const f32x2 c99 = {0.99f, 0.99f}, c01 = {0.01f, 0.01f};
    f32x2 o0 = __builtin_elementwise_fma(accP0, c99, accA0 * c01);
    f32x2 o1 = __builtin_elementwise_fma(accP1, c99, accA1 * c01);
    uint2 ov;
    ov.x = pk2(o0[0], o0[1]);
    ov.y = pk2(o1[0], o1[1]);
    *((uint2*)(agg + node * 256) + lane) = ov;
    // fused BN2 partial stats (from f32 pre-quantize values)
    red[w * 512 + c4 + 0] = o0[0]; red[w * 512 + c4 + 1] = o0[1];
    red[w * 512 + c4 + 2] = o1[0]; red[w * 512 + c4 + 3] = o1[1];
    red[w * 512 + 256 + c4 + 0] = o0[0] * o0[0];
    red[w * 512 + 256 + c4 + 1] = o0[1] * o0[1];
    red[w * 512 + 256 + c4 + 2] = o1[0] * o1[0];
    red[w * 512 + 256 + c4 + 3] = o1[1] * o1[1];
    __syncthreads();
    int cc = threadIdx.x;
    float s = red[cc] + red[512 + cc] + red[1024 + cc] + red[1536 + cc];
    float q = red[256 + cc] + red[768 + cc] + red[1280 + cc] + red[1792 + cc];
    int prow = (blockIdx.x & 255) * 512;
    atomicAdd(&PARTS[prow + cc], s);
    atomicAdd(&PARTS[prow + 256 + cc], q);
}

// ---------------- PARTS (256x512) -> ST reducer; optionally re-zero ----------
__global__ __launch_bounds__(512) void gme_bred(float* __restrict__ PARTS,
                                                float* __restrict__ ST, int zero) {
    int t = threadIdx.x;
    int b = blockIdx.x;
    float acc = 0.f;
#pragma unroll
    for (int r = 0; r < 16; ++r) acc += PARTS[(b * 16 + r) * 512 + t];
    atomicAdd(&ST[t], acc);
    if (zero) {
#pragma unroll
        for (int r = 0; r < 16; ++r) PARTS[(b * 16 + r) * 512 + t] = 0.f;
    }
}

// ---------------- GEMM, BN1+LeakyReLU fused on A (bf16 P in) -----------------
__global__ __launch_bounds__(256) void gme_gemm(const bf16_t* __restrict__ P,
                                                const float* __restrict__ ST,
                                                const float* __restrict__ bw,
                                                const float* __restrict__ bb,
                                                const bf16_t* __restrict__ W2B,
                                                const float* __restrict__ CB2,
                                                bf16_t* __restrict__ QB) {
    __shared__ float s_sc[256], s_sh[256];
    __shared__ __align__(16) uint4 sB[8192];  // 128 KB, 16B-slot swizzled
    {
        int c = threadIdx.x;
        float mean = ST[c] * (1.f / NN);
        float var = ST[256 + c] * (1.f / NN) - mean * mean;
        float sc = bw[c] * rsqrtf(var + 1e-5f);
        s_sc[c] = sc;
        s_sh[c] = bb[c] - mean * sc;
        const uint4* w4 = (const uint4*)W2B;
#pragma unroll
        for (int it = 0; it < 32; ++it) {
            int i = it * 256 + c;
            int row = i >> 5, slot = i & 31;
            sB[(row << 5) | (slot ^ (row & 7))] = w4[i];
        }
    }
    __syncthreads();
    int lane = threadIdx.x & 63;
    int wave = blockIdx.x * 4 + (threadIdx.x >> 6);
    if (wave >= NN / 16) return;
    int m0 = wave * 16;
    int r = lane & 15, q = lane >> 4;
    int rx = r & 7;
    const uint4* arow = (const uint4*)(P + (m0 + r) * 256);
    bf16x8 a[8];
#pragma unroll
    for (int kt = 0; kt < 8; ++kt) {
        int k0 = kt * 32 + q * 8;
        uint4 u = arow[q + kt * 4];
        f32x2 v0 = unpk2(u.x), v1 = unpk2(u.y), v2 = unpk2(u.z), v3 = unpk2(u.w);
        bf16x8 f;
        f[0] = (bf16_t)lrelu(fmaf(v0[0], s_sc[k0 + 0], s_sh[k0 + 0]));
        f[1] = (bf16_t)lrelu(fmaf(v0[1], s_sc[k0 + 1], s_sh[k0 + 1]));
        f[2] = (bf16_t)lrelu(fmaf(v1[0], s_sc[k0 + 2], s_sh[k0 + 2]));
        f[3] = (bf16_t)lrelu(fmaf(v1[1], s_sc[k0 + 3], s_sh[k0 + 3]));
        f[4] = (bf16_t)lrelu(fmaf(v2[0], s_sc[k0 + 4], s_sh[k0 + 4]));
        f[5] = (bf16_t)lrelu(fmaf(v2[1], s_sc[k0 + 5], s_sh[k0 + 5]));
        f[6] = (bf16_t)lrelu(fmaf(v3[0], s_sc[k0 + 6], s_sh[k0 + 6]));
        f[7] = (bf16_t)lrelu(fmaf(v3[1], s_sc[k0 + 7], s_sh[k0 + 7]));
        a[kt] = f;
    }
#pragma unroll 1
    for (int g = 0; g < 2; ++g) {
        f32x4 acc[8];
#pragma unroll
        for (int n8 = 0; n8 < 8; ++n8) acc[n8] = (f32x4){0.f, 0.f, 0.f, 0.f};
#pragma unroll
        for (int kt = 0; kt < 8; ++kt) {
            int slot = (kt * 4 + q) ^ rx;
            bf16x8 bf[8];
#pragma unroll
            for (int n8 = 0; n8 < 8; ++n8) {
                int row = g * 128 + n8 * 16 + r;
                bf[n8] = *(const bf16x8*)&sB[(row << 5) | slot];
            }
#pragma unroll
            for (int n8 = 0; n8 < 8; ++n8) {
                acc[n8] = __builtin_amdgcn_mfma_f32_16x16x32_bf16(bf[n8], a[kt], acc[n8], 0, 0, 0);
            }
        }
#pragma unroll
        for (int n8 = 0; n8 < 8; ++n8) {
            int nt = g * 8 + n8;
            float4 cbv = ((const float4*)CB2)[nt * 4 + q];
            bf16x4 o;
            o[0] = (bf16_t)(acc[n8][0] + cbv.x);
            o[1] = (bf16_t)(acc[n8][1] + cbv.y);
            o[2] = (bf16_t)(acc[n8][2] + cbv.z);
            o[3] = (bf16_t)(acc[n8][3] + cbv.w);
            *(bf16x4*)(QB + (m0 + r) * 256 + nt * 16 + q * 4) = o;
        }
    }
}

// ---------------- fused gate + attentional aggregation (bf16 P in) ----------
__global__ __launch_bounds__(256) void gme_attn(const int* __restrict__ GS,
                                                const bf16_t* __restrict__ P,
                                                const float* __restrict__ ST,
                                                const float* __restrict__ bw,
                                                const float* __restrict__ bb,
                                                const float* __restrict__ gw,
                                                const float* __restrict__ gb,
                                                float* __restrict__ out) {
    __shared__ float gl[1024];
    __shared__ float rr[8];
    int g = blockIdx.x, t = threadIdx.x;
    int lo = GS[g], hi = GS[g + 1];
    if (lo >= hi) { out[g * 256 + t] = 0.f; return; }
    int lane = t & 63, w = t >> 6;
    // phase A: per-node gates, wave-parallel
    {
        float4 s4 = ((const float4*)ST)[lane];
        float4 q4 = ((const float4*)(ST + 256))[lane];
        float4 w4 = ((const float4*)bw)[lane];
        float4 b4 = ((const float4*)bb)[lane];
        float4 g4 = ((const float4*)gw)[lane];
        float m0 = s4.x * (1.f / NN), m1 = s4.y * (1.f / NN);
        float m2 = s4.z * (1.f / NN), m3 = s4.w * (1.f / NN);
        float sc0 = w4.x * rsqrtf(q4.x * (1.f / NN) - m0 * m0 + 1e-5f);
        float sc1 = w4.y * rsqrtf(q4.y * (1.f / NN) - m1 * m1 + 1e-5f);
        float sc2 = w4.z * rsqrtf(q4.z * (1.f / NN) - m2 * m2 + 1e-5f);
        float sc3 = w4.w * rsqrtf(q4.w * (1.f / NN) - m3 * m3 + 1e-5f);
        float sh0 = b4.x - m0 * sc0, sh1 = b4.y - m1 * sc1;
        float sh2 = b4.z - m2 * sc2, sh3 = b4.w - m3 * sc3;
        float gb0 = gb[0];
        for (int n = lo + w; n < hi; n += 4) {
            uint2 u = *((const uint2*)(P + n * 256) + lane);
            f32x2 p01 = unpk2(u.x), p23 = unpk2(u.y);
            float d = lrelu(fmaf(p01[0], sc0, sh0)) * g4.x
                    + lrelu(fmaf(p01[1], sc1, sh1)) * g4.y
                    + lrelu(fmaf(p23[0], sc2, sh2)) * g4.z
                    + lrelu(fmaf(p23[1], sc3, sh3)) * g4.w;
#pragma unroll
            for (int off = 32; off > 0; off >>= 1) d += __shfl_xor(d, off, 64);
            if (lane == 0) gl[n - lo] = d + gb0;
        }
    }
    __syncthreads();
    // phase B: softmax max + denom
    int cnt = hi - lo;
    float lm = -3.0e38f;
    for (int i = t; i < cnt; i += 256) lm = fmaxf(lm, gl[i]);
#pragma unroll
    for (int off = 32; off > 0; off >>= 1) lm = fmaxf(lm, __shfl_xor(lm, off, 64));
    if (lane == 0) rr[w] = lm;
    __syncthreads();
    float mx = fmaxf(fmaxf(rr[0], rr[1]), fmaxf(rr[2], rr[3]));
    float ls = 0.f;
    for (int i = t; i < cnt; i += 256) { float e = expf(gl[i] - mx); gl[i] = e; ls += e; }
#pragma unroll
    for (int off = 32; off > 0; off >>= 1) ls += __shfl_xor(ls, off, 64);
    if (lane == 0) rr[4 + w] = ls;
    __syncthreads();
    float sinv = 1.f / (rr[4] + rr[5] + rr[6] + rr[7]);
    // phase C: weighted accumulate, thread t = channel t
    float mean = ST[t] * (1.f / NN);
    float var = ST[256 + t] * (1.f / NN) - mean * mean;
    float sc = bw[t] * rsqrtf(var + 1e-5f);
    float sh = bb[t] - mean * sc;
    float a0 = 0.f, a1 = 0.f, a2 = 0.f, a3 = 0.f;
    int n = lo;
    for (; n + 4 <= hi; n += 4) {
        float p0 = (float)P[n * 256 + t], p1 = (float)P[(n + 1) * 256 + t];
        float p2 = (float)P[(n + 2) * 256 + t], p3 = (float)P[(n + 3) * 256 + t];
        a0 = fmaf(gl[n - lo + 0], lrelu(fmaf(p0, sc, sh)), a0);
        a1 = fmaf(gl[n - lo + 1], lrelu(fmaf(p1, sc, sh)), a1);
        a2 = fmaf(gl[n - lo + 2], lrelu(fmaf(p2, sc, sh)), a2);
        a3 = fmaf(gl[n - lo + 3], lrelu(fmaf(p3, sc, sh)), a3);
    }
    for (; n < hi; ++n) a0 = fmaf(gl[n - lo], lrelu(fmaf((float)P[n * 256 + t], sc, sh)), a0);
    out[g * 256 + t] = (a0 + a1 + a2 + a3) * sinv;
}

extern "C" void kernel_launch(void* const* d_in, const int* in_sizes, int n_in,
                              void* d_out, int out_size, void* d_ws, size_t ws_size,
                              hipStream_t stream) {
    const int* node_ids = (const int*)d_in[0];
    const int* edge_index = (const int*)d_in[1];
    const float4* edge_attr = (const float4*)d_in[2];
    const int* batch = (const int*)d_in[3];
    const float* emb = (const float*)d_in[4];
    const float* c1l2w = (const float*)d_in[5];
    const float* c1l2b = (const float*)d_in[6];
    const float* c1lw = (const float*)d_in[7];
    const float* c1lb = (const float*)d_in[8];
    const float* bn1w = (const float*)d_in[9];
    const float* bn1b = (const float*)d_in[10];
    const float* c2l2w = (const float*)d_in[11];
    const float* c2l2b = (const float*)d_in[12];
    const float* c2lw = (const float*)d_in[13];
    const float* c2lb = (const float*)d_in[14];
    const float* bn2w = (const float*)d_in[15];
    const float* bn2b = (const float*)d_in[16];
    const float* gate_w = (const float*)d_in[17];
    const float* gate_b = (const float*)d_in[18];

    char* ws = (char*)d_ws;
    size_t oP = 0;                        // bf16 [50000,256]
    size_t oQB = oP + 25600000;           // bf16 [50000,256]
    size_t oSE = oQB + 25600000;          // uint4 [800000]
    size_t oRK = oSE + 12800000;          // int [800000]
    size_t oRS = oRK + 3200000;           // int [50001]
    size_t oCNT = oRS + 200064;           // int [50000]
    size_t oLP = oCNT + 200000;           // int [50000]
    size_t oBS = oLP + 200000;            // int [256]
    size_t oBX = oBS + 1024;              // int [256]
    size_t oTY = oBX + 1024;              // bf16 [51,256]
    size_t oWC1 = oTY + 52224;            // f32 [256,4]
    size_t oWC2 = oWC1 + 4096;            // f32 [256,4]
    size_t oCB2 = oWC2 + 4096;            // f32 [256]
    size_t oW2B = oCB2 + 1024;            // bf16 [256,256]
    size_t oST = oW2B + 131072;           // f32 [1024]: ST1+ST2
    size_t oPARTS = oST + 4096;           // f32 [256,512]
    size_t oGS = oPARTS + 524288;         // int [513]

    bf16_t* P = (bf16_t*)(ws + oP);
    bf16_t* QB = (bf16_t*)(ws + oQB);
    uint4* SE = (uint4*)(ws + oSE);
    int* RK = (int*)(ws + oRK);
    int* RS = (int*)(ws + oRS);
    int* CNT = (int*)(ws + oCNT);
    int* LP = (int*)(ws + oLP);
    int* BS = (int*)(ws + oBS);
    int* BX = (int*)(ws + oBX);
    bf16_t* TYB = (bf16_t*)(ws + oTY);
    float* WC1 = (float*)(ws + oWC1);
    float* WC2 = (float*)(ws + oWC2);
    float* CB2 = (float*)(ws + oCB2);
    bf16_t* W2B = (bf16_t*)(ws + oW2B);
    float* ST1 = (float*)(ws + oST);
    float* ST2 = ST1 + 512;
    float* PARTS = (float*)(ws + oPARTS);
    int* GS = (int*)(ws + oGS);

    // one memset covers ST1+ST2 (4 KB) and PARTS (512 KB), contiguous
    hipMemsetAsync(ST1, 0, 4096 + 524288, stream);

    gme_setup<<<313, 256, 0, stream>>>(emb, c1lw, c1l2w, c1l2b, c1lb,
                                       c2lw, c2l2w, c2l2b, c2lb,
                                       TYB, WC1, WC2, CB2, W2B, CNT);
    gme_count<<<NE / 256, 256, 0, stream>>>(edge_index, CNT, RK);
    gme_scan1<<<256, 256, 0, stream>>>(CNT, LP, BS);
    gme_scan2<<<1, 256, 0, stream>>>(BS, BX, RS);
    gme_scan3<<<256, 256, 0, stream>>>(LP, BX, RS, batch, GS);
    gme_scatter<<<NE / 256, 256, 0, stream>>>(edge_index, edge_attr, node_ids,
                                              RS, RK, SE);
    // conv1: bf16 TY in LDS, SE pipeline, BN1 stats fused -> PARTS
    gme_conv0<<<NN / 16, 256, 0, stream>>>(RS, SE, TYB, WC1, P, PARTS);
    gme_bred<<<16, 512, 0, stream>>>(PARTS, ST1, 1);   // -> ST1, re-zero PARTS
    gme_gemm<<<(NN / 16 + 3) / 4, 256, 0, stream>>>(P, ST1, bn1w, bn1b, W2B, CB2, QB);
    // conv2: SE pipeline, BN2 stats fused -> PARTS
    gme_conv1<<<NN / 4, 256, 0, stream>>>(RS, SE, QB, WC2, P, PARTS);
    gme_bred<<<16, 512, 0, stream>>>(PARTS, ST2, 0);   // -> ST2
    gme_attn<<<NG, 256, 0, stream>>>(GS, P, ST2, bn2w, bn2b, gate_w, gate_b,
                                     (float*)d_out);
}

// Round 13
// 351.547 us; speedup vs baseline: 1.2286x; 1.0110x over previous
//
#include <hip/hip_runtime.h>
#include <hip/hip_bf16.h>

#define NN 50000
#define NE 800000
#define NG 512

typedef __bf16 bf16_t;
typedef __bf16 bf16x8 __attribute__((ext_vector_type(8)));
typedef __bf16 bf16x4 __attribute__((ext_vector_type(4)));
typedef float f32x4 __attribute__((ext_vector_type(4)));
typedef float f32x2 __attribute__((ext_vector_type(2)));

__device__ __forceinline__ float lrelu(float v) { return v >= 0.f ? v : 0.01f * v; }

// unpack 2 bf16 (packed in one u32) -> float2 (pair order: lo, hi)
__device__ __forceinline__ f32x2 unpk2(unsigned w) {
    union { unsigned u; float f; } lo, hi;
    lo.u = w << 16;
    hi.u = w & 0xffff0000u;
    f32x2 r; r[0] = lo.f; r[1] = hi.f; return r;
}

// pack 2 f32 -> u32 of 2 bf16 (RTN via cast)
__device__ __forceinline__ unsigned pk2(float a, float b) {
    union { bf16_t h[2]; unsigned u; } p;
    p.h[0] = (bf16_t)a; p.h[1] = (bf16_t)b;
    return p.u;
}

// opaque per-lane zero: forces VGPR addressing (vmcnt path) for loads that the
// compiler would otherwise scalarize onto the s_load/lgkmcnt path.
__device__ __forceinline__ int vzero() {
    int vz;
    asm("v_mov_b32 %0, 0" : "=v"(vz));
    return vz;
}

// ---------------- tiny precomputes + CNT zeroing ----------------
__global__ void gme_setup(const float* __restrict__ emb,
                          const float* __restrict__ c1lw, const float* __restrict__ c1l2w,
                          const float* __restrict__ c1l2b, const float* __restrict__ c1lb,
                          const float* __restrict__ c2lw, const float* __restrict__ c2l2w,
                          const float* __restrict__ c2l2b, const float* __restrict__ c2lb,
                          bf16_t* __restrict__ TYB, float* __restrict__ WC1,
                          float* __restrict__ WC2, float* __restrict__ CB2,
                          bf16_t* __restrict__ W2B, int* __restrict__ CNT) {
    int b = blockIdx.x, t = threadIdx.x;
    if (b < 51) {
        const float4* er = (const float4*)(emb + b * 128);
        const float4* zb = (const float4*)c1l2b;
        const float4* wr = (const float4*)(c1lw + t * 128);
        float s = 0.f;
        for (int k = 0; k < 32; ++k) {
            float4 e = er[k], z = zb[k], w = wr[k];
            s += (e.x + z.x) * w.x + (e.y + z.y) * w.y + (e.z + z.z) * w.z + (e.w + z.w) * w.w;
        }
        TYB[b * 256 + t] = (bf16_t)(s + c1lb[t]);
    } else if (b == 51) {
        const float4* wr = (const float4*)(c1lw + t * 128);
        const float4* cw = (const float4*)c1l2w;
        float4 a = make_float4(0.f, 0.f, 0.f, 0.f);
        for (int k = 0; k < 32; ++k) {
            float4 w = wr[k];
            float4 c0 = cw[k * 4 + 0], c1 = cw[k * 4 + 1], c2 = cw[k * 4 + 2], c3 = cw[k * 4 + 3];
            a.x += w.x * c0.x + w.y * c1.x + w.z * c2.x + w.w * c3.x;
            a.y += w.x * c0.y + w.y * c1.y + w.z * c2.y + w.w * c3.y;
            a.z += w.x * c0.z + w.y * c1.z + w.z * c2.z + w.w * c3.z;
            a.w += w.x * c0.w + w.y * c1.w + w.z * c2.w + w.w * c3.w;
        }
        ((float4*)WC1)[t] = a;
    } else if (b == 52) {
        const float4* wr = (const float4*)(c2lw + t * 256);
        const float4* cw = (const float4*)c2l2w;
        const float4* zb = (const float4*)c2l2b;
        float4 a = make_float4(0.f, 0.f, 0.f, 0.f);
        float ab = 0.f;
        for (int k = 0; k < 64; ++k) {
            float4 w = wr[k];
            float4 c0 = cw[k * 4 + 0], c1 = cw[k * 4 + 1], c2 = cw[k * 4 + 2], c3 = cw[k * 4 + 3];
            float4 z = zb[k];
            a.x += w.x * c0.x + w.y * c1.x + w.z * c2.x + w.w * c3.x;
            a.y += w.x * c0.y + w.y * c1.y + w.z * c2.y + w.w * c3.y;
            a.z += w.x * c0.z + w.y * c1.z + w.z * c2.z + w.w * c3.z;
            a.w += w.x * c0.w + w.y * c1.w + w.z * c2.w + w.w * c3.w;
            ab += w.x * z.x + w.y * z.y + w.z * z.z + w.w * z.w;
        }
        ((float4*)WC2)[t] = a;
        CB2[t] = ab + c2lb[t];
    } else if (b < 117) {
        int i0 = (b - 53) * 1024;
        for (int r = 0; r < 4; ++r) {
            int i = i0 + r * 256 + t;
            W2B[i] = (bf16_t)c2lw[i];
        }
    } else {
        int i = (b - 117) * 256 + t;
        if (i < NN) CNT[i] = 0;
    }
}

// ---------------- CSR build ----------------
__global__ void gme_count(const int* __restrict__ ei, int* __restrict__ cnt,
                          int* __restrict__ RK) {
    int e = blockIdx.x * 256 + threadIdx.x;
    if (e >= NE) return;
    RK[e] = atomicAdd(&cnt[ei[NE + e]], 1);
}

__global__ void gme_scan1(const int* __restrict__ CNT, int* __restrict__ LP,
                          int* __restrict__ BS) {
    __shared__ int lds[256];
    int b = blockIdx.x, t = threadIdx.x;
    int i = b * 196 + t;
    int v = (t < 196 && i < NN) ? CNT[i] : 0;
    lds[t] = v;
    __syncthreads();
    for (int off = 1; off < 256; off <<= 1) {
        int u = (t >= off) ? lds[t - off] : 0;
        __syncthreads();
        lds[t] += u;
        __syncthreads();
    }
    if (t < 196 && i < NN) LP[i] = lds[t] - v;
    if (t == 255) BS[b] = lds[255];
}

__global__ void gme_scan2(const int* __restrict__ BS, int* __restrict__ BX,
                          int* __restrict__ RS) {
    __shared__ int lds[256];
    int t = threadIdx.x;
    int v = BS[t];
    lds[t] = v;
    __syncthreads();
    for (int off = 1; off < 256; off <<= 1) {
        int u = (t >= off) ? lds[t - off] : 0;
        __syncthreads();
        lds[t] += u;
        __syncthreads();
    }
    BX[t] = lds[t] - v;
    if (t == 255) RS[NN] = lds[255];
}

// scan3 + graph-segment boundaries fused
__global__ void gme_scan3(const int* __restrict__ LP, const int* __restrict__ BX,
                          int* __restrict__ RS,
                          const int* __restrict__ batch, int* __restrict__ GS) {
    int b = blockIdx.x, t = threadIdx.x;
    if (t >= 196) return;
    int i = b * 196 + t;
    if (i >= NN) return;
    RS[i] = BX[b] + LP[i];
    int bb = batch[i];
    if (i == 0) {
        for (int g = 0; g <= bb; ++g) GS[g] = 0;
    } else {
        int a = batch[i - 1];
        for (int g = a + 1; g <= bb; ++g) GS[g] = i;
    }
    if (i == NN - 1) {
        for (int g = bb + 1; g <= NG; ++g) GS[g] = NN;
    }
}

// single 16B record per edge; pos from persisted rank -> no atomic.
// w-word carries the precomputed LDS row offset (nid*64 uint2 units) for conv0.
__global__ void gme_scatter(const int* __restrict__ ei,
                            const float4* __restrict__ eattr,
                            const int* __restrict__ node_ids,
                            const int* __restrict__ RS, const int* __restrict__ RK,
                            uint4* __restrict__ SE) {
    int e = blockIdx.x * 256 + threadIdx.x;
    if (e >= NE) return;
    int s = ei[e];
    int d = ei[NE + e];
    int nid = node_ids[s];
    float4 at = eattr[e];
    int pos = RS[d] + RK[e];
    SE[pos] = make_uint4((unsigned)(s | (nid << 16)), pk2(at.x, at.y), pk2(at.z, at.w),
                         (unsigned)(nid << 6));
}

// ---------------- conv1 layer: bf16 TY in LDS; plain 8-batch; bf16 P out ----
__global__ __launch_bounds__(256) void gme_conv0(
        const int* __restrict__ RS, const uint4* __restrict__ SE,
        const bf16_t* __restrict__ TYB, const float* __restrict__ Wc,
        bf16_t* __restrict__ agg, float* __restrict__ PARTS) {
    __shared__ __align__(16) uint2 sTY[51 * 64];  // 26112 B bf16 table
    {
        const uint4* s4 = (const uint4*)TYB;
        uint4* d4 = (uint4*)sTY;
        for (int i = threadIdx.x; i < 51 * 32; i += 256) d4[i] = s4[i];
    }
    __syncthreads();
    int lane = threadIdx.x & 63;
    int w = threadIdx.x >> 6;
    int vz = vzero();
    const float4* wc4 = (const float4*)Wc;
    int c4 = lane * 4;
    float4 w0 = wc4[c4 + 0], w1 = wc4[c4 + 1], w2 = wc4[c4 + 2], w3 = wc4[c4 + 3];
    f32x2 wA0 = {w0.x, w1.x}, wB0 = {w0.y, w1.y}, wC0 = {w0.z, w1.z}, wD0 = {w0.w, w1.w};
    f32x2 wA1 = {w2.x, w3.x}, wB1 = {w2.y, w3.y}, wC1 = {w2.z, w3.z}, wD1 = {w2.w, w3.w};
    const f32x2 zero = {0.f, 0.f};
    const uint2* lrow = sTY + lane;
    int base = blockIdx.x * 16 + w * 4;
    f32x2 ssum0 = zero, ssum1 = zero, qsum0 = zero, qsum1 = zero;
#pragma unroll 1
    for (int k = 0; k < 4; ++k) {
        int node = __builtin_amdgcn_readfirstlane(base + k);
        int rs = RS[node], re = RS[node + 1];
        f32x2 accP0 = zero, accP1 = zero, accA0 = zero, accA1 = zero;
        auto accum = [&](uint4 se, uint2 r) {
            f32x2 y0 = unpk2(r.x), y1 = unpk2(r.y);
            f32x2 axy = unpk2(se.y), azw = unpk2(se.z);
            f32x2 ax = {axy[0], axy[0]}, ay = {axy[1], axy[1]};
            f32x2 az = {azw[0], azw[0]}, aw = {azw[1], azw[1]};
            f32x2 m0 = __builtin_elementwise_fma(ax, wA0, y0);
            f32x2 m1 = __builtin_elementwise_fma(ax, wA1, y1);
            m0 = __builtin_elementwise_fma(ay, wB0, m0);
            m1 = __builtin_elementwise_fma(ay, wB1, m1);
            m0 = __builtin_elementwise_fma(az, wC0, m0);
            m1 = __builtin_elementwise_fma(az, wC1, m1);
            m0 = __builtin_elementwise_fma(aw, wD0, m0);
            m1 = __builtin_elementwise_fma(aw, wD1, m1);
            accA0 += m0; accA1 += m1;
            accP0 += __builtin_elementwise_max(m0, zero);
            accP1 += __builtin_elementwise_max(m1, zero);
        };
        int j = rs;
        for (; j + 8 <= re; j += 8) {
            uint4 se[8]; uint2 r[8];
#pragma unroll
            for (int u = 0; u < 8; ++u) se[u] = SE[j + u + vz];
#pragma unroll
            for (int u = 0; u < 8; ++u) r[u] = lrow[se[u].w];
#pragma unroll
            for (int u = 0; u < 8; ++u) accum(se[u], r[u]);
        }
        if (j + 4 <= re) {
            uint4 se[4]; uint2 r[4];
#pragma unroll
            for (int u = 0; u < 4; ++u) se[u] = SE[j + u + vz];
#pragma unroll
            for (int u = 0; u < 4; ++u) r[u] = lrow[se[u].w];
#pragma unroll
            for (int u = 0; u < 4; ++u) accum(se[u], r[u]);
            j += 4;
        }
        for (; j < re; ++j) {
            uint4 se = SE[j + vz];
            accum(se, lrow[se.w]);
        }
        const f32x2 c99 = {0.99f, 0.99f}, c01 = {0.01f, 0.01f};
        f32x2 o0 = __builtin_elementwise_fma(accP0, c99, accA0 * c01);
        f32x2 o1 = __builtin_elementwise_fma(accP1, c99, accA1 * c01);
        uint2 ov;
        ov.x = pk2(o0[0], o0[1]);
        ov.y = pk2(o1[0], o1[1]);
        *((uint2*)(agg + node * 256) + lane) = ov;
        ssum0 += o0; ssum1 += o1;
        qsum0 += o0 * o0; qsum1 += o1 * o1;
    }
    // fused BN1 partial stats
    __syncthreads();
    float* red = (float*)sTY;
    red[w * 512 + c4 + 0] = ssum0[0]; red[w * 512 + c4 + 1] = ssum0[1];
    red[w * 512 + c4 + 2] = ssum1[0]; red[w * 512 + c4 + 3] = ssum1[1];
    red[w * 512 + 256 + c4 + 0] = qsum0[0]; red[w * 512 + 256 + c4 + 1] = qsum0[1];
    red[w * 512 + 256 + c4 + 2] = qsum1[0]; red[w * 512 + 256 + c4 + 3] = qsum1[1];
    __syncthreads();
    int cc = threadIdx.x;
    float s = red[cc] + red[512 + cc] + red[1024 + cc] + red[1536 + cc];
    float q = red[256 + cc] + red[768 + cc] + red[1280 + cc] + red[1792 + cc];
    int prow = (blockIdx.x & 255) * 512;
    atomicAdd(&PARTS[prow + cc], s);
    atomicAdd(&PARTS[prow + 256 + cc], q);
}

// ---------------- conv2 layer: random gather; SE pipeline; bf16 P out -------
__global__ __launch_bounds__(256, 4) void gme_conv1(
        const int* __restrict__ RS, const uint4* __restrict__ SE,
        const bf16_t* __restrict__ QB, const float* __restrict__ Wc,
        bf16_t* __restrict__ agg, float* __restrict__ PARTS) {
    __shared__ float red[2048];
    int lane = threadIdx.x & 63;
    int w = threadIdx.x >> 6;
    int node = __builtin_amdgcn_readfirstlane(blockIdx.x * 4 + w);
    const float4* wc4 = (const float4*)Wc;
    int c4 = lane * 4;
    float4 w0 = wc4[c4 + 0], w1 = wc4[c4 + 1], w2 = wc4[c4 + 2], w3 = wc4[c4 + 3];
    f32x2 wA0 = {w0.x, w1.x}, wB0 = {w0.y, w1.y}, wC0 = {w0.z, w1.z}, wD0 = {w0.w, w1.w};
    f32x2 wA1 = {w2.x, w3.x}, wB1 = {w2.y, w3.y}, wC1 = {w2.z, w3.z}, wD1 = {w2.w, w3.w};
    const f32x2 zero = {0.f, 0.f};
    f32x2 accP0 = zero, accP1 = zero, accA0 = zero, accA1 = zero;
    int rs = RS[node], re = RS[node + 1];
    const char* yb = (const char*)QB;
    unsigned loff = (unsigned)(lane << 3);
    auto rowld = [&](unsigned row) -> uint2 {
        return *(const uint2*)(yb + (row << 9) + loff);
    };
    auto accum = [&](uint4 se, uint2 r) {
        f32x2 y0 = unpk2(r.x), y1 = unpk2(r.y);
        f32x2 axy = unpk2(se.y), azw = unpk2(se.z);
        f32x2 ax = {axy[0], axy[0]}, ay = {axy[1], axy[1]};
        f32x2 az = {azw[0], azw[0]}, aw = {azw[1], azw[1]};
        f32x2 m0 = __builtin_elementwise_fma(ax, wA0, y0);
        f32x2 m1 = __builtin_elementwise_fma(ax, wA1, y1);
        m0 = __builtin_elementwise_fma(ay, wB0, m0);
        m1 = __builtin_elementwise_fma(ay, wB1, m1);
        m0 = __builtin_elementwise_fma(az, wC0, m0);
        m1 = __builtin_elementwise_fma(az, wC1, m1);
        m0 = __builtin_elementwise_fma(aw, wD0, m0);
        m1 = __builtin_elementwise_fma(aw, wD1, m1);
        accA0 += m0; accA1 += m1;
        accP0 += __builtin_elementwise_max(m0, zero);
        accP1 += __builtin_elementwise_max(m1, zero);
    };
    int j = rs;
    if (j + 8 <= re) {
        uint4 se[8];
#pragma unroll
        for (int u = 0; u < 8; ++u) se[u] = SE[j + u];
        while (true) {
            uint2 r[8];
#pragma unroll
            for (int u = 0; u < 8; ++u) r[u] = rowld(se[u].x & 0xffffu);
            bool more = (j + 16 <= re);
            uint4 seN[8];
            if (more) {
#pragma unroll
                for (int u = 0; u < 8; ++u) seN[u] = SE[j + 8 + u];
            }
#pragma unroll
            for (int u = 0; u < 8; ++u) accum(se[u], r[u]);
            j += 8;
            if (!more) break;
#pragma unroll
            for (int u = 0; u < 8; ++u) se[u] = seN[u];
        }
    }
    if (j + 4 <= re) {
        uint4 se[4]; uint2 r[4];
#pragma unroll
        for (int u = 0; u < 4; ++u) se[u] = SE[j + u];
#pragma unroll
        for (int u = 0; u < 4; ++u) r[u] = rowld(se[u].x & 0xffffu);
#pragma unroll
        for (int u = 0; u < 4; ++u) accum(se[u], r[u]);
        j += 4;
    }
    for (; j < re; ++j) {
        uint4 se = SE[j];
        accum(se, rowld(se.x & 0xffffu));
    }
    const f32x2 c99 = {0.99f, 0.99f}, c01 = {0.01f, 0.01f};
    f32x2 o0 = __builtin_elementwise_fma(accP0, c99, accA0 * c01);
    f32x2 o1 = __builtin_elementwise_fma(accP1, c99, accA1 * c01);
    uint2 ov;
    ov.x = pk2(o0[0], o0[1]);
    ov.y = pk2(o1[0], o1[1]);
    *((uint2*)(agg + node * 256) + lane) = ov;
    // fused BN2 partial stats (from f32 pre-quantize values)
    red[w * 512 + c4 + 0] = o0[0]; red[w * 512 + c4 + 1] = o0[1];
    red[w * 512 + c4 + 2] = o1[0]; red[w * 512 + c4 + 3] = o1[1];
    red[w * 512 + 256 + c4 + 0] = o0[0] * o0[0];
    red[w * 512 + 256 + c4 + 1] = o0[1] * o0[1];
    red[w * 512 + 256 + c4 + 2] = o1[0] * o1[0];
    red[w * 512 + 256 + c4 + 3] = o1[1] * o1[1];
    __syncthreads();
    int cc = threadIdx.x;
    float s = red[cc] + red[512 + cc] + red[1024 + cc] + red[1536 + cc];
    float q = red[256 + cc] + red[768 + cc] + red[1280 + cc] + red[1792 + cc];
    int prow = (blockIdx.x & 255) * 512;
    atomicAdd(&PARTS[prow + cc], s);
    atomicAdd(&PARTS[prow + 256 + cc], q);
}

// ---------------- PARTS (256x512) -> ST reducer; optionally re-zero ----------
__global__ __launch_bounds__(512) void gme_bred(float* __restrict__ PARTS,
                                                float* __restrict__ ST, int zero) {
    int t = threadIdx.x;
    int b = blockIdx.x;
    float acc = 0.f;
#pragma unroll
    for (int r = 0; r < 16; ++r) acc += PARTS[(b * 16 + r) * 512 + t];
    atomicAdd(&ST[t], acc);
    if (zero) {
#pragma unroll
        for (int r = 0; r < 16; ++r) PARTS[(b * 16 + r) * 512 + t] = 0.f;
    }
}

// ---------------- GEMM, BN1+LeakyReLU fused on A (bf16 P in) -----------------
__global__ __launch_bounds__(256) void gme_gemm(const bf16_t* __restrict__ P,
                                                const float* __restrict__ ST,
                                                const float* __restrict__ bw,
                                                const float* __restrict__ bb,
                                                const bf16_t* __restrict__ W2B,
                                                const float* __restrict__ CB2,
                                                bf16_t* __restrict__ QB) {
    __shared__ float s_sc[256], s_sh[256];
    __shared__ __align__(16) uint4 sB[8192];  // 128 KB, 16B-slot swizzled
    {
        int c = threadIdx.x;
        float mean = ST[c] * (1.f / NN);
        float var = ST[256 + c] * (1.f / NN) - mean * mean;
        float sc = bw[c] * rsqrtf(var + 1e-5f);
        s_sc[c] = sc;
        s_sh[c] = bb[c] - mean * sc;
        const uint4* w4 = (const uint4*)W2B;
#pragma unroll
        for (int it = 0; it < 32; ++it) {
            int i = it * 256 + c;
            int row = i >> 5, slot = i & 31;
            sB[(row << 5) | (slot ^ (row & 7))] = w4[i];
        }
    }
    __syncthreads();
    int lane = threadIdx.x & 63;
    int wave = blockIdx.x * 4 + (threadIdx.x >> 6);
    if (wave >= NN / 16) return;
    int m0 = wave * 16;
    int r = lane & 15, q = lane >> 4;
    int rx = r & 7;
    const uint4* arow = (const uint4*)(P + (m0 + r) * 256);
    bf16x8 a[8];
#pragma unroll
    for (int kt = 0; kt < 8; ++kt) {
        int k0 = kt * 32 + q * 8;
        uint4 u = arow[q + kt * 4];
        f32x2 v0 = unpk2(u.x), v1 = unpk2(u.y), v2 = unpk2(u.z), v3 = unpk2(u.w);
        bf16x8 f;
        f[0] = (bf16_t)lrelu(fmaf(v0[0], s_sc[k0 + 0], s_sh[k0 + 0]));
        f[1] = (bf16_t)lrelu(fmaf(v0[1], s_sc[k0 + 1], s_sh[k0 + 1]));
        f[2] = (bf16_t)lrelu(fmaf(v1[0], s_sc[k0 + 2], s_sh[k0 + 2]));
        f[3] = (bf16_t)lrelu(fmaf(v1[1], s_sc[k0 + 3], s_sh[k0 + 3]));
        f[4] = (bf16_t)lrelu(fmaf(v2[0], s_sc[k0 + 4], s_sh[k0 + 4]));
        f[5] = (bf16_t)lrelu(fmaf(v2[1], s_sc[k0 + 5], s_sh[k0 + 5]));
        f[6] = (bf16_t)lrelu(fmaf(v3[0], s_sc[k0 + 6], s_sh[k0 + 6]));
        f[7] = (bf16_t)lrelu(fmaf(v3[1], s_sc[k0 + 7], s_sh[k0 + 7]));
        a[kt] = f;
    }
#pragma unroll 1
    for (int g = 0; g < 2; ++g) {
        f32x4 acc[8];
#pragma unroll
        for (int n8 = 0; n8 < 8; ++n8) acc[n8] = (f32x4){0.f, 0.f, 0.f, 0.f};
#pragma unroll
        for (int kt = 0; kt < 8; ++kt) {
            int slot = (kt * 4 + q) ^ rx;
            bf16x8 bf[8];
#pragma unroll
            for (int n8 = 0; n8 < 8; ++n8) {
                int row = g * 128 + n8 * 16 + r;
                bf[n8] = *(const bf16x8*)&sB[(row << 5) | slot];
            }
#pragma unroll
            for (int n8 = 0; n8 < 8; ++n8) {
                acc[n8] = __builtin_amdgcn_mfma_f32_16x16x32_bf16(bf[n8], a[kt], acc[n8], 0, 0, 0);
            }
        }
#pragma unroll
        for (int n8 = 0; n8 < 8; ++n8) {
            int nt = g * 8 + n8;
            float4 cbv = ((const float4*)CB2)[nt * 4 + q];
            bf16x4 o;
            o[0] = (bf16_t)(acc[n8][0] + cbv.x);
            o[1] = (bf16_t)(acc[n8][1] + cbv.y);
            o[2] = (bf16_t)(acc[n8][2] + cbv.z);
            o[3] = (bf16_t)(acc[n8][3] + cbv.w);
            *(bf16x4*)(QB + (m0 + r) * 256 + nt * 16 + q * 4) = o;
        }
    }
}

// ---------------- fused gate + attentional aggregation (bf16 P in) ----------
__global__ __launch_bounds__(256) void gme_attn(const int* __restrict__ GS,
                                                const bf16_t* __restrict__ P,
                                                const float* __restrict__ ST,
                                                const float* __restrict__ bw,
                                                const float* __restrict__ bb,
                                                const float* __restrict__ gw,
                                                const float* __restrict__ gb,
                                                float* __restrict__ out) {
    __shared__ float gl[1024];
    __shared__ float rr[8];
    int g = blockIdx.x, t = threadIdx.x;
    int lo = GS[g], hi = GS[g + 1];
    if (lo >= hi) { out[g * 256 + t] = 0.f; return; }
    int lane = t & 63, w = t >> 6;
    // phase A: per-node gates, wave-parallel
    {
        float4 s4 = ((const float4*)ST)[lane];
        float4 q4 = ((const float4*)(ST + 256))[lane];
        float4 w4 = ((const float4*)bw)[lane];
        float4 b4 = ((const float4*)bb)[lane];
        float4 g4 = ((const float4*)gw)[lane];
        float m0 = s4.x * (1.f / NN), m1 = s4.y * (1.f / NN);
        float m2 = s4.z * (1.f / NN), m3 = s4.w * (1.f / NN);
        float sc0 = w4.x * rsqrtf(q4.x * (1.f / NN) - m0 * m0 + 1e-5f);
        float sc1 = w4.y * rsqrtf(q4.y * (1.f / NN) - m1 * m1 + 1e-5f);
        float sc2 = w4.z * rsqrtf(q4.z * (1.f / NN) - m2 * m2 + 1e-5f);
        float sc3 = w4.w * rsqrtf(q4.w * (1.f / NN) - m3 * m3 + 1e-5f);
        float sh0 = b4.x - m0 * sc0, sh1 = b4.y - m1 * sc1;
        float sh2 = b4.z - m2 * sc2, sh3 = b4.w - m3 * sc3;
        float gb0 = gb[0];
        for (int n = lo + w; n < hi; n += 4) {
            uint2 u = *((const uint2*)(P + n * 256) + lane);
            f32x2 p01 = unpk2(u.x), p23 = unpk2(u.y);
            float d = lrelu(fmaf(p01[0], sc0, sh0)) * g4.x
                    + lrelu(fmaf(p01[1], sc1, sh1)) * g4.y
                    + lrelu(fmaf(p23[0], sc2, sh2)) * g4.z
                    + lrelu(fmaf(p23[1], sc3, sh3)) * g4.w;
#pragma unroll
            for (int off = 32; off > 0; off >>= 1) d += __shfl_xor(d, off, 64);
            if (lane == 0) gl[n - lo] = d + gb0;
        }
    }
    __syncthreads();
    // phase B: softmax max + denom
    int cnt = hi - lo;
    float lm = -3.0e38f;
    for (int i = t; i < cnt; i += 256) lm = fmaxf(lm, gl[i]);
#pragma unroll
    for (int off = 32; off > 0; off >>= 1) lm = fmaxf(lm, __shfl_xor(lm, off, 64));
    if (lane == 0) rr[w] = lm;
    __syncthreads();
    float mx = fmaxf(fmaxf(rr[0], rr[1]), fmaxf(rr[2], rr[3]));
    float ls = 0.f;
    for (int i = t; i < cnt; i += 256) { float e = expf(gl[i] - mx); gl[i] = e; ls += e; }
#pragma unroll
    for (int off = 32; off > 0; off >>= 1) ls += __shfl_xor(ls, off, 64);
    if (lane == 0) rr[4 + w] = ls;
    __syncthreads();
    float sinv = 1.f / (rr[4] + rr[5] + rr[6] + rr[7]);
    // phase C: weighted accumulate, thread t = channel t
    float mean = ST[t] * (1.f / NN);
    float var = ST[256 + t] * (1.f / NN) - mean * mean;
    float sc = bw[t] * rsqrtf(var + 1e-5f);
    float sh = bb[t] - mean * sc;
    float a0 = 0.f, a1 = 0.f, a2 = 0.f, a3 = 0.f;
    int n = lo;
    for (; n + 4 <= hi; n += 4) {
        float p0 = (float)P[n * 256 + t], p1 = (float)P[(n + 1) * 256 + t];
        float p2 = (float)P[(n + 2) * 256 + t], p3 = (float)P[(n + 3) * 256 + t];
        a0 = fmaf(gl[n - lo + 0], lrelu(fmaf(p0, sc, sh)), a0);
        a1 = fmaf(gl[n - lo + 1], lrelu(fmaf(p1, sc, sh)), a1);
        a2 = fmaf(gl[n - lo + 2], lrelu(fmaf(p2, sc, sh)), a2);
        a3 = fmaf(gl[n - lo + 3], lrelu(fmaf(p3, sc, sh)), a3);
    }
    for (; n < hi; ++n) a0 = fmaf(gl[n - lo], lrelu(fmaf((float)P[n * 256 + t], sc, sh)), a0);
    out[g * 256 + t] = (a0 + a1 + a2 + a3) * sinv;
}

extern "C" void kernel_launch(void* const* d_in, const int* in_sizes, int n_in,
                              void* d_out, int out_size, void* d_ws, size_t ws_size,
                              hipStream_t stream) {
    const int* node_ids = (const int*)d_in[0];
    const int* edge_index = (const int*)d_in[1];
    const float4* edge_attr = (const float4*)d_in[2];
    const int* batch = (const int*)d_in[3];
    const float* emb = (const float*)d_in[4];
    const float* c1l2w = (const float*)d_in[5];
    const float* c1l2b = (const float*)d_in[6];
    const float* c1lw = (const float*)d_in[7];
    const float* c1lb = (const float*)d_in[8];
    const float* bn1w = (const float*)d_in[9];
    const float* bn1b = (const float*)d_in[10];
    const float* c2l2w = (const float*)d_in[11];
    const float* c2l2b = (const float*)d_in[12];
    const float* c2lw = (const float*)d_in[13];
    const float* c2lb = (const float*)d_in[14];
    const float* bn2w = (const float*)d_in[15];
    const float* bn2b = (const float*)d_in[16];
    const float* gate_w = (const float*)d_in[17];
    const float* gate_b = (const float*)d_in[18];

    char* ws = (char*)d_ws;
    size_t oP = 0;                        // bf16 [50000,256]
    size_t oQB = oP + 25600000;           // bf16 [50000,256]
    size_t oSE = oQB + 25600000;          // uint4 [800000]
    size_t oRK = oSE + 12800000;          // int [800000]
    size_t oRS = oRK + 3200000;           // int [50001]
    size_t oCNT = oRS + 200064;           // int [50000]
    size_t oLP = oCNT + 200000;           // int [50000]
    size_t oBS = oLP + 200000;            // int [256]
    size_t oBX = oBS + 1024;              // int [256]
    size_t oTY = oBX + 1024;              // bf16 [51,256]
    size_t oWC1 = oTY + 52224;            // f32 [256,4]
    size_t oWC2 = oWC1 + 4096;            // f32 [256,4]
    size_t oCB2 = oWC2 + 4096;            // f32 [256]
    size_t oW2B = oCB2 + 1024;            // bf16 [256,256]
    size_t oST = oW2B + 131072;           // f32 [1024]: ST1+ST2
    size_t oPARTS = oST + 4096;           // f32 [256,512]
    size_t oGS = oPARTS + 524288;         // int [513]

    bf16_t* P = (bf16_t*)(ws + oP);
    bf16_t* QB = (bf16_t*)(ws + oQB);
    uint4* SE = (uint4*)(ws + oSE);
    int* RK = (int*)(ws + oRK);
    int* RS = (int*)(ws + oRS);
    int* CNT = (int*)(ws + oCNT);
    int* LP = (int*)(ws + oLP);
    int* BS = (int*)(ws + oBS);
    int* BX = (int*)(ws + oBX);
    bf16_t* TYB = (bf16_t*)(ws + oTY);
    float* WC1 = (float*)(ws + oWC1);
    float* WC2 = (float*)(ws + oWC2);
    float* CB2 = (float*)(ws + oCB2);
    bf16_t* W2B = (bf16_t*)(ws + oW2B);
    float* ST1 = (float*)(ws + oST);
    float* ST2 = ST1 + 512;
    float* PARTS = (float*)(ws + oPARTS);
    int* GS = (int*)(ws + oGS);

    // one memset covers ST1+ST2 (4 KB) and PARTS (512 KB), contiguous
    hipMemsetAsync(ST1, 0, 4096 + 524288, stream);

    gme_setup<<<313, 256, 0, stream>>>(emb, c1lw, c1l2w, c1l2b, c1lb,
                                       c2lw, c2l2w, c2l2b, c2lb,
                                       TYB, WC1, WC2, CB2, W2B, CNT);
    gme_count<<<NE / 256, 256, 0, stream>>>(edge_index, CNT, RK);
    gme_scan1<<<256, 256, 0, stream>>>(CNT, LP, BS);
    gme_scan2<<<1, 256, 0, stream>>>(BS, BX, RS);
    gme_scan3<<<256, 256, 0, stream>>>(LP, BX, RS, batch, GS);
    gme_scatter<<<NE / 256, 256, 0, stream>>>(edge_index, edge_attr, node_ids,
                                              RS, RK, SE);
    // conv1: bf16 TY in LDS, plain 8-batch, BN1 stats fused -> PARTS
    gme_conv0<<<NN / 16, 256, 0, stream>>>(RS, SE, TYB, WC1, P, PARTS);
    gme_bred<<<16, 512, 0, stream>>>(PARTS, ST1, 1);   // -> ST1, re-zero PARTS
    gme_gemm<<<(NN / 16 + 3) / 4, 256, 0, stream>>>(P, ST1, bn1w, bn1b, W2B, CB2, QB);
    // conv2: SE pipeline, BN2 stats fused -> PARTS
    gme_conv1<<<NN / 4, 256, 0, stream>>>(RS, SE, QB, WC2, P, PARTS);
    gme_bred<<<16, 512, 0, stream>>>(PARTS, ST2, 0);   // -> ST2
    gme_attn<<<NG, 256, 0, stream>>>(GS, P, ST2, bn2w, bn2b, gate_w, gate_b,
                                     (float*)d_out);
}